// Round 1
// baseline (40912.457 us; speedup 1.0000x reference)
//
#include <hip/hip_runtime.h>
#include <math.h>

// ============================================================================
// AR_Transcriber round 6.
// Round-5 was still ~20 us/grid-barrier despite hierarchical ARRIVAL: the
// convoy is on the RELEASE line (191 same-line pollers serialize at the
// coherence point), and the 3rd barrier additionally pays 88-vs-104 block
// imbalance (projection). This round:
//   1. 16 distributed arrival lines + 16 distributed RELEASE lines
//      (12 pollers/line); master moved to block 191 (non-projection).
//   2. 3rd grid barrier removed: prev exchange via producer-count wait
//      (8 lines, 88 bumps) checked AFTER the next step's x-dot, so the wait
//      overlaps compute; prevg double-buffered by parity.
//   3. #pragma unroll 4 on batch-dot loops: 4 independent red16 shuffle
//      chains in flight instead of 1.
// Everything else (conv kernels, GEMM, register-resident weights, relaxed
// atomic h-state exchange) identical to round 5.
// ============================================================================

typedef unsigned long long ull;

#define ACO_FL 6266880ull  // 8160*768
#define MASTER_BLK 191

__device__ __forceinline__ float sigf(float x) { return 1.0f / (1.0f + expf(-x)); }

__device__ __forceinline__ ull pack2(float x, float y) {
  union { float f[2]; ull u; } c; c.f[0] = x; c.f[1] = y; return c.u;
}
__device__ __forceinline__ float2 unpack2(ull u) {
  union { ull u; float2 v; } c; c.u = u; return c.v;
}
__device__ __forceinline__ ull at_load(const ull* p) {
  return __hip_atomic_load((ull*)p, __ATOMIC_RELAXED, __HIP_MEMORY_SCOPE_AGENT);
}
__device__ __forceinline__ void at_store(ull* p, ull v) {
  __hip_atomic_store(p, v, __ATOMIC_RELAXED, __HIP_MEMORY_SCOPE_AGENT);
}

// Distributed grid barrier.
// bar layout (u32): [0..255]    16 arrival counters, 16-u32 (64B) apart
//                   [256..511]  16 release lines,    16-u32 apart
//                   [512..639]   8 prev-ready counters, 16-u32 apart
__device__ __forceinline__ void gbar(unsigned* bar, unsigned nb, unsigned NG) {
  __syncthreads();
  if (threadIdx.x == 0) {
    __builtin_amdgcn_s_waitcnt(0);
    __atomic_signal_fence(__ATOMIC_SEQ_CST);
    __hip_atomic_fetch_add(bar + (blockIdx.x & 15) * 16, 1u,
                           __ATOMIC_RELAXED, __HIP_MEMORY_SCOPE_AGENT);
    if (blockIdx.x == MASTER_BLK) {
      const unsigned target = nb * NG;
      for (;;) {
        unsigned s0 = 0;
#pragma unroll
        for (int i = 0; i < 16; ++i)
          s0 += __hip_atomic_load(bar + i * 16, __ATOMIC_RELAXED,
                                  __HIP_MEMORY_SCOPE_AGENT);
        if (s0 >= target) break;
        __builtin_amdgcn_s_sleep(1);
      }
#pragma unroll
      for (int i = 0; i < 16; ++i)
        __hip_atomic_store(bar + 256 + i * 16, nb, __ATOMIC_RELAXED,
                           __HIP_MEMORY_SCOPE_AGENT);
    } else {
      unsigned* rel = bar + 256 + (blockIdx.x & 15) * 16;
      while (__hip_atomic_load(rel, __ATOMIC_RELAXED,
                               __HIP_MEMORY_SCOPE_AGENT) < nb) {
        __builtin_amdgcn_s_sleep(1);
      }
    }
    __atomic_signal_fence(__ATOMIC_SEQ_CST);
  }
  __syncthreads();
}

// Wait until >= target prev publications observed (8 distributed counters).
__device__ __forceinline__ void pwait(unsigned* bar, unsigned target) {
  for (;;) {
    unsigned s0 = 0;
#pragma unroll
    for (int i = 0; i < 8; ++i)
      s0 += __hip_atomic_load(bar + 512 + i * 16, __ATOMIC_RELAXED,
                              __HIP_MEMORY_SCOPE_AGENT);
    if (s0 >= target) break;
    __builtin_amdgcn_s_sleep(1);
  }
  __atomic_signal_fence(__ATOMIC_SEQ_CST);
}

__device__ __forceinline__ float red16(float v) {
  v += __shfl_xor(v, 1, 16);
  v += __shfl_xor(v, 2, 16);
  v += __shfl_xor(v, 4, 16);
  v += __shfl_xor(v, 8, 16);
  return v;
}

// 48-FMA chunk dot: weights from VGPR array W, data from LDS pointer PTR.
#define CDOT48(W, PTR, RES) do {                                              \
  const float* _p = (PTR);                                                    \
  float _a0 = 0.f, _a1 = 0.f, _a2 = 0.f, _a3 = 0.f;                           \
  _Pragma("unroll")                                                           \
  for (int _i = 0; _i < 48; _i += 16) {                                       \
    float4 _v0 = *(const float4*)(_p + _i);                                   \
    float4 _v1 = *(const float4*)(_p + _i + 4);                               \
    float4 _v2 = *(const float4*)(_p + _i + 8);                               \
    float4 _v3 = *(const float4*)(_p + _i + 12);                              \
    _a0 = fmaf((W)[_i + 0], _v0.x, _a0); _a0 = fmaf((W)[_i + 1], _v0.y, _a0); \
    _a0 = fmaf((W)[_i + 2], _v0.z, _a0); _a0 = fmaf((W)[_i + 3], _v0.w, _a0); \
    _a1 = fmaf((W)[_i + 4], _v1.x, _a1); _a1 = fmaf((W)[_i + 5], _v1.y, _a1); \
    _a1 = fmaf((W)[_i + 6], _v1.z, _a1); _a1 = fmaf((W)[_i + 7], _v1.w, _a1); \
    _a2 = fmaf((W)[_i + 8], _v2.x, _a2); _a2 = fmaf((W)[_i + 9], _v2.y, _a2); \
    _a2 = fmaf((W)[_i +10], _v2.z, _a2); _a2 = fmaf((W)[_i +11], _v2.w, _a2); \
    _a3 = fmaf((W)[_i +12], _v3.x, _a3); _a3 = fmaf((W)[_i +13], _v3.y, _a3); \
    _a3 = fmaf((W)[_i +14], _v3.z, _a3); _a3 = fmaf((W)[_i +15], _v3.w, _a3); \
  }                                                                           \
  RES = (_a0 + _a1) + (_a2 + _a3);                                            \
} while (0)

// Stage one h buffer (ull [16][384]) into hs chunked layout. r=batch, s=chunk.
#define STAGE_H(SRC) do {                                                     \
  const ull* _sp = (SRC) + r * 384 + s * 24;                                  \
  float* _dp = hs + s * 772 + r * 48;                                         \
  _Pragma("unroll")                                                           \
  for (int _q = 0; _q < 24; _q += 2) {                                        \
    float2 _va = unpack2(at_load(_sp + _q));                                  \
    float2 _vb = unpack2(at_load(_sp + _q + 1));                              \
    *(float4*)(_dp + 2 * _q) = make_float4(_va.x, _va.y, _vb.x, _vb.y);       \
  }                                                                           \
} while (0)

// ---------------------------------------------------------------------------
// K1: fused conv1+bn1+relu -> conv2+bn2+relu -> pool(1,2). (unchanged)
// ---------------------------------------------------------------------------
__global__ __launch_bounds__(256) void conv12_kernel(
    const float* __restrict__ mel,
    const float* __restrict__ c1w, const float* __restrict__ c1b,
    const float* __restrict__ bn1g, const float* __restrict__ bn1b,
    const float* __restrict__ bn1m, const float* __restrict__ bn1v,
    const float* __restrict__ c2w, const float* __restrict__ c2b,
    const float* __restrict__ bn2g, const float* __restrict__ bn2b,
    const float* __restrict__ bn2m, const float* __restrict__ bn2v,
    float* __restrict__ A, int b0)
{
  __shared__ float melS[5 * 232];
  __shared__ float x1S[12 * 3 * 232];
  __shared__ float wS[48 * 12 * 9];
  const int tid = threadIdx.x;
  const int bl = blockIdx.x >> 9;
  const int b = b0 + bl;
  const int t = blockIdx.x & 511;

  for (int idx = tid; idx < 5 * 232; idx += 256) {
    int rr = idx / 232, cc = idx - rr * 232;
    int r = t - 2 + rr, w = cc - 1;
    float v = 0.f;
    if (r >= 0 && r < 512 && w >= 0 && w < 229) v = mel[(b * 512 + r) * 229 + w];
    melS[idx] = v;
  }

  float accA[22], accB[22];
#pragma unroll
  for (int i = 0; i < 22; ++i) { accA[i] = 0.f; accB[i] = 0.f; }
  __syncthreads();

  for (int icc = 0; icc < 4; ++icc) {
    if (icc) __syncthreads();
    for (int idx = tid; idx < 12 * 3 * 232; idx += 256) {
      int cl = idx / (3 * 232);
      int rem = idx - cl * (3 * 232);
      int rr = rem / 232, cc = rem - rr * 232;
      int c = icc * 12 + cl;
      int r1 = t - 1 + rr, w = cc - 1;
      float v = 0.f;
      if (r1 >= 0 && r1 < 512 && w >= 0 && w < 229) {
        const float* cw = c1w + c * 9;
        const float* m0 = melS + rr * 232 + cc - 1;
        float s = m0[0] * cw[0] + m0[1] * cw[1] + m0[2] * cw[2]
                + m0[232] * cw[3] + m0[233] * cw[4] + m0[234] * cw[5]
                + m0[464] * cw[6] + m0[465] * cw[7] + m0[466] * cw[8];
        s += c1b[c];
        float sc = bn1g[c] * rsqrtf(bn1v[c] + 1e-5f);
        v = fmaxf(s * sc + (bn1b[c] - bn1m[c] * sc), 0.f);
      }
      x1S[idx] = v;
    }
    for (int idx = tid; idx < 48 * 12 * 9; idx += 256) {
      int oc = idx / 108, rem = idx - oc * 108;
      wS[idx] = c2w[(oc * 48 + icc * 12) * 9 + rem];
    }
    __syncthreads();
    for (int i = 0; i < 22; ++i) {
      int oidx = tid + i * 256;
      if (oidx >= 5472) break;
      int oc = oidx / 114, wp = oidx - oc * 114;
      int w0 = 2 * wp;
      float a0 = accA[i], a1 = accB[i];
      const float* wp9 = wS + oc * 108;
      for (int icl = 0; icl < 12; ++icl) {
#pragma unroll
        for (int a = 0; a < 3; ++a) {
          const float* xr = x1S + (icl * 3 + a) * 232 + w0;
          float x0 = xr[0], x1 = xr[1], x2 = xr[2], x3 = xr[3];
          float wA = wp9[icl * 9 + a * 3 + 0];
          float wB = wp9[icl * 9 + a * 3 + 1];
          float wC = wp9[icl * 9 + a * 3 + 2];
          a0 = fmaf(x0, wA, a0); a0 = fmaf(x1, wB, a0); a0 = fmaf(x2, wC, a0);
          a1 = fmaf(x1, wA, a1); a1 = fmaf(x2, wB, a1); a1 = fmaf(x3, wC, a1);
        }
      }
      accA[i] = a0; accB[i] = a1;
    }
  }
  for (int i = 0; i < 22; ++i) {
    int oidx = tid + i * 256;
    if (oidx >= 5472) break;
    int oc = oidx / 114, wp = oidx - oc * 114;
    float sc = bn2g[oc] * rsqrtf(bn2v[oc] + 1e-5f);
    float sh = bn2b[oc] - bn2m[oc] * sc;
    float v0 = fmaxf((accA[i] + c2b[oc]) * sc + sh, 0.f);
    float v1 = fmaxf((accB[i] + c2b[oc]) * sc + sh, 0.f);
    A[((bl * 48 + oc) * 512 + t) * 114 + wp] = fmaxf(v0, v1);
  }
}

// ---------------------------------------------------------------------------
// K2: conv3+bn3+relu+pool(1,2); GEMM-ready output. (unchanged)
// ---------------------------------------------------------------------------
__global__ __launch_bounds__(256) void conv3_kernel(
    const float* __restrict__ A,
    const float* __restrict__ c3w, const float* __restrict__ c3b,
    const float* __restrict__ bn3g, const float* __restrict__ bn3b,
    const float* __restrict__ bn3m, const float* __restrict__ bn3v,
    float* __restrict__ Bf)
{
  __shared__ float aS[16 * 3 * 116];
  __shared__ float wS[48 * 16 * 9];
  const int tid = threadIdx.x;
  const int bl = blockIdx.x / 510;
  const int t = blockIdx.x - bl * 510;

  for (int ocg = 0; ocg < 2; ++ocg) {
    float accA[11], accB[11];
#pragma unroll
    for (int i = 0; i < 11; ++i) { accA[i] = 0.f; accB[i] = 0.f; }
    for (int icc = 0; icc < 3; ++icc) {
      __syncthreads();
      for (int idx = tid; idx < 16 * 3 * 116; idx += 256) {
        int cl = idx / 348, rem = idx - cl * 348;
        int rr = rem / 116, cc = rem - rr * 116;
        int w = cc - 1;
        float v = 0.f;
        if (w >= 0 && w < 114) v = A[((bl * 48 + icc * 16 + cl) * 512 + t + rr) * 114 + w];
        aS[idx] = v;
      }
      for (int idx = tid; idx < 48 * 16 * 9; idx += 256) {
        int ocl = idx / 144, rem = idx - ocl * 144;
        wS[idx] = c3w[((ocg * 48 + ocl) * 48 + icc * 16) * 9 + rem];
      }
      __syncthreads();
      for (int i = 0; i < 11; ++i) {
        int oidx = tid + i * 256;
        if (oidx >= 2736) break;
        int ocl = oidx / 57, wp = oidx - ocl * 57;
        int w0 = 2 * wp;
        float a0 = accA[i], a1 = accB[i];
        const float* wb = wS + ocl * 144;
        for (int icl = 0; icl < 16; ++icl) {
#pragma unroll
          for (int a = 0; a < 3; ++a) {
            const float* xr = aS + (icl * 3 + a) * 116 + w0;
            float x0 = xr[0], x1 = xr[1], x2 = xr[2], x3 = xr[3];
            float wA = wb[icl * 9 + a * 3 + 0];
            float wB = wb[icl * 9 + a * 3 + 1];
            float wC = wb[icl * 9 + a * 3 + 2];
            a0 = fmaf(x0, wA, a0); a0 = fmaf(x1, wB, a0); a0 = fmaf(x2, wC, a0);
            a1 = fmaf(x1, wA, a1); a1 = fmaf(x2, wB, a1); a1 = fmaf(x3, wC, a1);
          }
        }
        accA[i] = a0; accB[i] = a1;
      }
    }
    for (int i = 0; i < 11; ++i) {
      int oidx = tid + i * 256;
      if (oidx >= 2736) break;
      int ocl = oidx / 57, wp = oidx - ocl * 57;
      int oc = ocg * 48 + ocl;
      float sc = bn3g[oc] * rsqrtf(bn3v[oc] + 1e-5f);
      float sh = bn3b[oc] - bn3m[oc] * sc;
      float v0 = fmaxf((accA[i] + c3b[oc]) * sc + sh, 0.f);
      float v1 = fmaxf((accB[i] + c3b[oc]) * sc + sh, 0.f);
      Bf[(size_t)(bl * 510 + t) * 5472 + oc * 57 + wp] = fmaxf(v0, v1);
    }
  }
}

// ---------------------------------------------------------------------------
// K3: fp32 NT GEMM  C[M,N] = A * B^T + bias. (FC only, unchanged)
// ---------------------------------------------------------------------------
__global__ __launch_bounds__(256) void gemm_nt(
    const float* __restrict__ Am, const float* __restrict__ Bm,
    const float* __restrict__ bias, float* __restrict__ C,
    int M, int N, int K, int lda, int ldb, int ldc)
{
  __shared__ float As[64 * 33];
  __shared__ float Bs[64 * 33];
  const int tid = threadIdx.x;
  const int m0 = blockIdx.x * 64, n0 = blockIdx.y * 64;
  const int tx = tid & 15, ty = tid >> 4;
  const int kq = (tid & 7) * 4, rw = tid >> 3;
  float acc[4][4];
#pragma unroll
  for (int i = 0; i < 4; ++i)
#pragma unroll
    for (int j = 0; j < 4; ++j) acc[i][j] = 0.f;

  for (int k0 = 0; k0 < K; k0 += 32) {
    int m1 = m0 + rw, m2 = m1 + 32;
    float4 va = make_float4(0.f, 0.f, 0.f, 0.f), vb = va;
    if (m1 < M) va = *(const float4*)(Am + (size_t)m1 * lda + k0 + kq);
    if (m2 < M) vb = *(const float4*)(Am + (size_t)m2 * lda + k0 + kq);
    float4 wa = *(const float4*)(Bm + (size_t)(n0 + rw) * ldb + k0 + kq);
    float4 wb = *(const float4*)(Bm + (size_t)(n0 + rw + 32) * ldb + k0 + kq);
    As[rw * 33 + kq + 0] = va.x; As[rw * 33 + kq + 1] = va.y;
    As[rw * 33 + kq + 2] = va.z; As[rw * 33 + kq + 3] = va.w;
    As[(rw + 32) * 33 + kq + 0] = vb.x; As[(rw + 32) * 33 + kq + 1] = vb.y;
    As[(rw + 32) * 33 + kq + 2] = vb.z; As[(rw + 32) * 33 + kq + 3] = vb.w;
    Bs[rw * 33 + kq + 0] = wa.x; Bs[rw * 33 + kq + 1] = wa.y;
    Bs[rw * 33 + kq + 2] = wa.z; Bs[rw * 33 + kq + 3] = wa.w;
    Bs[(rw + 32) * 33 + kq + 0] = wb.x; Bs[(rw + 32) * 33 + kq + 1] = wb.y;
    Bs[(rw + 32) * 33 + kq + 2] = wb.z; Bs[(rw + 32) * 33 + kq + 3] = wb.w;
    __syncthreads();
#pragma unroll 8
    for (int k = 0; k < 32; ++k) {
      float av[4], bv[4];
#pragma unroll
      for (int i = 0; i < 4; ++i) av[i] = As[(ty * 4 + i) * 33 + k];
#pragma unroll
      for (int j = 0; j < 4; ++j) bv[j] = Bs[(tx * 4 + j) * 33 + k];
#pragma unroll
      for (int i = 0; i < 4; ++i)
#pragma unroll
        for (int j = 0; j < 4; ++j) acc[i][j] = fmaf(av[i], bv[j], acc[i][j]);
    }
    __syncthreads();
  }
#pragma unroll
  for (int i = 0; i < 4; ++i) {
    int m = m0 + ty * 4 + i;
    if (m >= M) continue;
#pragma unroll
    for (int j = 0; j < 4; ++j) {
      int n = n0 + tx * 4 + j;
      C[(size_t)m * ldc + n] = acc[i][j] + bias[n];
    }
  }
}

// ---------------------------------------------------------------------------
__global__ void init_state(ull* __restrict__ h1g, ull* __restrict__ h2g,
                           ull* __restrict__ prevg, unsigned* __restrict__ bar) {
  int gid = blockIdx.x * 256 + threadIdx.x;
  if (gid < 12288) { at_store(h1g + gid, 0ull); at_store(h2g + gid, 0ull); }
  if (gid < 2816) at_store(prevg + gid, 0ull);
  if (gid < 1024)
    __hip_atomic_store(bar + gid, 0u, __ATOMIC_RELAXED, __HIP_MEMORY_SCOPE_AGENT);
}

// ---------------------------------------------------------------------------
// K6: persistent LSTM. 2 grid barriers/step + overlapped prev-ready wait.
// ---------------------------------------------------------------------------
__global__ __launch_bounds__(256, 1) void lstm_kernel(
    const float* __restrict__ aco,   // [16][510][768]
    const float* __restrict__ whh0,  // [3072][768]
    const float* __restrict__ wih0,  // [3072][944]
    const float* __restrict__ wih1,  // [3072][768]
    const float* __restrict__ whh1,  // [3072][768]
    const float* __restrict__ bih0, const float* __restrict__ bhh0,
    const float* __restrict__ bih1, const float* __restrict__ bhh1,
    const float* __restrict__ pw,    // [440][768]
    const float* __restrict__ pb,
    const float* __restrict__ emb,   // [5][2]
    ull* __restrict__ h1g,           // [2][16][384] packed pairs
    ull* __restrict__ h2g,
    ull* __restrict__ prevg,         // [2][16][88] packed emb pairs
    unsigned* __restrict__ bar,
    float* __restrict__ out)         // [16][510][440]
{
  __shared__ float hs[16 * 772];     // chunked [s][b][48], stride 772
  __shared__ float prevs[16 * 177];  // chunked [s][b][11], stride 177
  __shared__ float zl[16 * 17];      // [row][b]
  __shared__ float harr[64];
  __shared__ float embS[10];
  const int tid = threadIdx.x;
  const int s = tid & 15;            // k-chunk
  const int r = tid >> 4;            // gate-row (dots) / batch (staging)
  const int uB = blockIdx.x * 4;
  const int j = (r >> 2) * 768 + uB + (r & 3);

  // ---- one-time register weight load ----
  float wx[48], w0[48], w1[48], w2[48], wp[11], pwr[48];
  {
    const float* p = wih0 + (size_t)j * 944 + 48 * s;
#pragma unroll
    for (int i = 0; i < 48; i += 4) {
      float4 v = *(const float4*)(p + i);
      wx[i] = v.x; wx[i+1] = v.y; wx[i+2] = v.z; wx[i+3] = v.w;
    }
    p = whh0 + (size_t)j * 768 + 48 * s;
#pragma unroll
    for (int i = 0; i < 48; i += 4) {
      float4 v = *(const float4*)(p + i);
      w0[i] = v.x; w0[i+1] = v.y; w0[i+2] = v.z; w0[i+3] = v.w;
    }
    p = wih1 + (size_t)j * 768 + 48 * s;
#pragma unroll
    for (int i = 0; i < 48; i += 4) {
      float4 v = *(const float4*)(p + i);
      w1[i] = v.x; w1[i+1] = v.y; w1[i+2] = v.z; w1[i+3] = v.w;
    }
    p = whh1 + (size_t)j * 768 + 48 * s;
#pragma unroll
    for (int i = 0; i < 48; i += 4) {
      float4 v = *(const float4*)(p + i);
      w2[i] = v.x; w2[i+1] = v.y; w2[i+2] = v.z; w2[i+3] = v.w;
    }
    const float* pp = wih0 + (size_t)j * 944 + 768 + 11 * s;
#pragma unroll
    for (int i = 0; i < 11; ++i) wp[i] = pp[i];
  }
  const bool pv = (blockIdx.x < 88) && (r < 5);
  const int prow = blockIdx.x * 5 + r;
  float pbv = 0.f;
  if (pv) {
    const float* p = pw + (size_t)prow * 768 + 48 * s;
#pragma unroll
    for (int i = 0; i < 48; i += 4) {
      float4 v = *(const float4*)(p + i);
      pwr[i] = v.x; pwr[i+1] = v.y; pwr[i+2] = v.z; pwr[i+3] = v.w;
    }
    pbv = pb[prow];
  } else {
#pragma unroll
    for (int i = 0; i < 48; ++i) pwr[i] = 0.f;
  }
  // cell-thread constants (tid<64: ul = tid>>4, b = tid&15)
  float bl1[4], bl2[4], c1 = 0.f, c2 = 0.f;
  if (tid < 64) {
    int ul = tid >> 4;
#pragma unroll
    for (int g = 0; g < 4; ++g) {
      int jj = g * 768 + uB + ul;
      bl1[g] = bih0[jj] + bhh0[jj];
      bl2[g] = bih1[jj] + bhh1[jj];
    }
  }
  if (tid < 10) embS[tid] = emb[tid];

  unsigned nb = 0;
  const unsigned NG = gridDim.x;

  for (int t = 0; t < 510; ++t) {
    const int wbuf = t & 1, rbuf = wbuf ^ 1;  // rbuf == (t-1)&1 for t>=1
    // ============ PH1a: stage x(t), x-dot (overlaps prev-ready wait) =======
    {
      const float* xr = aco + ((size_t)r * 510 + t) * 768 + 48 * s;
      float* dst = hs + s * 772 + r * 48;
#pragma unroll
      for (int i = 0; i < 48; i += 4) *(float4*)(dst + i) = *(const float4*)(xr + i);
    }
    __syncthreads();
#pragma unroll 4
    for (int b = 0; b < 16; ++b) {
      float p; CDOT48(wx, hs + s * 772 + b * 48, p);
      p = red16(p);
      if (s == 0) zl[r * 17 + b] = p;
    }
    // prev(t-1) published by 88 proj blocks during step t-1 => count 88*t.
    if (tid == 0 && t) pwait(bar, 88u * (unsigned)t);
    __syncthreads();
    // ============ PH1b: stage h1(t-1) + prevs, recurrent dot ============
    STAGE_H(h1g + rbuf * 6144);
    if (t == 0) {
      float* pd = prevs + s * 177 + r * 11;
#pragma unroll
      for (int i = 0; i < 11; ++i) pd[i] = 0.f;
    } else {
      const ull* pg = prevg + rbuf * 1408 + r * 88;
      float* pd = prevs + s * 177 + r * 11;
      int d0 = 11 * s;
#pragma unroll
      for (int i = 0; i < 11; ++i) {
        int d = d0 + i;
        float2 e = unpack2(at_load(pg + (d >> 1)));
        pd[i] = (d & 1) ? e.y : e.x;
      }
    }
    __syncthreads();
#pragma unroll 4
    for (int b = 0; b < 16; ++b) {
      float p; CDOT48(w0, hs + s * 772 + b * 48, p);
      const float* pvv = prevs + s * 177 + b * 11;
#pragma unroll
      for (int i = 0; i < 11; ++i) p = fmaf(wp[i], pvv[i], p);
      p = red16(p);
      if (s == 0) zl[r * 17 + b] += p;
    }
    __syncthreads();
    if (tid < 64) {
      int ul = tid >> 4, bb = tid & 15;
      float zi = zl[(0 * 4 + ul) * 17 + bb] + bl1[0];
      float zf = zl[(1 * 4 + ul) * 17 + bb] + bl1[1];
      float zg = zl[(2 * 4 + ul) * 17 + bb] + bl1[2];
      float zo = zl[(3 * 4 + ul) * 17 + bb] + bl1[3];
      c1 = sigf(zf) * c1 + sigf(zi) * tanhf(zg);
      harr[tid] = sigf(zo) * tanhf(c1);
    }
    __syncthreads();
    if (tid < 32) {
      int q = tid >> 4, bb = tid & 15;
      at_store(h1g + wbuf * 6144 + bb * 384 + blockIdx.x * 2 + q,
               pack2(harr[(2 * q) * 16 + bb], harr[(2 * q + 1) * 16 + bb]));
    }
    ++nb; gbar(bar, nb, NG);           // barrier A: h1(t) visible
    // ============ PH2: h2 cell ============
    STAGE_H(h1g + wbuf * 6144);
    __syncthreads();
#pragma unroll 4
    for (int b = 0; b < 16; ++b) {
      float p; CDOT48(w1, hs + s * 772 + b * 48, p);
      p = red16(p);
      if (s == 0) zl[r * 17 + b] = p;
    }
    __syncthreads();
    STAGE_H(h2g + rbuf * 6144);
    __syncthreads();
#pragma unroll 4
    for (int b = 0; b < 16; ++b) {
      float p; CDOT48(w2, hs + s * 772 + b * 48, p);
      p = red16(p);
      if (s == 0) zl[r * 17 + b] += p;
    }
    __syncthreads();
    if (tid < 64) {
      int ul = tid >> 4, bb = tid & 15;
      float zi = zl[(0 * 4 + ul) * 17 + bb] + bl2[0];
      float zf = zl[(1 * 4 + ul) * 17 + bb] + bl2[1];
      float zg = zl[(2 * 4 + ul) * 17 + bb] + bl2[2];
      float zo = zl[(3 * 4 + ul) * 17 + bb] + bl2[3];
      c2 = sigf(zf) * c2 + sigf(zi) * tanhf(zg);
      harr[tid] = sigf(zo) * tanhf(c2);
    }
    __syncthreads();
    if (tid < 32) {
      int q = tid >> 4, bb = tid & 15;
      at_store(h2g + wbuf * 6144 + bb * 384 + blockIdx.x * 2 + q,
               pack2(harr[(2 * q) * 16 + bb], harr[(2 * q + 1) * 16 + bb]));
    }
    ++nb; gbar(bar, nb, NG);           // barrier B: h2(t) visible
    // ============ PH3: projection + argmax (blocks < 88), NO grid barrier ==
    // Back-pressure: nobody passes step-(t+1)'s pwait until all 88 blocks
    // bump pcnt below, so h2g/prevg parity reuse stays race-free.
    if (blockIdx.x < 88) {
      STAGE_H(h2g + wbuf * 6144);
      __syncthreads();
#pragma unroll 4
      for (int b = 0; b < 16; ++b) {
        float p; CDOT48(pwr, hs + s * 772 + b * 48, p);
        p = red16(p);
        if (pv && s == 0) {
          float lg = p + pbv;
          out[((size_t)b * 510 + t) * 440 + prow] = lg;
          zl[r * 17 + b] = lg;
        }
      }
      __syncthreads();
      if (tid < 16) {
        float best = zl[0 * 17 + tid]; int bi = 0;
#pragma unroll
        for (int c = 1; c < 5; ++c) {
          float v = zl[c * 17 + tid];
          if (v > best) { best = v; bi = c; }
        }
        at_store(prevg + wbuf * 1408 + tid * 88 + blockIdx.x,
                 pack2(embS[bi * 2], embS[bi * 2 + 1]));
      }
      // stores above are wave-0; waitcnt in same wave covers them
      if (tid == 0) {
        __builtin_amdgcn_s_waitcnt(0);
        __atomic_signal_fence(__ATOMIC_SEQ_CST);
        __hip_atomic_fetch_add(bar + 512 + (blockIdx.x & 7) * 16, 1u,
                               __ATOMIC_RELAXED, __HIP_MEMORY_SCOPE_AGENT);
      }
    }
  }
}

// ---------------------------------------------------------------------------
extern "C" void kernel_launch(void* const* d_in, const int* in_sizes, int n_in,
                              void* d_out, int out_size, void* d_ws, size_t ws_size,
                              hipStream_t stream) {
  (void)in_sizes; (void)n_in; (void)out_size;
  const float* mel  = (const float*)d_in[0];
  const float* c1w  = (const float*)d_in[1];
  const float* c1b  = (const float*)d_in[2];
  const float* c2w  = (const float*)d_in[3];
  const float* c2b  = (const float*)d_in[4];
  const float* c3w  = (const float*)d_in[5];
  const float* c3b  = (const float*)d_in[6];
  const float* bn1g = (const float*)d_in[7];
  const float* bn1b = (const float*)d_in[8];
  const float* bn1m = (const float*)d_in[9];
  const float* bn1v = (const float*)d_in[10];
  const float* bn2g = (const float*)d_in[11];
  const float* bn2b = (const float*)d_in[12];
  const float* bn2m = (const float*)d_in[13];
  const float* bn2v = (const float*)d_in[14];
  const float* bn3g = (const float*)d_in[15];
  const float* bn3b = (const float*)d_in[16];
  const float* bn3m = (const float*)d_in[17];
  const float* bn3v = (const float*)d_in[18];
  const float* fcw  = (const float*)d_in[19];
  const float* fcb  = (const float*)d_in[20];
  const float* wih0 = (const float*)d_in[21];
  const float* whh0 = (const float*)d_in[22];
  const float* bih0 = (const float*)d_in[23];
  const float* bhh0 = (const float*)d_in[24];
  const float* wih1 = (const float*)d_in[25];
  const float* whh1 = (const float*)d_in[26];
  const float* bih1 = (const float*)d_in[27];
  const float* bhh1 = (const float*)d_in[28];
  const float* pw   = (const float*)d_in[29];
  const float* pb   = (const float*)d_in[30];
  const float* emb  = (const float*)d_in[31];

  float* ws = (float*)d_ws;
  float* outp = (float*)d_out;

  // state: h1g(12288) + h2g(12288) + prevg(2*1408=2816) ulls, bar 1024 u32
  const size_t ST_ULL = 12288ull + 12288ull + 2816ull;
  int CB = 1;
  for (int cb = 4; cb >= 1; cb >>= 1) {
    size_t need = (ACO_FL + (size_t)cb * 48 * 512 * 114 + (size_t)cb * 510 * 5472) * 4
                + ST_ULL * 8 + 4096 + 1024;
    if (ws_size >= need) { CB = cb; break; }
  }
  const int nchunks = 16 / CB;
  const size_t A_FL  = (size_t)CB * 48 * 512 * 114;
  const size_t BF_FL = (size_t)CB * 510 * 5472;

  float* aco = ws;
  float* Ac  = ws + ACO_FL;
  float* Bfc = Ac + A_FL;
  ull* h1g   = (ull*)(Bfc + BF_FL);
  ull* h2g   = h1g + 12288;
  ull* prevg = h2g + 12288;
  unsigned* bar = (unsigned*)(prevg + 2816);

  for (int ch = 0; ch < nchunks; ++ch) {
    int b0 = ch * CB;
    hipLaunchKernelGGL(conv12_kernel, dim3(CB * 512), dim3(256), 0, stream,
                       mel, c1w, c1b, bn1g, bn1b, bn1m, bn1v,
                       c2w, c2b, bn2g, bn2b, bn2m, bn2v, Ac, b0);
    hipLaunchKernelGGL(conv3_kernel, dim3(CB * 510), dim3(256), 0, stream,
                       Ac, c3w, c3b, bn3g, bn3b, bn3m, bn3v, Bfc);
    int M = CB * 510;
    hipLaunchKernelGGL(gemm_nt, dim3((M + 63) / 64, 12), dim3(256), 0, stream,
                       Bfc, fcw, fcb, aco + (size_t)b0 * 510 * 768,
                       M, 768, 5472, 5472, 5472, 768);
  }
  hipLaunchKernelGGL(init_state, dim3(48), dim3(256), 0, stream,
                     h1g, h2g, prevg, bar);

  {
    void* args[] = {
      (void*)&aco, (void*)&whh0, (void*)&wih0, (void*)&wih1, (void*)&whh1,
      (void*)&bih0, (void*)&bhh0, (void*)&bih1, (void*)&bhh1,
      (void*)&pw, (void*)&pb, (void*)&emb,
      (void*)&h1g, (void*)&h2g, (void*)&prevg, (void*)&bar, (void*)&outp
    };
    hipError_t e = hipLaunchCooperativeKernel((const void*)lstm_kernel,
                                              dim3(192), dim3(256), args, 0, stream);
    if (e != hipSuccess) {
      (void)hipGetLastError();
      hipLaunchKernelGGL(lstm_kernel, dim3(192), dim3(256), 0, stream,
                         aco, whh0, wih0, wih1, whh1, bih0, bhh0, bih1, bhh1,
                         pw, pb, emb, h1g, h2g, prevg, bar, outp);
    }
  }
}

// Round 2
// 36131.119 us; speedup vs baseline: 1.1323x; 1.1323x over previous
//
#include <hip/hip_runtime.h>
#include <math.h>

// ============================================================================
// AR_Transcriber round 7.
// r5/r6 falsified barrier-latency theories (two rewrites, zero delta).
// New theory: the ~50 us/step idle is the h-state all-gather: STAGE_H issued
// 24x8B agent-scope atomic loads per lane at 192B lane stride = 64 line
// transactions per wave instr, 4.1M L2-bypass requests/step, ~1536 serialized
// same-line hits at the coherence point. Fixes:
//  1. Global h layout -> chunked [parity][s][r][24 ull] == LDS order, staged
//     with lane-consecutive (coalesced) loads + precomputed LDS scatter.
//  2. Second LDS h-buffer keeps h1(t) from PH2 into step t+1 (one fewer
//     stage event); PH2 issues both stages back-to-back, fuses w1/w2 dots
//     into one red16 pass.
//  3. prev-stage and x-stage also coalesced (aco relaid to [t][16][768] by
//     the FC GEMM).
// Barrier/pwait machinery unchanged from r6.
// ============================================================================

typedef unsigned long long ull;

#define ACO_FL 6266880ull  // 510*16*768
#define MASTER_BLK 191

__device__ __forceinline__ float sigf(float x) { return 1.0f / (1.0f + expf(-x)); }

__device__ __forceinline__ ull pack2(float x, float y) {
  union { float f[2]; ull u; } c; c.f[0] = x; c.f[1] = y; return c.u;
}
__device__ __forceinline__ float2 unpack2(ull u) {
  union { ull u; float2 v; } c; c.u = u; return c.v;
}
__device__ __forceinline__ ull at_load(const ull* p) {
  return __hip_atomic_load((ull*)p, __ATOMIC_RELAXED, __HIP_MEMORY_SCOPE_AGENT);
}
__device__ __forceinline__ float at_loadf(const float* p) {
  return __hip_atomic_load((float*)p, __ATOMIC_RELAXED, __HIP_MEMORY_SCOPE_AGENT);
}
__device__ __forceinline__ void at_store(ull* p, ull v) {
  __hip_atomic_store(p, v, __ATOMIC_RELAXED, __HIP_MEMORY_SCOPE_AGENT);
}

// Distributed grid barrier (r6 design).
// bar layout (u32): [0..255]   16 arrival counters, 16-u32 apart
//                   [256..511] 16 release lines,    16-u32 apart
//                   [512..639]  8 prev-ready counters, 16-u32 apart
__device__ __forceinline__ void gbar(unsigned* bar, unsigned nb, unsigned NG) {
  __syncthreads();
  if (threadIdx.x == 0) {
    __builtin_amdgcn_s_waitcnt(0);
    __atomic_signal_fence(__ATOMIC_SEQ_CST);
    __hip_atomic_fetch_add(bar + (blockIdx.x & 15) * 16, 1u,
                           __ATOMIC_RELAXED, __HIP_MEMORY_SCOPE_AGENT);
    if (blockIdx.x == MASTER_BLK) {
      const unsigned target = nb * NG;
      for (;;) {
        unsigned s0 = 0;
#pragma unroll
        for (int i = 0; i < 16; ++i)
          s0 += __hip_atomic_load(bar + i * 16, __ATOMIC_RELAXED,
                                  __HIP_MEMORY_SCOPE_AGENT);
        if (s0 >= target) break;
        __builtin_amdgcn_s_sleep(1);
      }
#pragma unroll
      for (int i = 0; i < 16; ++i)
        __hip_atomic_store(bar + 256 + i * 16, nb, __ATOMIC_RELAXED,
                           __HIP_MEMORY_SCOPE_AGENT);
    } else {
      unsigned* rel = bar + 256 + (blockIdx.x & 15) * 16;
      while (__hip_atomic_load(rel, __ATOMIC_RELAXED,
                               __HIP_MEMORY_SCOPE_AGENT) < nb) {
        __builtin_amdgcn_s_sleep(1);
      }
    }
    __atomic_signal_fence(__ATOMIC_SEQ_CST);
  }
  __syncthreads();
}

__device__ __forceinline__ void pwait(unsigned* bar, unsigned target) {
  for (;;) {
    unsigned s0 = 0;
#pragma unroll
    for (int i = 0; i < 8; ++i)
      s0 += __hip_atomic_load(bar + 512 + i * 16, __ATOMIC_RELAXED,
                              __HIP_MEMORY_SCOPE_AGENT);
    if (s0 >= target) break;
    __builtin_amdgcn_s_sleep(1);
  }
  __atomic_signal_fence(__ATOMIC_SEQ_CST);
}

__device__ __forceinline__ float red16(float v) {
  v += __shfl_xor(v, 1, 16);
  v += __shfl_xor(v, 2, 16);
  v += __shfl_xor(v, 4, 16);
  v += __shfl_xor(v, 8, 16);
  return v;
}

// 48-FMA chunk dot: weights from VGPR array W, data from LDS pointer PTR.
#define CDOT48(W, PTR, RES) do {                                              \
  const float* _p = (PTR);                                                    \
  float _a0 = 0.f, _a1 = 0.f, _a2 = 0.f, _a3 = 0.f;                           \
  _Pragma("unroll")                                                           \
  for (int _i = 0; _i < 48; _i += 16) {                                       \
    float4 _v0 = *(const float4*)(_p + _i);                                   \
    float4 _v1 = *(const float4*)(_p + _i + 4);                               \
    float4 _v2 = *(const float4*)(_p + _i + 8);                               \
    float4 _v3 = *(const float4*)(_p + _i + 12);                              \
    _a0 = fmaf((W)[_i + 0], _v0.x, _a0); _a0 = fmaf((W)[_i + 1], _v0.y, _a0); \
    _a0 = fmaf((W)[_i + 2], _v0.z, _a0); _a0 = fmaf((W)[_i + 3], _v0.w, _a0); \
    _a1 = fmaf((W)[_i + 4], _v1.x, _a1); _a1 = fmaf((W)[_i + 5], _v1.y, _a1); \
    _a1 = fmaf((W)[_i + 6], _v1.z, _a1); _a1 = fmaf((W)[_i + 7], _v1.w, _a1); \
    _a2 = fmaf((W)[_i + 8], _v2.x, _a2); _a2 = fmaf((W)[_i + 9], _v2.y, _a2); \
    _a2 = fmaf((W)[_i +10], _v2.z, _a2); _a2 = fmaf((W)[_i +11], _v2.w, _a2); \
    _a3 = fmaf((W)[_i +12], _v3.x, _a3); _a3 = fmaf((W)[_i +13], _v3.y, _a3); \
    _a3 = fmaf((W)[_i +14], _v3.z, _a3); _a3 = fmaf((W)[_i +15], _v3.w, _a3); \
  }                                                                           \
  RES = (_a0 + _a1) + (_a2 + _a3);                                            \
} while (0)

// Coalesced h stage: global chunked layout [s][r][24 ull] -> LDS chunked
// [s*772 + r*48 + 2q]. Lane loads G = q*256+tid (consecutive 8B), scatters
// via precomputed offH.
#define STAGE_HC(SRC, DST) do {                                               \
  _Pragma("unroll")                                                           \
  for (int _q = 0; _q < 24; ++_q) {                                           \
    ull _v = at_load((SRC) + _q * 256 + tid);                                 \
    *(float2*)((DST) + offH[_q]) = unpack2(_v);                               \
  }                                                                           \
} while (0)

// ---------------------------------------------------------------------------
// K1: fused conv1+bn1+relu -> conv2+bn2+relu -> pool(1,2). (unchanged)
// ---------------------------------------------------------------------------
__global__ __launch_bounds__(256) void conv12_kernel(
    const float* __restrict__ mel,
    const float* __restrict__ c1w, const float* __restrict__ c1b,
    const float* __restrict__ bn1g, const float* __restrict__ bn1b,
    const float* __restrict__ bn1m, const float* __restrict__ bn1v,
    const float* __restrict__ c2w, const float* __restrict__ c2b,
    const float* __restrict__ bn2g, const float* __restrict__ bn2b,
    const float* __restrict__ bn2m, const float* __restrict__ bn2v,
    float* __restrict__ A, int b0)
{
  __shared__ float melS[5 * 232];
  __shared__ float x1S[12 * 3 * 232];
  __shared__ float wS[48 * 12 * 9];
  const int tid = threadIdx.x;
  const int bl = blockIdx.x >> 9;
  const int b = b0 + bl;
  const int t = blockIdx.x & 511;

  for (int idx = tid; idx < 5 * 232; idx += 256) {
    int rr = idx / 232, cc = idx - rr * 232;
    int r = t - 2 + rr, w = cc - 1;
    float v = 0.f;
    if (r >= 0 && r < 512 && w >= 0 && w < 229) v = mel[(b * 512 + r) * 229 + w];
    melS[idx] = v;
  }

  float accA[22], accB[22];
#pragma unroll
  for (int i = 0; i < 22; ++i) { accA[i] = 0.f; accB[i] = 0.f; }
  __syncthreads();

  for (int icc = 0; icc < 4; ++icc) {
    if (icc) __syncthreads();
    for (int idx = tid; idx < 12 * 3 * 232; idx += 256) {
      int cl = idx / (3 * 232);
      int rem = idx - cl * (3 * 232);
      int rr = rem / 232, cc = rem - rr * 232;
      int c = icc * 12 + cl;
      int r1 = t - 1 + rr, w = cc - 1;
      float v = 0.f;
      if (r1 >= 0 && r1 < 512 && w >= 0 && w < 229) {
        const float* cw = c1w + c * 9;
        const float* m0 = melS + rr * 232 + cc - 1;
        float s = m0[0] * cw[0] + m0[1] * cw[1] + m0[2] * cw[2]
                + m0[232] * cw[3] + m0[233] * cw[4] + m0[234] * cw[5]
                + m0[464] * cw[6] + m0[465] * cw[7] + m0[466] * cw[8];
        s += c1b[c];
        float sc = bn1g[c] * rsqrtf(bn1v[c] + 1e-5f);
        v = fmaxf(s * sc + (bn1b[c] - bn1m[c] * sc), 0.f);
      }
      x1S[idx] = v;
    }
    for (int idx = tid; idx < 48 * 12 * 9; idx += 256) {
      int oc = idx / 108, rem = idx - oc * 108;
      wS[idx] = c2w[(oc * 48 + icc * 12) * 9 + rem];
    }
    __syncthreads();
    for (int i = 0; i < 22; ++i) {
      int oidx = tid + i * 256;
      if (oidx >= 5472) break;
      int oc = oidx / 114, wp = oidx - oc * 114;
      int w0 = 2 * wp;
      float a0 = accA[i], a1 = accB[i];
      const float* wp9 = wS + oc * 108;
      for (int icl = 0; icl < 12; ++icl) {
#pragma unroll
        for (int a = 0; a < 3; ++a) {
          const float* xr = x1S + (icl * 3 + a) * 232 + w0;
          float x0 = xr[0], x1 = xr[1], x2 = xr[2], x3 = xr[3];
          float wA = wp9[icl * 9 + a * 3 + 0];
          float wB = wp9[icl * 9 + a * 3 + 1];
          float wC = wp9[icl * 9 + a * 3 + 2];
          a0 = fmaf(x0, wA, a0); a0 = fmaf(x1, wB, a0); a0 = fmaf(x2, wC, a0);
          a1 = fmaf(x1, wA, a1); a1 = fmaf(x2, wB, a1); a1 = fmaf(x3, wC, a1);
        }
      }
      accA[i] = a0; accB[i] = a1;
    }
  }
  for (int i = 0; i < 22; ++i) {
    int oidx = tid + i * 256;
    if (oidx >= 5472) break;
    int oc = oidx / 114, wp = oidx - oc * 114;
    float sc = bn2g[oc] * rsqrtf(bn2v[oc] + 1e-5f);
    float sh = bn2b[oc] - bn2m[oc] * sc;
    float v0 = fmaxf((accA[i] + c2b[oc]) * sc + sh, 0.f);
    float v1 = fmaxf((accB[i] + c2b[oc]) * sc + sh, 0.f);
    A[((bl * 48 + oc) * 512 + t) * 114 + wp] = fmaxf(v0, v1);
  }
}

// ---------------------------------------------------------------------------
// K2: conv3+bn3+relu+pool(1,2); GEMM-ready output. (unchanged)
// ---------------------------------------------------------------------------
__global__ __launch_bounds__(256) void conv3_kernel(
    const float* __restrict__ A,
    const float* __restrict__ c3w, const float* __restrict__ c3b,
    const float* __restrict__ bn3g, const float* __restrict__ bn3b,
    const float* __restrict__ bn3m, const float* __restrict__ bn3v,
    float* __restrict__ Bf)
{
  __shared__ float aS[16 * 3 * 116];
  __shared__ float wS[48 * 16 * 9];
  const int tid = threadIdx.x;
  const int bl = blockIdx.x / 510;
  const int t = blockIdx.x - bl * 510;

  for (int ocg = 0; ocg < 2; ++ocg) {
    float accA[11], accB[11];
#pragma unroll
    for (int i = 0; i < 11; ++i) { accA[i] = 0.f; accB[i] = 0.f; }
    for (int icc = 0; icc < 3; ++icc) {
      __syncthreads();
      for (int idx = tid; idx < 16 * 3 * 116; idx += 256) {
        int cl = idx / 348, rem = idx - cl * 348;
        int rr = rem / 116, cc = rem - rr * 116;
        int w = cc - 1;
        float v = 0.f;
        if (w >= 0 && w < 114) v = A[((bl * 48 + icc * 16 + cl) * 512 + t + rr) * 114 + w];
        aS[idx] = v;
      }
      for (int idx = tid; idx < 48 * 16 * 9; idx += 256) {
        int ocl = idx / 144, rem = idx - ocl * 144;
        wS[idx] = c3w[((ocg * 48 + ocl) * 48 + icc * 16) * 9 + rem];
      }
      __syncthreads();
      for (int i = 0; i < 11; ++i) {
        int oidx = tid + i * 256;
        if (oidx >= 2736) break;
        int ocl = oidx / 57, wp = oidx - ocl * 57;
        int w0 = 2 * wp;
        float a0 = accA[i], a1 = accB[i];
        const float* wb = wS + ocl * 144;
        for (int icl = 0; icl < 16; ++icl) {
#pragma unroll
          for (int a = 0; a < 3; ++a) {
            const float* xr = aS + (icl * 3 + a) * 116 + w0;
            float x0 = xr[0], x1 = xr[1], x2 = xr[2], x3 = xr[3];
            float wA = wb[icl * 9 + a * 3 + 0];
            float wB = wb[icl * 9 + a * 3 + 1];
            float wC = wb[icl * 9 + a * 3 + 2];
            a0 = fmaf(x0, wA, a0); a0 = fmaf(x1, wB, a0); a0 = fmaf(x2, wC, a0);
            a1 = fmaf(x1, wA, a1); a1 = fmaf(x2, wB, a1); a1 = fmaf(x3, wC, a1);
          }
        }
        accA[i] = a0; accB[i] = a1;
      }
    }
    for (int i = 0; i < 11; ++i) {
      int oidx = tid + i * 256;
      if (oidx >= 2736) break;
      int ocl = oidx / 57, wp = oidx - ocl * 57;
      int oc = ocg * 48 + ocl;
      float sc = bn3g[oc] * rsqrtf(bn3v[oc] + 1e-5f);
      float sh = bn3b[oc] - bn3m[oc] * sc;
      float v0 = fmaxf((accA[i] + c3b[oc]) * sc + sh, 0.f);
      float v1 = fmaxf((accB[i] + c3b[oc]) * sc + sh, 0.f);
      Bf[(size_t)(bl * 510 + t) * 5472 + oc * 57 + wp] = fmaxf(v0, v1);
    }
  }
}

// ---------------------------------------------------------------------------
// K3: fp32 NT GEMM  C = A * B^T + bias, output relaid to [t][16][768].
// ---------------------------------------------------------------------------
__global__ __launch_bounds__(256) void gemm_nt(
    const float* __restrict__ Am, const float* __restrict__ Bm,
    const float* __restrict__ bias, float* __restrict__ C,
    int M, int K, int lda, int ldb, int b0)
{
  __shared__ float As[64 * 33];
  __shared__ float Bs[64 * 33];
  const int tid = threadIdx.x;
  const int m0 = blockIdx.x * 64, n0 = blockIdx.y * 64;
  const int tx = tid & 15, ty = tid >> 4;
  const int kq = (tid & 7) * 4, rw = tid >> 3;
  float acc[4][4];
#pragma unroll
  for (int i = 0; i < 4; ++i)
#pragma unroll
    for (int j = 0; j < 4; ++j) acc[i][j] = 0.f;

  for (int k0 = 0; k0 < K; k0 += 32) {
    int m1 = m0 + rw, m2 = m1 + 32;
    float4 va = make_float4(0.f, 0.f, 0.f, 0.f), vb = va;
    if (m1 < M) va = *(const float4*)(Am + (size_t)m1 * lda + k0 + kq);
    if (m2 < M) vb = *(const float4*)(Am + (size_t)m2 * lda + k0 + kq);
    float4 wa = *(const float4*)(Bm + (size_t)(n0 + rw) * ldb + k0 + kq);
    float4 wb = *(const float4*)(Bm + (size_t)(n0 + rw + 32) * ldb + k0 + kq);
    As[rw * 33 + kq + 0] = va.x; As[rw * 33 + kq + 1] = va.y;
    As[rw * 33 + kq + 2] = va.z; As[rw * 33 + kq + 3] = va.w;
    As[(rw + 32) * 33 + kq + 0] = vb.x; As[(rw + 32) * 33 + kq + 1] = vb.y;
    As[(rw + 32) * 33 + kq + 2] = vb.z; As[(rw + 32) * 33 + kq + 3] = vb.w;
    Bs[rw * 33 + kq + 0] = wa.x; Bs[rw * 33 + kq + 1] = wa.y;
    Bs[rw * 33 + kq + 2] = wa.z; Bs[rw * 33 + kq + 3] = wa.w;
    Bs[(rw + 32) * 33 + kq + 0] = wb.x; Bs[(rw + 32) * 33 + kq + 1] = wb.y;
    Bs[(rw + 32) * 33 + kq + 2] = wb.z; Bs[(rw + 32) * 33 + kq + 3] = wb.w;
    __syncthreads();
#pragma unroll 8
    for (int k = 0; k < 32; ++k) {
      float av[4], bv[4];
#pragma unroll
      for (int i = 0; i < 4; ++i) av[i] = As[(ty * 4 + i) * 33 + k];
#pragma unroll
      for (int j = 0; j < 4; ++j) bv[j] = Bs[(tx * 4 + j) * 33 + k];
#pragma unroll
      for (int i = 0; i < 4; ++i)
#pragma unroll
        for (int j = 0; j < 4; ++j) acc[i][j] = fmaf(av[i], bv[j], acc[i][j]);
    }
    __syncthreads();
  }
#pragma unroll
  for (int i = 0; i < 4; ++i) {
    int m = m0 + ty * 4 + i;
    if (m >= M) continue;
    int bl2 = m / 510, tt2 = m - bl2 * 510;           // local batch, time
    float* crow = C + ((size_t)tt2 * 16 + (b0 + bl2)) * 768;
#pragma unroll
    for (int j = 0; j < 4; ++j) {
      int n = n0 + tx * 4 + j;
      crow[n] = acc[i][j] + bias[n];
    }
  }
}

// ---------------------------------------------------------------------------
__global__ void init_state(ull* __restrict__ h1g, ull* __restrict__ h2g,
                           ull* __restrict__ prevg, unsigned* __restrict__ bar) {
  int gid = blockIdx.x * 256 + threadIdx.x;
  if (gid < 12288) { at_store(h1g + gid, 0ull); at_store(h2g + gid, 0ull); }
  if (gid < 2816) at_store(prevg + gid, 0ull);
  if (gid < 1024)
    __hip_atomic_store(bar + gid, 0u, __ATOMIC_RELAXED, __HIP_MEMORY_SCOPE_AGENT);
}

// ---------------------------------------------------------------------------
// K6: persistent LSTM, coalesced chunked-layout state exchange, 2 h-buffers.
// h1g/h2g layout: [2 parity][16 s][16 r][24 ull]  (ull idx = s*384+r*24+q,
// floats = h[batch r][dim 48s+2q .. +1]).
// ---------------------------------------------------------------------------
__global__ __launch_bounds__(256, 1) void lstm_kernel(
    const float* __restrict__ aco,   // [510][16][768]
    const float* __restrict__ whh0,  // [3072][768]
    const float* __restrict__ wih0,  // [3072][944]
    const float* __restrict__ wih1,  // [3072][768]
    const float* __restrict__ whh1,  // [3072][768]
    const float* __restrict__ bih0, const float* __restrict__ bhh0,
    const float* __restrict__ bih1, const float* __restrict__ bhh1,
    const float* __restrict__ pw,    // [440][768]
    const float* __restrict__ pb,
    const float* __restrict__ emb,   // [5][2]
    ull* __restrict__ h1g,           // [2][6144] chunked
    ull* __restrict__ h2g,
    ull* __restrict__ prevg,         // [2][16][88] packed emb pairs
    unsigned* __restrict__ bar,
    float* __restrict__ out)         // [16][510][440]
{
  __shared__ float bufA[16 * 772];   // x(t) -> h2(t-1) -> h2(t)[proj]
  __shared__ float bufB[16 * 772];   // h1 (persists across step boundary)
  __shared__ float prevs[16 * 177];
  __shared__ float zl[16 * 17];
  __shared__ float harr[64];
  __shared__ float embS[10];
  const int tid = threadIdx.x;
  const int s = tid & 15;            // k-chunk
  const int r = tid >> 4;            // gate-row (dots)
  const int uB = blockIdx.x * 4;
  const int j = (r >> 2) * 768 + uB + (r & 3);

  // ---- one-time register weight load ----
  float wx[48], w0[48], w1[48], w2[48], wp[11], pwr[48];
  {
    const float* p = wih0 + (size_t)j * 944 + 48 * s;
#pragma unroll
    for (int i = 0; i < 48; i += 4) {
      float4 v = *(const float4*)(p + i);
      wx[i] = v.x; wx[i+1] = v.y; wx[i+2] = v.z; wx[i+3] = v.w;
    }
    p = whh0 + (size_t)j * 768 + 48 * s;
#pragma unroll
    for (int i = 0; i < 48; i += 4) {
      float4 v = *(const float4*)(p + i);
      w0[i] = v.x; w0[i+1] = v.y; w0[i+2] = v.z; w0[i+3] = v.w;
    }
    p = wih1 + (size_t)j * 768 + 48 * s;
#pragma unroll
    for (int i = 0; i < 48; i += 4) {
      float4 v = *(const float4*)(p + i);
      w1[i] = v.x; w1[i+1] = v.y; w1[i+2] = v.z; w1[i+3] = v.w;
    }
    p = whh1 + (size_t)j * 768 + 48 * s;
#pragma unroll
    for (int i = 0; i < 48; i += 4) {
      float4 v = *(const float4*)(p + i);
      w2[i] = v.x; w2[i+1] = v.y; w2[i+2] = v.z; w2[i+3] = v.w;
    }
    const float* pp = wih0 + (size_t)j * 944 + 768 + 11 * s;
#pragma unroll
    for (int i = 0; i < 11; ++i) wp[i] = pp[i];
  }
  const bool pv = (blockIdx.x < 88) && (r < 5);
  const int prow = blockIdx.x * 5 + r;
  float pbv = 0.f;
  if (pv) {
    const float* p = pw + (size_t)prow * 768 + 48 * s;
#pragma unroll
    for (int i = 0; i < 48; i += 4) {
      float4 v = *(const float4*)(p + i);
      pwr[i] = v.x; pwr[i+1] = v.y; pwr[i+2] = v.z; pwr[i+3] = v.w;
    }
    pbv = pb[prow];
  } else {
#pragma unroll
    for (int i = 0; i < 48; ++i) pwr[i] = 0.f;
  }
  // cell-thread constants
  float bl1[4], bl2[4], c1 = 0.f, c2 = 0.f;
  if (tid < 64) {
    int ul = tid >> 4;
#pragma unroll
    for (int g = 0; g < 4; ++g) {
      int jj = g * 768 + uB + ul;
      bl1[g] = bih0[jj] + bhh0[jj];
      bl2[g] = bih1[jj] + bhh1[jj];
    }
  }
  if (tid < 10) embS[tid] = emb[tid];

  // ---- precomputed LDS scatter offsets for coalesced staging ----
  int offH[24];
#pragma unroll
  for (int q = 0; q < 24; ++q) {
    int G = q * 256 + tid;               // ull index in [0,6144)
    int s2 = G / 384, rem = G - s2 * 384;
    int r2 = rem / 24, q2 = rem - r2 * 24;
    offH[q] = s2 * 772 + r2 * 48 + 2 * q2;  // float offset (8B aligned)
  }
  int offX[12];
#pragma unroll
  for (int q = 0; q < 12; ++q) {
    int F4 = q * 256 + tid;              // float4 index in [0,3072)
    int b2 = F4 / 192, rem = F4 - b2 * 192;
    int s2 = rem / 12;
    offX[q] = s2 * 772 + b2 * 48 + (rem - s2 * 12) * 4;  // 16B aligned
  }
  int offP[11];
#pragma unroll
  for (int q = 0; q < 11; ++q) {
    int F = q * 256 + tid;               // float index in [0,2816)
    int b2 = F / 176, d = F - b2 * 176;
    int s2 = d / 11;
    offP[q] = s2 * 177 + b2 * 11 + (d - s2 * 11);
  }
  // producer store base: block owns dims 4*blk..4*blk+3
  const int hdst = (blockIdx.x / 12) * 384 + (blockIdx.x % 12) * 2;

  // bufB must hold h1(-1) = 0 at t=0
  for (int i = tid; i < 16 * 772; i += 256) bufB[i] = 0.f;

  unsigned nb = 0;
  const unsigned NG = gridDim.x;

  for (int t = 0; t < 510; ++t) {
    const int wbuf = t & 1, rbuf = wbuf ^ 1;
    // ===== PH1a: coalesced x(t) stage -> bufA, x-dot (overlaps proj PH3) ===
    {
      const float4* xb = (const float4*)(aco + (size_t)t * 12288);
#pragma unroll
      for (int q = 0; q < 12; ++q)
        *(float4*)(bufA + offX[q]) = xb[q * 256 + tid];
    }
    __syncthreads();
#pragma unroll 4
    for (int b = 0; b < 16; ++b) {
      float p; CDOT48(wx, bufA + s * 772 + b * 48, p);
      p = red16(p);
      if (s == 0) zl[r * 17 + b] = p;
    }
    if (tid == 0 && t) pwait(bar, 88u * (unsigned)t);
    __syncthreads();
    // ===== PH1b: coalesced prev stage; recurrent dot from persistent bufB ==
    if (t == 0) {
#pragma unroll
      for (int q = 0; q < 11; ++q) prevs[offP[q]] = 0.f;
    } else {
      const float* pg = (const float*)(prevg + rbuf * 1408);
#pragma unroll
      for (int q = 0; q < 11; ++q)
        prevs[offP[q]] = at_loadf(pg + q * 256 + tid);
    }
    __syncthreads();
#pragma unroll 4
    for (int b = 0; b < 16; ++b) {
      float p; CDOT48(w0, bufB + s * 772 + b * 48, p);
      const float* pvv = prevs + s * 177 + b * 11;
#pragma unroll
      for (int i = 0; i < 11; ++i) p = fmaf(wp[i], pvv[i], p);
      p = red16(p);
      if (s == 0) zl[r * 17 + b] += p;
    }
    __syncthreads();
    if (tid < 64) {
      int ul = tid >> 4, bb = tid & 15;
      float zi = zl[(0 * 4 + ul) * 17 + bb] + bl1[0];
      float zf = zl[(1 * 4 + ul) * 17 + bb] + bl1[1];
      float zg = zl[(2 * 4 + ul) * 17 + bb] + bl1[2];
      float zo = zl[(3 * 4 + ul) * 17 + bb] + bl1[3];
      c1 = sigf(zf) * c1 + sigf(zi) * tanhf(zg);
      harr[tid] = sigf(zo) * tanhf(c1);
    }
    __syncthreads();
    if (tid < 32) {
      int q = tid >> 4, bb = tid & 15;
      at_store(h1g + wbuf * 6144 + hdst + bb * 24 + q,
               pack2(harr[(2 * q) * 16 + bb], harr[(2 * q + 1) * 16 + bb]));
    }
    ++nb; gbar(bar, nb, NG);           // barrier A: h1(t) visible
    // ===== PH2: both stages issued back-to-back, fused w1/w2 dot ===========
    STAGE_HC(h1g + wbuf * 6144, bufB);   // h1(t), persists into step t+1
    STAGE_HC(h2g + rbuf * 6144, bufA);   // h2(t-1)
    __syncthreads();
#pragma unroll 2
    for (int b = 0; b < 16; ++b) {
      float p1, p2;
      CDOT48(w1, bufB + s * 772 + b * 48, p1);
      CDOT48(w2, bufA + s * 772 + b * 48, p2);
      float p = red16(p1 + p2);
      if (s == 0) zl[r * 17 + b] = p;
    }
    __syncthreads();
    if (tid < 64) {
      int ul = tid >> 4, bb = tid & 15;
      float zi = zl[(0 * 4 + ul) * 17 + bb] + bl2[0];
      float zf = zl[(1 * 4 + ul) * 17 + bb] + bl2[1];
      float zg = zl[(2 * 4 + ul) * 17 + bb] + bl2[2];
      float zo = zl[(3 * 4 + ul) * 17 + bb] + bl2[3];
      c2 = sigf(zf) * c2 + sigf(zi) * tanhf(zg);
      harr[tid] = sigf(zo) * tanhf(c2);
    }
    __syncthreads();
    if (tid < 32) {
      int q = tid >> 4, bb = tid & 15;
      at_store(h2g + wbuf * 6144 + hdst + bb * 24 + q,
               pack2(harr[(2 * q) * 16 + bb], harr[(2 * q + 1) * 16 + bb]));
    }
    ++nb; gbar(bar, nb, NG);           // barrier B: h2(t) visible
    // ===== PH3: projection + argmax (blocks < 88), no grid barrier =========
    if (blockIdx.x < 88) {
      STAGE_HC(h2g + wbuf * 6144, bufA);
      __syncthreads();
#pragma unroll 4
      for (int b = 0; b < 16; ++b) {
        float p; CDOT48(pwr, bufA + s * 772 + b * 48, p);
        p = red16(p);
        if (pv && s == 0) {
          float lg = p + pbv;
          out[((size_t)b * 510 + t) * 440 + prow] = lg;
          zl[r * 17 + b] = lg;
        }
      }
      __syncthreads();
      if (tid < 16) {
        float best = zl[0 * 17 + tid]; int bi = 0;
#pragma unroll
        for (int c = 1; c < 5; ++c) {
          float v = zl[c * 17 + tid];
          if (v > best) { best = v; bi = c; }
        }
        at_store(prevg + wbuf * 1408 + tid * 88 + blockIdx.x,
                 pack2(embS[bi * 2], embS[bi * 2 + 1]));
      }
      if (tid == 0) {
        __builtin_amdgcn_s_waitcnt(0);
        __atomic_signal_fence(__ATOMIC_SEQ_CST);
        __hip_atomic_fetch_add(bar + 512 + (blockIdx.x & 7) * 16, 1u,
                               __ATOMIC_RELAXED, __HIP_MEMORY_SCOPE_AGENT);
      }
    }
  }
}

// ---------------------------------------------------------------------------
extern "C" void kernel_launch(void* const* d_in, const int* in_sizes, int n_in,
                              void* d_out, int out_size, void* d_ws, size_t ws_size,
                              hipStream_t stream) {
  (void)in_sizes; (void)n_in; (void)out_size;
  const float* mel  = (const float*)d_in[0];
  const float* c1w  = (const float*)d_in[1];
  const float* c1b  = (const float*)d_in[2];
  const float* c2w  = (const float*)d_in[3];
  const float* c2b  = (const float*)d_in[4];
  const float* c3w  = (const float*)d_in[5];
  const float* c3b  = (const float*)d_in[6];
  const float* bn1g = (const float*)d_in[7];
  const float* bn1b = (const float*)d_in[8];
  const float* bn1m = (const float*)d_in[9];
  const float* bn1v = (const float*)d_in[10];
  const float* bn2g = (const float*)d_in[11];
  const float* bn2b = (const float*)d_in[12];
  const float* bn2m = (const float*)d_in[13];
  const float* bn2v = (const float*)d_in[14];
  const float* bn3g = (const float*)d_in[15];
  const float* bn3b = (const float*)d_in[16];
  const float* bn3m = (const float*)d_in[17];
  const float* bn3v = (const float*)d_in[18];
  const float* fcw  = (const float*)d_in[19];
  const float* fcb  = (const float*)d_in[20];
  const float* wih0 = (const float*)d_in[21];
  const float* whh0 = (const float*)d_in[22];
  const float* bih0 = (const float*)d_in[23];
  const float* bhh0 = (const float*)d_in[24];
  const float* wih1 = (const float*)d_in[25];
  const float* whh1 = (const float*)d_in[26];
  const float* bih1 = (const float*)d_in[27];
  const float* bhh1 = (const float*)d_in[28];
  const float* pw   = (const float*)d_in[29];
  const float* pb   = (const float*)d_in[30];
  const float* emb  = (const float*)d_in[31];

  float* ws = (float*)d_ws;
  float* outp = (float*)d_out;

  const size_t ST_ULL = 12288ull + 12288ull + 2816ull;
  int CB = 1;
  for (int cb = 4; cb >= 1; cb >>= 1) {
    size_t need = (ACO_FL + (size_t)cb * 48 * 512 * 114 + (size_t)cb * 510 * 5472) * 4
                + ST_ULL * 8 + 4096 + 1024;
    if (ws_size >= need) { CB = cb; break; }
  }
  const int nchunks = 16 / CB;
  const size_t A_FL  = (size_t)CB * 48 * 512 * 114;
  const size_t BF_FL = (size_t)CB * 510 * 5472;

  float* aco = ws;                       // [510][16][768]
  float* Ac  = ws + ACO_FL;
  float* Bfc = Ac + A_FL;
  ull* h1g   = (ull*)(Bfc + BF_FL);
  ull* h2g   = h1g + 12288;
  ull* prevg = h2g + 12288;
  unsigned* bar = (unsigned*)(prevg + 2816);

  for (int ch = 0; ch < nchunks; ++ch) {
    int b0 = ch * CB;
    hipLaunchKernelGGL(conv12_kernel, dim3(CB * 512), dim3(256), 0, stream,
                       mel, c1w, c1b, bn1g, bn1b, bn1m, bn1v,
                       c2w, c2b, bn2g, bn2b, bn2m, bn2v, Ac, b0);
    hipLaunchKernelGGL(conv3_kernel, dim3(CB * 510), dim3(256), 0, stream,
                       Ac, c3w, c3b, bn3g, bn3b, bn3m, bn3v, Bfc);
    int M = CB * 510;
    hipLaunchKernelGGL(gemm_nt, dim3((M + 63) / 64, 12), dim3(256), 0, stream,
                       Bfc, fcw, fcb, aco, M, 5472, 5472, 5472, b0);
  }
  hipLaunchKernelGGL(init_state, dim3(48), dim3(256), 0, stream,
                     h1g, h2g, prevg, bar);

  {
    void* args[] = {
      (void*)&aco, (void*)&whh0, (void*)&wih0, (void*)&wih1, (void*)&whh1,
      (void*)&bih0, (void*)&bhh0, (void*)&bih1, (void*)&bhh1,
      (void*)&pw, (void*)&pb, (void*)&emb,
      (void*)&h1g, (void*)&h2g, (void*)&prevg, (void*)&bar, (void*)&outp
    };
    hipError_t e = hipLaunchCooperativeKernel((const void*)lstm_kernel,
                                              dim3(192), dim3(256), args, 0, stream);
    if (e != hipSuccess) {
      (void)hipGetLastError();
      hipLaunchKernelGGL(lstm_kernel, dim3(192), dim3(256), 0, stream,
                         aco, whh0, wih0, wih1, whh1, bih0, bhh0, bih1, bhh1,
                         pw, pb, emb, h1g, h2g, prevg, bar, outp);
    }
  }
}

// Round 3
// 34763.730 us; speedup vs baseline: 1.1769x; 1.0393x over previous
//
#include <hip/hip_runtime.h>
#include <math.h>

// ============================================================================
// AR_Transcriber round 8.
// r7 (coalesced state exchange) gave the first real win (33.1->28.9 ms steady
// lstm). Remaining ~45 us/step = serial chain of cross-XCD round trips:
// 2x master-mediated grid barriers (~4 RT each) + stages. This round:
//  1. gbar deleted. Producers publish per-block step-tagged flags (192 lines);
//     consumers poll all 192 flags directly (1 flag/thread, private spin).
//     Removes master-detect + release hops.
//  2. Happens-before analysis: f1(t) (h1 publish) implies PH2(t-1)/PH3(t-1)
//     complete everywhere -> non-proj blocks need ONE flag-wait per step.
//     f2-wait (h2) only for the 88 projection blocks, which run decoupled.
//  3. x-dot of step t+1 software-pipelined into the f1-wait window (zx in
//     registers; red16 leaves the sum in all 16 lanes).
//  4. Buffer hazards re-verified under the <=1-step skew bound: h1/h2/prev
//     stay double-buffered; pwait counter machinery unchanged.
// Conv kernels / GEMM / register-resident weights unchanged from r7.
// ============================================================================

typedef unsigned long long ull;

#define ACO_FL 6266880ull  // 510*16*768
#define F1_OFF 0           // 192 flags * 16 u32 stride
#define F2_OFF 3072
#define PC_OFF 6144        // 8 prev counters * 16 u32 stride
#define BAR_U32 8192

__device__ __forceinline__ float sigf(float x) { return 1.0f / (1.0f + expf(-x)); }

__device__ __forceinline__ ull pack2(float x, float y) {
  union { float f[2]; ull u; } c; c.f[0] = x; c.f[1] = y; return c.u;
}
__device__ __forceinline__ float2 unpack2(ull u) {
  union { ull u; float2 v; } c; c.u = u; return c.v;
}
__device__ __forceinline__ ull at_load(const ull* p) {
  return __hip_atomic_load((ull*)p, __ATOMIC_RELAXED, __HIP_MEMORY_SCOPE_AGENT);
}
__device__ __forceinline__ float at_loadf(const float* p) {
  return __hip_atomic_load((float*)p, __ATOMIC_RELAXED, __HIP_MEMORY_SCOPE_AGENT);
}
__device__ __forceinline__ void at_store(ull* p, ull v) {
  __hip_atomic_store(p, v, __ATOMIC_RELAXED, __HIP_MEMORY_SCOPE_AGENT);
}

// Per-producer flag wait: thread tid<192 spins on producer tid's flag line.
__device__ __forceinline__ void wait_flags(const unsigned* f, unsigned tgt, int tid) {
  if (tid < 192) {
    const unsigned* fp = f + tid * 16;
    while (__hip_atomic_load((unsigned*)fp, __ATOMIC_RELAXED,
                             __HIP_MEMORY_SCOPE_AGENT) < tgt)
      __builtin_amdgcn_s_sleep(2);
  }
  __atomic_signal_fence(__ATOMIC_SEQ_CST);
  __syncthreads();
}

__device__ __forceinline__ void pwait(const unsigned* pc, unsigned target) {
  for (;;) {
    unsigned s0 = 0;
#pragma unroll
    for (int i = 0; i < 8; ++i)
      s0 += __hip_atomic_load((unsigned*)(pc + i * 16), __ATOMIC_RELAXED,
                              __HIP_MEMORY_SCOPE_AGENT);
    if (s0 >= target) break;
    __builtin_amdgcn_s_sleep(2);
  }
  __atomic_signal_fence(__ATOMIC_SEQ_CST);
}

__device__ __forceinline__ float red16(float v) {
  v += __shfl_xor(v, 1, 16);
  v += __shfl_xor(v, 2, 16);
  v += __shfl_xor(v, 4, 16);
  v += __shfl_xor(v, 8, 16);
  return v;
}

// 48-FMA chunk dot: weights from VGPR array W, data from LDS pointer PTR.
#define CDOT48(W, PTR, RES) do {                                              \
  const float* _p = (PTR);                                                    \
  float _a0 = 0.f, _a1 = 0.f, _a2 = 0.f, _a3 = 0.f;                           \
  _Pragma("unroll")                                                           \
  for (int _i = 0; _i < 48; _i += 16) {                                       \
    float4 _v0 = *(const float4*)(_p + _i);                                   \
    float4 _v1 = *(const float4*)(_p + _i + 4);                               \
    float4 _v2 = *(const float4*)(_p + _i + 8);                               \
    float4 _v3 = *(const float4*)(_p + _i + 12);                              \
    _a0 = fmaf((W)[_i + 0], _v0.x, _a0); _a0 = fmaf((W)[_i + 1], _v0.y, _a0); \
    _a0 = fmaf((W)[_i + 2], _v0.z, _a0); _a0 = fmaf((W)[_i + 3], _v0.w, _a0); \
    _a1 = fmaf((W)[_i + 4], _v1.x, _a1); _a1 = fmaf((W)[_i + 5], _v1.y, _a1); \
    _a1 = fmaf((W)[_i + 6], _v1.z, _a1); _a1 = fmaf((W)[_i + 7], _v1.w, _a1); \
    _a2 = fmaf((W)[_i + 8], _v2.x, _a2); _a2 = fmaf((W)[_i + 9], _v2.y, _a2); \
    _a2 = fmaf((W)[_i +10], _v2.z, _a2); _a2 = fmaf((W)[_i +11], _v2.w, _a2); \
    _a3 = fmaf((W)[_i +12], _v3.x, _a3); _a3 = fmaf((W)[_i +13], _v3.y, _a3); \
    _a3 = fmaf((W)[_i +14], _v3.z, _a3); _a3 = fmaf((W)[_i +15], _v3.w, _a3); \
  }                                                                           \
  RES = (_a0 + _a1) + (_a2 + _a3);                                            \
} while (0)

// Coalesced h stage: global chunked layout -> LDS via precomputed offH.
#define STAGE_HC(SRC, DST) do {                                               \
  _Pragma("unroll")                                                           \
  for (int _q = 0; _q < 24; ++_q) {                                           \
    ull _v = at_load((SRC) + _q * 256 + tid);                                 \
    *(float2*)((DST) + offH[_q]) = unpack2(_v);                               \
  }                                                                           \
} while (0)

// ---------------------------------------------------------------------------
// K1: fused conv1+bn1+relu -> conv2+bn2+relu -> pool(1,2). (unchanged)
// ---------------------------------------------------------------------------
__global__ __launch_bounds__(256) void conv12_kernel(
    const float* __restrict__ mel,
    const float* __restrict__ c1w, const float* __restrict__ c1b,
    const float* __restrict__ bn1g, const float* __restrict__ bn1b,
    const float* __restrict__ bn1m, const float* __restrict__ bn1v,
    const float* __restrict__ c2w, const float* __restrict__ c2b,
    const float* __restrict__ bn2g, const float* __restrict__ bn2b,
    const float* __restrict__ bn2m, const float* __restrict__ bn2v,
    float* __restrict__ A, int b0)
{
  __shared__ float melS[5 * 232];
  __shared__ float x1S[12 * 3 * 232];
  __shared__ float wS[48 * 12 * 9];
  const int tid = threadIdx.x;
  const int bl = blockIdx.x >> 9;
  const int b = b0 + bl;
  const int t = blockIdx.x & 511;

  for (int idx = tid; idx < 5 * 232; idx += 256) {
    int rr = idx / 232, cc = idx - rr * 232;
    int r = t - 2 + rr, w = cc - 1;
    float v = 0.f;
    if (r >= 0 && r < 512 && w >= 0 && w < 229) v = mel[(b * 512 + r) * 229 + w];
    melS[idx] = v;
  }

  float accA[22], accB[22];
#pragma unroll
  for (int i = 0; i < 22; ++i) { accA[i] = 0.f; accB[i] = 0.f; }
  __syncthreads();

  for (int icc = 0; icc < 4; ++icc) {
    if (icc) __syncthreads();
    for (int idx = tid; idx < 12 * 3 * 232; idx += 256) {
      int cl = idx / (3 * 232);
      int rem = idx - cl * (3 * 232);
      int rr = rem / 232, cc = rem - rr * 232;
      int c = icc * 12 + cl;
      int r1 = t - 1 + rr, w = cc - 1;
      float v = 0.f;
      if (r1 >= 0 && r1 < 512 && w >= 0 && w < 229) {
        const float* cw = c1w + c * 9;
        const float* m0 = melS + rr * 232 + cc - 1;
        float s = m0[0] * cw[0] + m0[1] * cw[1] + m0[2] * cw[2]
                + m0[232] * cw[3] + m0[233] * cw[4] + m0[234] * cw[5]
                + m0[464] * cw[6] + m0[465] * cw[7] + m0[466] * cw[8];
        s += c1b[c];
        float sc = bn1g[c] * rsqrtf(bn1v[c] + 1e-5f);
        v = fmaxf(s * sc + (bn1b[c] - bn1m[c] * sc), 0.f);
      }
      x1S[idx] = v;
    }
    for (int idx = tid; idx < 48 * 12 * 9; idx += 256) {
      int oc = idx / 108, rem = idx - oc * 108;
      wS[idx] = c2w[(oc * 48 + icc * 12) * 9 + rem];
    }
    __syncthreads();
    for (int i = 0; i < 22; ++i) {
      int oidx = tid + i * 256;
      if (oidx >= 5472) break;
      int oc = oidx / 114, wp = oidx - oc * 114;
      int w0 = 2 * wp;
      float a0 = accA[i], a1 = accB[i];
      const float* wp9 = wS + oc * 108;
      for (int icl = 0; icl < 12; ++icl) {
#pragma unroll
        for (int a = 0; a < 3; ++a) {
          const float* xr = x1S + (icl * 3 + a) * 232 + w0;
          float x0 = xr[0], x1 = xr[1], x2 = xr[2], x3 = xr[3];
          float wA = wp9[icl * 9 + a * 3 + 0];
          float wB = wp9[icl * 9 + a * 3 + 1];
          float wC = wp9[icl * 9 + a * 3 + 2];
          a0 = fmaf(x0, wA, a0); a0 = fmaf(x1, wB, a0); a0 = fmaf(x2, wC, a0);
          a1 = fmaf(x1, wA, a1); a1 = fmaf(x2, wB, a1); a1 = fmaf(x3, wC, a1);
        }
      }
      accA[i] = a0; accB[i] = a1;
    }
  }
  for (int i = 0; i < 22; ++i) {
    int oidx = tid + i * 256;
    if (oidx >= 5472) break;
    int oc = oidx / 114, wp = oidx - oc * 114;
    float sc = bn2g[oc] * rsqrtf(bn2v[oc] + 1e-5f);
    float sh = bn2b[oc] - bn2m[oc] * sc;
    float v0 = fmaxf((accA[i] + c2b[oc]) * sc + sh, 0.f);
    float v1 = fmaxf((accB[i] + c2b[oc]) * sc + sh, 0.f);
    A[((bl * 48 + oc) * 512 + t) * 114 + wp] = fmaxf(v0, v1);
  }
}

// ---------------------------------------------------------------------------
// K2: conv3+bn3+relu+pool(1,2); GEMM-ready output. (unchanged)
// ---------------------------------------------------------------------------
__global__ __launch_bounds__(256) void conv3_kernel(
    const float* __restrict__ A,
    const float* __restrict__ c3w, const float* __restrict__ c3b,
    const float* __restrict__ bn3g, const float* __restrict__ bn3b,
    const float* __restrict__ bn3m, const float* __restrict__ bn3v,
    float* __restrict__ Bf)
{
  __shared__ float aS[16 * 3 * 116];
  __shared__ float wS[48 * 16 * 9];
  const int tid = threadIdx.x;
  const int bl = blockIdx.x / 510;
  const int t = blockIdx.x - bl * 510;

  for (int ocg = 0; ocg < 2; ++ocg) {
    float accA[11], accB[11];
#pragma unroll
    for (int i = 0; i < 11; ++i) { accA[i] = 0.f; accB[i] = 0.f; }
    for (int icc = 0; icc < 3; ++icc) {
      __syncthreads();
      for (int idx = tid; idx < 16 * 3 * 116; idx += 256) {
        int cl = idx / 348, rem = idx - cl * 348;
        int rr = rem / 116, cc = rem - rr * 116;
        int w = cc - 1;
        float v = 0.f;
        if (w >= 0 && w < 114) v = A[((bl * 48 + icc * 16 + cl) * 512 + t + rr) * 114 + w];
        aS[idx] = v;
      }
      for (int idx = tid; idx < 48 * 16 * 9; idx += 256) {
        int ocl = idx / 144, rem = idx - ocl * 144;
        wS[idx] = c3w[((ocg * 48 + ocl) * 48 + icc * 16) * 9 + rem];
      }
      __syncthreads();
      for (int i = 0; i < 11; ++i) {
        int oidx = tid + i * 256;
        if (oidx >= 2736) break;
        int ocl = oidx / 57, wp = oidx - ocl * 57;
        int w0 = 2 * wp;
        float a0 = accA[i], a1 = accB[i];
        const float* wb = wS + ocl * 144;
        for (int icl = 0; icl < 16; ++icl) {
#pragma unroll
          for (int a = 0; a < 3; ++a) {
            const float* xr = aS + (icl * 3 + a) * 116 + w0;
            float x0 = xr[0], x1 = xr[1], x2 = xr[2], x3 = xr[3];
            float wA = wb[icl * 9 + a * 3 + 0];
            float wB = wb[icl * 9 + a * 3 + 1];
            float wC = wb[icl * 9 + a * 3 + 2];
            a0 = fmaf(x0, wA, a0); a0 = fmaf(x1, wB, a0); a0 = fmaf(x2, wC, a0);
            a1 = fmaf(x1, wA, a1); a1 = fmaf(x2, wB, a1); a1 = fmaf(x3, wC, a1);
          }
        }
        accA[i] = a0; accB[i] = a1;
      }
    }
    for (int i = 0; i < 11; ++i) {
      int oidx = tid + i * 256;
      if (oidx >= 2736) break;
      int ocl = oidx / 57, wp = oidx - ocl * 57;
      int oc = ocg * 48 + ocl;
      float sc = bn3g[oc] * rsqrtf(bn3v[oc] + 1e-5f);
      float sh = bn3b[oc] - bn3m[oc] * sc;
      float v0 = fmaxf((accA[i] + c3b[oc]) * sc + sh, 0.f);
      float v1 = fmaxf((accB[i] + c3b[oc]) * sc + sh, 0.f);
      Bf[(size_t)(bl * 510 + t) * 5472 + oc * 57 + wp] = fmaxf(v0, v1);
    }
  }
}

// ---------------------------------------------------------------------------
// K3: fp32 NT GEMM  C = A * B^T + bias, output relaid to [t][16][768].
// ---------------------------------------------------------------------------
__global__ __launch_bounds__(256) void gemm_nt(
    const float* __restrict__ Am, const float* __restrict__ Bm,
    const float* __restrict__ bias, float* __restrict__ C,
    int M, int K, int lda, int ldb, int b0)
{
  __shared__ float As[64 * 33];
  __shared__ float Bs[64 * 33];
  const int tid = threadIdx.x;
  const int m0 = blockIdx.x * 64, n0 = blockIdx.y * 64;
  const int tx = tid & 15, ty = tid >> 4;
  const int kq = (tid & 7) * 4, rw = tid >> 3;
  float acc[4][4];
#pragma unroll
  for (int i = 0; i < 4; ++i)
#pragma unroll
    for (int j = 0; j < 4; ++j) acc[i][j] = 0.f;

  for (int k0 = 0; k0 < K; k0 += 32) {
    int m1 = m0 + rw, m2 = m1 + 32;
    float4 va = make_float4(0.f, 0.f, 0.f, 0.f), vb = va;
    if (m1 < M) va = *(const float4*)(Am + (size_t)m1 * lda + k0 + kq);
    if (m2 < M) vb = *(const float4*)(Am + (size_t)m2 * lda + k0 + kq);
    float4 wa = *(const float4*)(Bm + (size_t)(n0 + rw) * ldb + k0 + kq);
    float4 wb = *(const float4*)(Bm + (size_t)(n0 + rw + 32) * ldb + k0 + kq);
    As[rw * 33 + kq + 0] = va.x; As[rw * 33 + kq + 1] = va.y;
    As[rw * 33 + kq + 2] = va.z; As[rw * 33 + kq + 3] = va.w;
    As[(rw + 32) * 33 + kq + 0] = vb.x; As[(rw + 32) * 33 + kq + 1] = vb.y;
    As[(rw + 32) * 33 + kq + 2] = vb.z; As[(rw + 32) * 33 + kq + 3] = vb.w;
    Bs[rw * 33 + kq + 0] = wa.x; Bs[rw * 33 + kq + 1] = wa.y;
    Bs[rw * 33 + kq + 2] = wa.z; Bs[rw * 33 + kq + 3] = wa.w;
    Bs[(rw + 32) * 33 + kq + 0] = wb.x; Bs[(rw + 32) * 33 + kq + 1] = wb.y;
    Bs[(rw + 32) * 33 + kq + 2] = wb.z; Bs[(rw + 32) * 33 + kq + 3] = wb.w;
    __syncthreads();
#pragma unroll 8
    for (int k = 0; k < 32; ++k) {
      float av[4], bv[4];
#pragma unroll
      for (int i = 0; i < 4; ++i) av[i] = As[(ty * 4 + i) * 33 + k];
#pragma unroll
      for (int j = 0; j < 4; ++j) bv[j] = Bs[(tx * 4 + j) * 33 + k];
#pragma unroll
      for (int i = 0; i < 4; ++i)
#pragma unroll
        for (int j = 0; j < 4; ++j) acc[i][j] = fmaf(av[i], bv[j], acc[i][j]);
    }
    __syncthreads();
  }
#pragma unroll
  for (int i = 0; i < 4; ++i) {
    int m = m0 + ty * 4 + i;
    if (m >= M) continue;
    int bl2 = m / 510, tt2 = m - bl2 * 510;
    float* crow = C + ((size_t)tt2 * 16 + (b0 + bl2)) * 768;
#pragma unroll
    for (int j = 0; j < 4; ++j) {
      int n = n0 + tx * 4 + j;
      crow[n] = acc[i][j] + bias[n];
    }
  }
}

// ---------------------------------------------------------------------------
__global__ void init_state(ull* __restrict__ h1g, ull* __restrict__ h2g,
                           ull* __restrict__ prevg, unsigned* __restrict__ bar) {
  int gid = blockIdx.x * 256 + threadIdx.x;
  if (gid < 12288) { at_store(h1g + gid, 0ull); at_store(h2g + gid, 0ull); }
  if (gid < 2816) at_store(prevg + gid, 0ull);
  if (gid < BAR_U32)
    __hip_atomic_store(bar + gid, 0u, __ATOMIC_RELAXED, __HIP_MEMORY_SCOPE_AGENT);
}

// ---------------------------------------------------------------------------
// K6: persistent LSTM. Flag-based sync: one f1-wait/step (all blocks),
// f2-wait only for 88 proj blocks (decoupled). x-dot pipelined into the
// wait window.
// ---------------------------------------------------------------------------
__global__ __launch_bounds__(256, 1) void lstm_kernel(
    const float* __restrict__ aco,   // [510][16][768]
    const float* __restrict__ whh0,  // [3072][768]
    const float* __restrict__ wih0,  // [3072][944]
    const float* __restrict__ wih1,  // [3072][768]
    const float* __restrict__ whh1,  // [3072][768]
    const float* __restrict__ bih0, const float* __restrict__ bhh0,
    const float* __restrict__ bih1, const float* __restrict__ bhh1,
    const float* __restrict__ pw,    // [440][768]
    const float* __restrict__ pb,
    const float* __restrict__ emb,   // [5][2]
    ull* __restrict__ h1g,           // [2][6144] chunked
    ull* __restrict__ h2g,           // [2][6144] chunked
    ull* __restrict__ prevg,         // [2][16][88]
    unsigned* __restrict__ bar,
    float* __restrict__ out)         // [16][510][440]
{
  __shared__ float bufA[16 * 772];   // x(t+1) -> h2(t-1) -> h2(t)[proj]
  __shared__ float bufB[16 * 772];   // h1 (persists across step boundary)
  __shared__ float prevs[16 * 177];
  __shared__ float zl[16 * 17];
  __shared__ float harr[64];
  __shared__ float embS[10];
  const int tid = threadIdx.x;
  const int s = tid & 15;
  const int r = tid >> 4;
  const int uB = blockIdx.x * 4;
  const int j = (r >> 2) * 768 + uB + (r & 3);
  unsigned* f1 = bar + F1_OFF;
  unsigned* f2 = bar + F2_OFF;
  unsigned* pc = bar + PC_OFF;

  // ---- one-time register weight load ----
  float wx[48], w0[48], w1[48], w2[48], wp[11], pwr[48];
  {
    const float* p = wih0 + (size_t)j * 944 + 48 * s;
#pragma unroll
    for (int i = 0; i < 48; i += 4) {
      float4 v = *(const float4*)(p + i);
      wx[i] = v.x; wx[i+1] = v.y; wx[i+2] = v.z; wx[i+3] = v.w;
    }
    p = whh0 + (size_t)j * 768 + 48 * s;
#pragma unroll
    for (int i = 0; i < 48; i += 4) {
      float4 v = *(const float4*)(p + i);
      w0[i] = v.x; w0[i+1] = v.y; w0[i+2] = v.z; w0[i+3] = v.w;
    }
    p = wih1 + (size_t)j * 768 + 48 * s;
#pragma unroll
    for (int i = 0; i < 48; i += 4) {
      float4 v = *(const float4*)(p + i);
      w1[i] = v.x; w1[i+1] = v.y; w1[i+2] = v.z; w1[i+3] = v.w;
    }
    p = whh1 + (size_t)j * 768 + 48 * s;
#pragma unroll
    for (int i = 0; i < 48; i += 4) {
      float4 v = *(const float4*)(p + i);
      w2[i] = v.x; w2[i+1] = v.y; w2[i+2] = v.z; w2[i+3] = v.w;
    }
    const float* pp = wih0 + (size_t)j * 944 + 768 + 11 * s;
#pragma unroll
    for (int i = 0; i < 11; ++i) wp[i] = pp[i];
  }
  const bool pv = (blockIdx.x < 88) && (r < 5);
  const int prow = blockIdx.x * 5 + r;
  float pbv = 0.f;
  if (pv) {
    const float* p = pw + (size_t)prow * 768 + 48 * s;
#pragma unroll
    for (int i = 0; i < 48; i += 4) {
      float4 v = *(const float4*)(p + i);
      pwr[i] = v.x; pwr[i+1] = v.y; pwr[i+2] = v.z; pwr[i+3] = v.w;
    }
    pbv = pb[prow];
  } else {
#pragma unroll
    for (int i = 0; i < 48; ++i) pwr[i] = 0.f;
  }
  float bl1[4], bl2[4], c1 = 0.f, c2 = 0.f;
  if (tid < 64) {
    int ul = tid >> 4;
#pragma unroll
    for (int g = 0; g < 4; ++g) {
      int jj = g * 768 + uB + ul;
      bl1[g] = bih0[jj] + bhh0[jj];
      bl2[g] = bih1[jj] + bhh1[jj];
    }
  }
  if (tid < 10) embS[tid] = emb[tid];

  // ---- precomputed LDS scatter offsets ----
  int offH[24];
#pragma unroll
  for (int q = 0; q < 24; ++q) {
    int G = q * 256 + tid;
    int s2 = G / 384, rem = G - s2 * 384;
    int r2 = rem / 24, q2 = rem - r2 * 24;
    offH[q] = s2 * 772 + r2 * 48 + 2 * q2;
  }
  int offX[12];
#pragma unroll
  for (int q = 0; q < 12; ++q) {
    int F4 = q * 256 + tid;
    int b2 = F4 / 192, rem = F4 - b2 * 192;
    int s2 = rem / 12;
    offX[q] = s2 * 772 + b2 * 48 + (rem - s2 * 12) * 4;
  }
  int offP[11];
#pragma unroll
  for (int q = 0; q < 11; ++q) {
    int F = q * 256 + tid;
    int b2 = F / 176, d = F - b2 * 176;
    int s2 = d / 11;
    offP[q] = s2 * 177 + b2 * 11 + (d - s2 * 11);
  }
  const int hdst = (blockIdx.x / 12) * 384 + (blockIdx.x % 12) * 2;

  for (int i = tid; i < 16 * 772; i += 256) bufB[i] = 0.f;  // h1(-1)=0

  // ---- prologue: x(0) stage + dot -> zxr ----
  float zxr[16];
  {
    const float4* xb = (const float4*)(aco);
#pragma unroll
    for (int q = 0; q < 12; ++q)
      *(float4*)(bufA + offX[q]) = xb[q * 256 + tid];
  }
  __syncthreads();
#pragma unroll 4
  for (int b = 0; b < 16; ++b) {
    float p; CDOT48(wx, bufA + s * 772 + b * 48, p);
    zxr[b] = red16(p);
  }

  for (int t = 0; t < 510; ++t) {
    const int wbuf = t & 1, rbuf = wbuf ^ 1;
    __syncthreads();
    // ===== PH1: w0 dot (bufB = h1(t-1)), zl = zx + w0dot =====
#pragma unroll 4
    for (int b = 0; b < 16; ++b) {
      float p; CDOT48(w0, bufB + s * 772 + b * 48, p);
      p = red16(p);
      if (s == 0) zl[r * 17 + b] = zxr[b] + p;
    }
    // prev(t-1): pwait (overlapped with other blocks' w0 dots) + stage + dot
    if (tid == 0 && t) pwait(pc, 88u * (unsigned)t);
    __syncthreads();
    if (t == 0) {
#pragma unroll
      for (int q = 0; q < 11; ++q) prevs[offP[q]] = 0.f;
    } else {
      const float* pg = (const float*)(prevg + rbuf * 1408);
#pragma unroll
      for (int q = 0; q < 11; ++q)
        prevs[offP[q]] = at_loadf(pg + q * 256 + tid);
    }
    __syncthreads();
#pragma unroll 4
    for (int b = 0; b < 16; ++b) {
      const float* pvv = prevs + s * 177 + b * 11;
      float p = 0.f;
#pragma unroll
      for (int i = 0; i < 11; ++i) p = fmaf(wp[i], pvv[i], p);
      p = red16(p);
      if (s == 0) zl[r * 17 + b] += p;
    }
    __syncthreads();
    if (tid < 64) {
      int ul = tid >> 4, bb = tid & 15;
      float zi = zl[(0 * 4 + ul) * 17 + bb] + bl1[0];
      float zf = zl[(1 * 4 + ul) * 17 + bb] + bl1[1];
      float zg = zl[(2 * 4 + ul) * 17 + bb] + bl1[2];
      float zo = zl[(3 * 4 + ul) * 17 + bb] + bl1[3];
      c1 = sigf(zf) * c1 + sigf(zi) * tanhf(zg);
      harr[tid] = sigf(zo) * tanhf(c1);
    }
    __syncthreads();
    // publish h1(t): data stores + waitcnt + flag (all wave 0, program order)
    if (tid < 32) {
      int q = tid >> 4, bb = tid & 15;
      at_store(h1g + wbuf * 6144 + hdst + bb * 24 + q,
               pack2(harr[(2 * q) * 16 + bb], harr[(2 * q + 1) * 16 + bb]));
    }
    if (tid == 0) {
      __builtin_amdgcn_s_waitcnt(0);
      __atomic_signal_fence(__ATOMIC_SEQ_CST);
      __hip_atomic_store(f1 + blockIdx.x * 16, (unsigned)(t + 1),
                         __ATOMIC_RELAXED, __HIP_MEMORY_SCOPE_AGENT);
    }
    // ===== pipelined x(t+1) stage + dot (hides f1 wait) =====
    if (t < 509) {
      const float4* xb = (const float4*)(aco + (size_t)(t + 1) * 12288);
#pragma unroll
      for (int q = 0; q < 12; ++q)
        *(float4*)(bufA + offX[q]) = xb[q * 256 + tid];
      __syncthreads();
#pragma unroll 4
      for (int b = 0; b < 16; ++b) {
        float p; CDOT48(wx, bufA + s * 772 + b * 48, p);
        zxr[b] = red16(p);
      }
    }
    // ===== f1 wait: h1(t) from all 192 producers =====
    wait_flags(f1, (unsigned)(t + 1), tid);
    // ===== PH2: stage h1(t)->bufB, h2(t-1)->bufA; fused w1/w2 dot =====
    STAGE_HC(h1g + wbuf * 6144, bufB);
    STAGE_HC(h2g + rbuf * 6144, bufA);
    __syncthreads();
#pragma unroll 2
    for (int b = 0; b < 16; ++b) {
      float p1, p2;
      CDOT48(w1, bufB + s * 772 + b * 48, p1);
      CDOT48(w2, bufA + s * 772 + b * 48, p2);
      float p = red16(p1 + p2);
      if (s == 0) zl[r * 17 + b] = p;
    }
    __syncthreads();
    if (tid < 64) {
      int ul = tid >> 4, bb = tid & 15;
      float zi = zl[(0 * 4 + ul) * 17 + bb] + bl2[0];
      float zf = zl[(1 * 4 + ul) * 17 + bb] + bl2[1];
      float zg = zl[(2 * 4 + ul) * 17 + bb] + bl2[2];
      float zo = zl[(3 * 4 + ul) * 17 + bb] + bl2[3];
      c2 = sigf(zf) * c2 + sigf(zi) * tanhf(zg);
      harr[tid] = sigf(zo) * tanhf(c2);
    }
    __syncthreads();
    if (tid < 32) {
      int q = tid >> 4, bb = tid & 15;
      at_store(h2g + wbuf * 6144 + hdst + bb * 24 + q,
               pack2(harr[(2 * q) * 16 + bb], harr[(2 * q + 1) * 16 + bb]));
    }
    if (tid == 0) {
      __builtin_amdgcn_s_waitcnt(0);
      __atomic_signal_fence(__ATOMIC_SEQ_CST);
      __hip_atomic_store(f2 + blockIdx.x * 16, (unsigned)(t + 1),
                         __ATOMIC_RELAXED, __HIP_MEMORY_SCOPE_AGENT);
    }
    // ===== PH3 (proj blocks only, decoupled from the other 104) =====
    if (blockIdx.x < 88) {
      wait_flags(f2, (unsigned)(t + 1), tid);
      STAGE_HC(h2g + wbuf * 6144, bufA);
      __syncthreads();
#pragma unroll 4
      for (int b = 0; b < 16; ++b) {
        float p; CDOT48(pwr, bufA + s * 772 + b * 48, p);
        p = red16(p);
        if (pv && s == 0) {
          float lg = p + pbv;
          out[((size_t)b * 510 + t) * 440 + prow] = lg;
          zl[r * 17 + b] = lg;
        }
      }
      __syncthreads();
      if (tid < 16) {
        float best = zl[0 * 17 + tid]; int bi = 0;
#pragma unroll
        for (int c = 1; c < 5; ++c) {
          float v = zl[c * 17 + tid];
          if (v > best) { best = v; bi = c; }
        }
        at_store(prevg + wbuf * 1408 + tid * 88 + blockIdx.x,
                 pack2(embS[bi * 2], embS[bi * 2 + 1]));
      }
      if (tid == 0) {
        __builtin_amdgcn_s_waitcnt(0);
        __atomic_signal_fence(__ATOMIC_SEQ_CST);
        __hip_atomic_fetch_add(pc + (blockIdx.x & 7) * 16, 1u,
                               __ATOMIC_RELAXED, __HIP_MEMORY_SCOPE_AGENT);
      }
    }
  }
}

// ---------------------------------------------------------------------------
extern "C" void kernel_launch(void* const* d_in, const int* in_sizes, int n_in,
                              void* d_out, int out_size, void* d_ws, size_t ws_size,
                              hipStream_t stream) {
  (void)in_sizes; (void)n_in; (void)out_size;
  const float* mel  = (const float*)d_in[0];
  const float* c1w  = (const float*)d_in[1];
  const float* c1b  = (const float*)d_in[2];
  const float* c2w  = (const float*)d_in[3];
  const float* c2b  = (const float*)d_in[4];
  const float* c3w  = (const float*)d_in[5];
  const float* c3b  = (const float*)d_in[6];
  const float* bn1g = (const float*)d_in[7];
  const float* bn1b = (const float*)d_in[8];
  const float* bn1m = (const float*)d_in[9];
  const float* bn1v = (const float*)d_in[10];
  const float* bn2g = (const float*)d_in[11];
  const float* bn2b = (const float*)d_in[12];
  const float* bn2m = (const float*)d_in[13];
  const float* bn2v = (const float*)d_in[14];
  const float* bn3g = (const float*)d_in[15];
  const float* bn3b = (const float*)d_in[16];
  const float* bn3m = (const float*)d_in[17];
  const float* bn3v = (const float*)d_in[18];
  const float* fcw  = (const float*)d_in[19];
  const float* fcb  = (const float*)d_in[20];
  const float* wih0 = (const float*)d_in[21];
  const float* whh0 = (const float*)d_in[22];
  const float* bih0 = (const float*)d_in[23];
  const float* bhh0 = (const float*)d_in[24];
  const float* wih1 = (const float*)d_in[25];
  const float* whh1 = (const float*)d_in[26];
  const float* bih1 = (const float*)d_in[27];
  const float* bhh1 = (const float*)d_in[28];
  const float* pw   = (const float*)d_in[29];
  const float* pb   = (const float*)d_in[30];
  const float* emb  = (const float*)d_in[31];

  float* ws = (float*)d_ws;
  float* outp = (float*)d_out;

  const size_t ST_ULL = 12288ull + 12288ull + 2816ull;
  int CB = 1;
  for (int cb = 4; cb >= 1; cb >>= 1) {
    size_t need = (ACO_FL + (size_t)cb * 48 * 512 * 114 + (size_t)cb * 510 * 5472) * 4
                + ST_ULL * 8 + BAR_U32 * 4 + 1024;
    if (ws_size >= need) { CB = cb; break; }
  }
  const int nchunks = 16 / CB;
  const size_t A_FL  = (size_t)CB * 48 * 512 * 114;
  const size_t BF_FL = (size_t)CB * 510 * 5472;

  float* aco = ws;                       // [510][16][768]
  float* Ac  = ws + ACO_FL;
  float* Bfc = Ac + A_FL;
  ull* h1g   = (ull*)(Bfc + BF_FL);
  ull* h2g   = h1g + 12288;
  ull* prevg = h2g + 12288;
  unsigned* bar = (unsigned*)(prevg + 2816);

  for (int ch = 0; ch < nchunks; ++ch) {
    int b0 = ch * CB;
    hipLaunchKernelGGL(conv12_kernel, dim3(CB * 512), dim3(256), 0, stream,
                       mel, c1w, c1b, bn1g, bn1b, bn1m, bn1v,
                       c2w, c2b, bn2g, bn2b, bn2m, bn2v, Ac, b0);
    hipLaunchKernelGGL(conv3_kernel, dim3(CB * 510), dim3(256), 0, stream,
                       Ac, c3w, c3b, bn3g, bn3b, bn3m, bn3v, Bfc);
    int M = CB * 510;
    hipLaunchKernelGGL(gemm_nt, dim3((M + 63) / 64, 12), dim3(256), 0, stream,
                       Bfc, fcw, fcb, aco, M, 5472, 5472, 5472, b0);
  }
  hipLaunchKernelGGL(init_state, dim3(48), dim3(256), 0, stream,
                     h1g, h2g, prevg, bar);

  {
    void* args[] = {
      (void*)&aco, (void*)&whh0, (void*)&wih0, (void*)&wih1, (void*)&whh1,
      (void*)&bih0, (void*)&bhh0, (void*)&bih1, (void*)&bhh1,
      (void*)&pw, (void*)&pb, (void*)&emb,
      (void*)&h1g, (void*)&h2g, (void*)&prevg, (void*)&bar, (void*)&outp
    };
    hipError_t e = hipLaunchCooperativeKernel((const void*)lstm_kernel,
                                              dim3(192), dim3(256), args, 0, stream);
    if (e != hipSuccess) {
      (void)hipGetLastError();
      hipLaunchKernelGGL(lstm_kernel, dim3(192), dim3(256), 0, stream,
                         aco, whh0, wih0, wih1, whh1, bih0, bhh0, bih1, bhh1,
                         pw, pb, emb, h1g, h2g, prevg, bar, outp);
    }
  }
}

// Round 4
// 33806.537 us; speedup vs baseline: 1.2102x; 1.0283x over previous
//
#include <hip/hip_runtime.h>
#include <math.h>

// ============================================================================
// AR_Transcriber round 9.
// r8 (direct flags) gave 28.9->26.7ms; still ~52us/step vs ~7us VALU work.
// Diagnosis: 3 dependent global hops/step, and proj work (PH3) rides on
// compute blocks -> they straggle the global f1 wait every step.
// This round:
//  1. Role split: 192 compute blocks + 44 dedicated projection blocks (=236,
//     1/CU). Proj blocks run a decoupled f2->stage->dot->argmax->prev loop
//     that overlaps compute's next-step w0-dot; prev hop leaves the
//     critical path (pwait after w0-dot absorbs it).
//  2. Third LDS buffer: h2(t-1) prefetched into bufC right after pwait
//     (happens-before chain makes it visible there), overlapping prev/cell1.
//     Post-f1 stage halves (h1 only).
//  3. Compute loop has no divergent proj tail.
// Conv kernels / GEMM / coalesced chunked state exchange unchanged from r8.
// ============================================================================

typedef unsigned long long ull;

#define ACO_FL 6266880ull  // 510*16*768
#define F1_OFF 0           // 192 flags * 16 u32 stride
#define F2_OFF 3072
#define PC_OFF 6144        // 8 prev counters * 16 u32 stride
#define BAR_U32 8192
#define NCOMP 192
#define NPROJ 44

__device__ __forceinline__ float sigf(float x) { return 1.0f / (1.0f + expf(-x)); }

__device__ __forceinline__ ull pack2(float x, float y) {
  union { float f[2]; ull u; } c; c.f[0] = x; c.f[1] = y; return c.u;
}
__device__ __forceinline__ float2 unpack2(ull u) {
  union { ull u; float2 v; } c; c.u = u; return c.v;
}
__device__ __forceinline__ ull at_load(const ull* p) {
  return __hip_atomic_load((ull*)p, __ATOMIC_RELAXED, __HIP_MEMORY_SCOPE_AGENT);
}
__device__ __forceinline__ float at_loadf(const float* p) {
  return __hip_atomic_load((float*)p, __ATOMIC_RELAXED, __HIP_MEMORY_SCOPE_AGENT);
}
__device__ __forceinline__ void at_store(ull* p, ull v) {
  __hip_atomic_store(p, v, __ATOMIC_RELAXED, __HIP_MEMORY_SCOPE_AGENT);
}

// Per-producer flag wait: thread tid<NCOMP spins on producer tid's line.
__device__ __forceinline__ void wait_flags(const unsigned* f, unsigned tgt, int tid) {
  if (tid < NCOMP) {
    const unsigned* fp = f + tid * 16;
    while (__hip_atomic_load((unsigned*)fp, __ATOMIC_RELAXED,
                             __HIP_MEMORY_SCOPE_AGENT) < tgt)
      __builtin_amdgcn_s_sleep(1);
  }
  __atomic_signal_fence(__ATOMIC_SEQ_CST);
  __syncthreads();
}

__device__ __forceinline__ void pwait(const unsigned* pc, unsigned target) {
  for (;;) {
    unsigned s0 = 0;
#pragma unroll
    for (int i = 0; i < 8; ++i)
      s0 += __hip_atomic_load((unsigned*)(pc + i * 16), __ATOMIC_RELAXED,
                              __HIP_MEMORY_SCOPE_AGENT);
    if (s0 >= target) break;
    __builtin_amdgcn_s_sleep(1);
  }
  __atomic_signal_fence(__ATOMIC_SEQ_CST);
}

__device__ __forceinline__ float red16(float v) {
  v += __shfl_xor(v, 1, 16);
  v += __shfl_xor(v, 2, 16);
  v += __shfl_xor(v, 4, 16);
  v += __shfl_xor(v, 8, 16);
  return v;
}

// 48-FMA chunk dot: weights from VGPR array W, data from LDS pointer PTR.
#define CDOT48(W, PTR, RES) do {                                              \
  const float* _p = (PTR);                                                    \
  float _a0 = 0.f, _a1 = 0.f, _a2 = 0.f, _a3 = 0.f;                           \
  _Pragma("unroll")                                                           \
  for (int _i = 0; _i < 48; _i += 16) {                                       \
    float4 _v0 = *(const float4*)(_p + _i);                                   \
    float4 _v1 = *(const float4*)(_p + _i + 4);                               \
    float4 _v2 = *(const float4*)(_p + _i + 8);                               \
    float4 _v3 = *(const float4*)(_p + _i + 12);                              \
    _a0 = fmaf((W)[_i + 0], _v0.x, _a0); _a0 = fmaf((W)[_i + 1], _v0.y, _a0); \
    _a0 = fmaf((W)[_i + 2], _v0.z, _a0); _a0 = fmaf((W)[_i + 3], _v0.w, _a0); \
    _a1 = fmaf((W)[_i + 4], _v1.x, _a1); _a1 = fmaf((W)[_i + 5], _v1.y, _a1); \
    _a1 = fmaf((W)[_i + 6], _v1.z, _a1); _a1 = fmaf((W)[_i + 7], _v1.w, _a1); \
    _a2 = fmaf((W)[_i + 8], _v2.x, _a2); _a2 = fmaf((W)[_i + 9], _v2.y, _a2); \
    _a2 = fmaf((W)[_i +10], _v2.z, _a2); _a2 = fmaf((W)[_i +11], _v2.w, _a2); \
    _a3 = fmaf((W)[_i +12], _v3.x, _a3); _a3 = fmaf((W)[_i +13], _v3.y, _a3); \
    _a3 = fmaf((W)[_i +14], _v3.z, _a3); _a3 = fmaf((W)[_i +15], _v3.w, _a3); \
  }                                                                           \
  RES = (_a0 + _a1) + (_a2 + _a3);                                            \
} while (0)

// Coalesced h stage: global chunked layout -> LDS via precomputed offH.
#define STAGE_HC(SRC, DST) do {                                               \
  _Pragma("unroll")                                                           \
  for (int _q = 0; _q < 24; ++_q) {                                           \
    ull _v = at_load((SRC) + _q * 256 + tid);                                 \
    *(float2*)((DST) + offH[_q]) = unpack2(_v);                               \
  }                                                                           \
} while (0)

// ---------------------------------------------------------------------------
// K1: fused conv1+bn1+relu -> conv2+bn2+relu -> pool(1,2). (unchanged)
// ---------------------------------------------------------------------------
__global__ __launch_bounds__(256) void conv12_kernel(
    const float* __restrict__ mel,
    const float* __restrict__ c1w, const float* __restrict__ c1b,
    const float* __restrict__ bn1g, const float* __restrict__ bn1b,
    const float* __restrict__ bn1m, const float* __restrict__ bn1v,
    const float* __restrict__ c2w, const float* __restrict__ c2b,
    const float* __restrict__ bn2g, const float* __restrict__ bn2b,
    const float* __restrict__ bn2m, const float* __restrict__ bn2v,
    float* __restrict__ A, int b0)
{
  __shared__ float melS[5 * 232];
  __shared__ float x1S[12 * 3 * 232];
  __shared__ float wS[48 * 12 * 9];
  const int tid = threadIdx.x;
  const int bl = blockIdx.x >> 9;
  const int b = b0 + bl;
  const int t = blockIdx.x & 511;

  for (int idx = tid; idx < 5 * 232; idx += 256) {
    int rr = idx / 232, cc = idx - rr * 232;
    int r = t - 2 + rr, w = cc - 1;
    float v = 0.f;
    if (r >= 0 && r < 512 && w >= 0 && w < 229) v = mel[(b * 512 + r) * 229 + w];
    melS[idx] = v;
  }

  float accA[22], accB[22];
#pragma unroll
  for (int i = 0; i < 22; ++i) { accA[i] = 0.f; accB[i] = 0.f; }
  __syncthreads();

  for (int icc = 0; icc < 4; ++icc) {
    if (icc) __syncthreads();
    for (int idx = tid; idx < 12 * 3 * 232; idx += 256) {
      int cl = idx / (3 * 232);
      int rem = idx - cl * (3 * 232);
      int rr = rem / 232, cc = rem - rr * 232;
      int c = icc * 12 + cl;
      int r1 = t - 1 + rr, w = cc - 1;
      float v = 0.f;
      if (r1 >= 0 && r1 < 512 && w >= 0 && w < 229) {
        const float* cw = c1w + c * 9;
        const float* m0 = melS + rr * 232 + cc - 1;
        float s = m0[0] * cw[0] + m0[1] * cw[1] + m0[2] * cw[2]
                + m0[232] * cw[3] + m0[233] * cw[4] + m0[234] * cw[5]
                + m0[464] * cw[6] + m0[465] * cw[7] + m0[466] * cw[8];
        s += c1b[c];
        float sc = bn1g[c] * rsqrtf(bn1v[c] + 1e-5f);
        v = fmaxf(s * sc + (bn1b[c] - bn1m[c] * sc), 0.f);
      }
      x1S[idx] = v;
    }
    for (int idx = tid; idx < 48 * 12 * 9; idx += 256) {
      int oc = idx / 108, rem = idx - oc * 108;
      wS[idx] = c2w[(oc * 48 + icc * 12) * 9 + rem];
    }
    __syncthreads();
    for (int i = 0; i < 22; ++i) {
      int oidx = tid + i * 256;
      if (oidx >= 5472) break;
      int oc = oidx / 114, wp = oidx - oc * 114;
      int w0 = 2 * wp;
      float a0 = accA[i], a1 = accB[i];
      const float* wp9 = wS + oc * 108;
      for (int icl = 0; icl < 12; ++icl) {
#pragma unroll
        for (int a = 0; a < 3; ++a) {
          const float* xr = x1S + (icl * 3 + a) * 232 + w0;
          float x0 = xr[0], x1 = xr[1], x2 = xr[2], x3 = xr[3];
          float wA = wp9[icl * 9 + a * 3 + 0];
          float wB = wp9[icl * 9 + a * 3 + 1];
          float wC = wp9[icl * 9 + a * 3 + 2];
          a0 = fmaf(x0, wA, a0); a0 = fmaf(x1, wB, a0); a0 = fmaf(x2, wC, a0);
          a1 = fmaf(x1, wA, a1); a1 = fmaf(x2, wB, a1); a1 = fmaf(x3, wC, a1);
        }
      }
      accA[i] = a0; accB[i] = a1;
    }
  }
  for (int i = 0; i < 22; ++i) {
    int oidx = tid + i * 256;
    if (oidx >= 5472) break;
    int oc = oidx / 114, wp = oidx - oc * 114;
    float sc = bn2g[oc] * rsqrtf(bn2v[oc] + 1e-5f);
    float sh = bn2b[oc] - bn2m[oc] * sc;
    float v0 = fmaxf((accA[i] + c2b[oc]) * sc + sh, 0.f);
    float v1 = fmaxf((accB[i] + c2b[oc]) * sc + sh, 0.f);
    A[((bl * 48 + oc) * 512 + t) * 114 + wp] = fmaxf(v0, v1);
  }
}

// ---------------------------------------------------------------------------
// K2: conv3+bn3+relu+pool(1,2); GEMM-ready output. (unchanged)
// ---------------------------------------------------------------------------
__global__ __launch_bounds__(256) void conv3_kernel(
    const float* __restrict__ A,
    const float* __restrict__ c3w, const float* __restrict__ c3b,
    const float* __restrict__ bn3g, const float* __restrict__ bn3b,
    const float* __restrict__ bn3m, const float* __restrict__ bn3v,
    float* __restrict__ Bf)
{
  __shared__ float aS[16 * 3 * 116];
  __shared__ float wS[48 * 16 * 9];
  const int tid = threadIdx.x;
  const int bl = blockIdx.x / 510;
  const int t = blockIdx.x - bl * 510;

  for (int ocg = 0; ocg < 2; ++ocg) {
    float accA[11], accB[11];
#pragma unroll
    for (int i = 0; i < 11; ++i) { accA[i] = 0.f; accB[i] = 0.f; }
    for (int icc = 0; icc < 3; ++icc) {
      __syncthreads();
      for (int idx = tid; idx < 16 * 3 * 116; idx += 256) {
        int cl = idx / 348, rem = idx - cl * 348;
        int rr = rem / 116, cc = rem - rr * 116;
        int w = cc - 1;
        float v = 0.f;
        if (w >= 0 && w < 114) v = A[((bl * 48 + icc * 16 + cl) * 512 + t + rr) * 114 + w];
        aS[idx] = v;
      }
      for (int idx = tid; idx < 48 * 16 * 9; idx += 256) {
        int ocl = idx / 144, rem = idx - ocl * 144;
        wS[idx] = c3w[((ocg * 48 + ocl) * 48 + icc * 16) * 9 + rem];
      }
      __syncthreads();
      for (int i = 0; i < 11; ++i) {
        int oidx = tid + i * 256;
        if (oidx >= 2736) break;
        int ocl = oidx / 57, wp = oidx - ocl * 57;
        int w0 = 2 * wp;
        float a0 = accA[i], a1 = accB[i];
        const float* wb = wS + ocl * 144;
        for (int icl = 0; icl < 16; ++icl) {
#pragma unroll
          for (int a = 0; a < 3; ++a) {
            const float* xr = aS + (icl * 3 + a) * 116 + w0;
            float x0 = xr[0], x1 = xr[1], x2 = xr[2], x3 = xr[3];
            float wA = wb[icl * 9 + a * 3 + 0];
            float wB = wb[icl * 9 + a * 3 + 1];
            float wC = wb[icl * 9 + a * 3 + 2];
            a0 = fmaf(x0, wA, a0); a0 = fmaf(x1, wB, a0); a0 = fmaf(x2, wC, a0);
            a1 = fmaf(x1, wA, a1); a1 = fmaf(x2, wB, a1); a1 = fmaf(x3, wC, a1);
          }
        }
        accA[i] = a0; accB[i] = a1;
      }
    }
    for (int i = 0; i < 11; ++i) {
      int oidx = tid + i * 256;
      if (oidx >= 2736) break;
      int ocl = oidx / 57, wp = oidx - ocl * 57;
      int oc = ocg * 48 + ocl;
      float sc = bn3g[oc] * rsqrtf(bn3v[oc] + 1e-5f);
      float sh = bn3b[oc] - bn3m[oc] * sc;
      float v0 = fmaxf((accA[i] + c3b[oc]) * sc + sh, 0.f);
      float v1 = fmaxf((accB[i] + c3b[oc]) * sc + sh, 0.f);
      Bf[(size_t)(bl * 510 + t) * 5472 + oc * 57 + wp] = fmaxf(v0, v1);
    }
  }
}

// ---------------------------------------------------------------------------
// K3: fp32 NT GEMM  C = A * B^T + bias, output relaid to [t][16][768].
// ---------------------------------------------------------------------------
__global__ __launch_bounds__(256) void gemm_nt(
    const float* __restrict__ Am, const float* __restrict__ Bm,
    const float* __restrict__ bias, float* __restrict__ C,
    int M, int K, int lda, int ldb, int b0)
{
  __shared__ float As[64 * 33];
  __shared__ float Bs[64 * 33];
  const int tid = threadIdx.x;
  const int m0 = blockIdx.x * 64, n0 = blockIdx.y * 64;
  const int tx = tid & 15, ty = tid >> 4;
  const int kq = (tid & 7) * 4, rw = tid >> 3;
  float acc[4][4];
#pragma unroll
  for (int i = 0; i < 4; ++i)
#pragma unroll
    for (int j = 0; j < 4; ++j) acc[i][j] = 0.f;

  for (int k0 = 0; k0 < K; k0 += 32) {
    int m1 = m0 + rw, m2 = m1 + 32;
    float4 va = make_float4(0.f, 0.f, 0.f, 0.f), vb = va;
    if (m1 < M) va = *(const float4*)(Am + (size_t)m1 * lda + k0 + kq);
    if (m2 < M) vb = *(const float4*)(Am + (size_t)m2 * lda + k0 + kq);
    float4 wa = *(const float4*)(Bm + (size_t)(n0 + rw) * ldb + k0 + kq);
    float4 wb = *(const float4*)(Bm + (size_t)(n0 + rw + 32) * ldb + k0 + kq);
    As[rw * 33 + kq + 0] = va.x; As[rw * 33 + kq + 1] = va.y;
    As[rw * 33 + kq + 2] = va.z; As[rw * 33 + kq + 3] = va.w;
    As[(rw + 32) * 33 + kq + 0] = vb.x; As[(rw + 32) * 33 + kq + 1] = vb.y;
    As[(rw + 32) * 33 + kq + 2] = vb.z; As[(rw + 32) * 33 + kq + 3] = vb.w;
    Bs[rw * 33 + kq + 0] = wa.x; Bs[rw * 33 + kq + 1] = wa.y;
    Bs[rw * 33 + kq + 2] = wa.z; Bs[rw * 33 + kq + 3] = wa.w;
    Bs[(rw + 32) * 33 + kq + 0] = wb.x; Bs[(rw + 32) * 33 + kq + 1] = wb.y;
    Bs[(rw + 32) * 33 + kq + 2] = wb.z; Bs[(rw + 32) * 33 + kq + 3] = wb.w;
    __syncthreads();
#pragma unroll 8
    for (int k = 0; k < 32; ++k) {
      float av[4], bv[4];
#pragma unroll
      for (int i = 0; i < 4; ++i) av[i] = As[(ty * 4 + i) * 33 + k];
#pragma unroll
      for (int j = 0; j < 4; ++j) bv[j] = Bs[(tx * 4 + j) * 33 + k];
#pragma unroll
      for (int i = 0; i < 4; ++i)
#pragma unroll
        for (int j = 0; j < 4; ++j) acc[i][j] = fmaf(av[i], bv[j], acc[i][j]);
    }
    __syncthreads();
  }
#pragma unroll
  for (int i = 0; i < 4; ++i) {
    int m = m0 + ty * 4 + i;
    if (m >= M) continue;
    int bl2 = m / 510, tt2 = m - bl2 * 510;
    float* crow = C + ((size_t)tt2 * 16 + (b0 + bl2)) * 768;
#pragma unroll
    for (int j = 0; j < 4; ++j) {
      int n = n0 + tx * 4 + j;
      crow[n] = acc[i][j] + bias[n];
    }
  }
}

// ---------------------------------------------------------------------------
__global__ void init_state(ull* __restrict__ h1g, ull* __restrict__ h2g,
                           ull* __restrict__ prevg, unsigned* __restrict__ bar) {
  int gid = blockIdx.x * 256 + threadIdx.x;
  if (gid < 12288) { at_store(h1g + gid, 0ull); at_store(h2g + gid, 0ull); }
  if (gid < 2816) at_store(prevg + gid, 0ull);
  if (gid < BAR_U32)
    __hip_atomic_store(bar + gid, 0u, __ATOMIC_RELAXED, __HIP_MEMORY_SCOPE_AGENT);
}

// ---------------------------------------------------------------------------
// K6: persistent LSTM. 192 compute blocks + 44 dedicated projection blocks.
// ---------------------------------------------------------------------------
__global__ __launch_bounds__(256, 1) void lstm_kernel(
    const float* __restrict__ aco,   // [510][16][768]
    const float* __restrict__ whh0,  // [3072][768]
    const float* __restrict__ wih0,  // [3072][944]
    const float* __restrict__ wih1,  // [3072][768]
    const float* __restrict__ whh1,  // [3072][768]
    const float* __restrict__ bih0, const float* __restrict__ bhh0,
    const float* __restrict__ bih1, const float* __restrict__ bhh1,
    const float* __restrict__ pw,    // [440][768]
    const float* __restrict__ pb,
    const float* __restrict__ emb,   // [5][2]
    ull* __restrict__ h1g,           // [2][6144] chunked
    ull* __restrict__ h2g,           // [2][6144] chunked
    ull* __restrict__ prevg,         // [2][16][88]
    unsigned* __restrict__ bar,
    float* __restrict__ out)         // [16][510][440]
{
  __shared__ float bufA[16 * 772];   // x (compute) / h2 (proj)
  __shared__ float bufB[16 * 772];   // h1
  __shared__ float bufC[16 * 772];   // h2(t-1)
  __shared__ float prevs[16 * 177];
  __shared__ float zl[16 * 17];
  __shared__ float harr[64];
  __shared__ float embS[10];
  const int tid = threadIdx.x;
  const int s = tid & 15;
  const int r = tid >> 4;
  unsigned* f1 = bar + F1_OFF;
  unsigned* f2 = bar + F2_OFF;
  unsigned* pc = bar + PC_OFF;

  // ---- precomputed LDS scatter offsets (both roles) ----
  int offH[24];
#pragma unroll
  for (int q = 0; q < 24; ++q) {
    int G = q * 256 + tid;
    int s2 = G / 384, rem = G - s2 * 384;
    int r2 = rem / 24, q2 = rem - r2 * 24;
    offH[q] = s2 * 772 + r2 * 48 + 2 * q2;
  }

  if (blockIdx.x < NCOMP) {
    // =======================================================================
    // COMPUTE BLOCK: 4 hidden dims (both layers), all 16 batches.
    // =======================================================================
    const int uB = blockIdx.x * 4;
    const int j = (r >> 2) * 768 + uB + (r & 3);

    float wx[48], w0[48], w1[48], w2[48], wp[11];
    {
      const float* p = wih0 + (size_t)j * 944 + 48 * s;
#pragma unroll
      for (int i = 0; i < 48; i += 4) {
        float4 v = *(const float4*)(p + i);
        wx[i] = v.x; wx[i+1] = v.y; wx[i+2] = v.z; wx[i+3] = v.w;
      }
      p = whh0 + (size_t)j * 768 + 48 * s;
#pragma unroll
      for (int i = 0; i < 48; i += 4) {
        float4 v = *(const float4*)(p + i);
        w0[i] = v.x; w0[i+1] = v.y; w0[i+2] = v.z; w0[i+3] = v.w;
      }
      p = wih1 + (size_t)j * 768 + 48 * s;
#pragma unroll
      for (int i = 0; i < 48; i += 4) {
        float4 v = *(const float4*)(p + i);
        w1[i] = v.x; w1[i+1] = v.y; w1[i+2] = v.z; w1[i+3] = v.w;
      }
      p = whh1 + (size_t)j * 768 + 48 * s;
#pragma unroll
      for (int i = 0; i < 48; i += 4) {
        float4 v = *(const float4*)(p + i);
        w2[i] = v.x; w2[i+1] = v.y; w2[i+2] = v.z; w2[i+3] = v.w;
      }
      const float* pp = wih0 + (size_t)j * 944 + 768 + 11 * s;
#pragma unroll
      for (int i = 0; i < 11; ++i) wp[i] = pp[i];
    }
    float bl1[4], bl2[4], c1 = 0.f, c2 = 0.f;
    if (tid < 64) {
      int ul = tid >> 4;
#pragma unroll
      for (int g = 0; g < 4; ++g) {
        int jj = g * 768 + uB + ul;
        bl1[g] = bih0[jj] + bhh0[jj];
        bl2[g] = bih1[jj] + bhh1[jj];
      }
    }
    int offX[12];
#pragma unroll
    for (int q = 0; q < 12; ++q) {
      int F4 = q * 256 + tid;
      int b2 = F4 / 192, rem = F4 - b2 * 192;
      int s2 = rem / 12;
      offX[q] = s2 * 772 + b2 * 48 + (rem - s2 * 12) * 4;
    }
    int offP[11];
#pragma unroll
    for (int q = 0; q < 11; ++q) {
      int F = q * 256 + tid;
      int b2 = F / 176, d = F - b2 * 176;
      int s2 = d / 11;
      offP[q] = s2 * 177 + b2 * 11 + (d - s2 * 11);
    }
    const int hdst = (blockIdx.x / 12) * 384 + (blockIdx.x % 12) * 2;

    // h1(-1) = 0, h2(-1) = 0
    for (int i = tid; i < 16 * 772; i += 256) { bufB[i] = 0.f; bufC[i] = 0.f; }

    // prologue: x(0) stage + dot
    float zxr[16];
    {
      const float4* xb = (const float4*)(aco);
#pragma unroll
      for (int q = 0; q < 12; ++q)
        *(float4*)(bufA + offX[q]) = xb[q * 256 + tid];
    }
    __syncthreads();
#pragma unroll 4
    for (int b = 0; b < 16; ++b) {
      float p; CDOT48(wx, bufA + s * 772 + b * 48, p);
      zxr[b] = red16(p);
    }

    for (int t = 0; t < 510; ++t) {
      const int wbuf = t & 1, rbuf = wbuf ^ 1;
      __syncthreads();
      // ---- w0 dot: bufB = h1(t-1) (overlaps proj blocks' PH3(t-1)) ----
#pragma unroll 4
      for (int b = 0; b < 16; ++b) {
        float p; CDOT48(w0, bufB + s * 772 + b * 48, p);
        p = red16(p);
        if (s == 0) zl[r * 17 + b] = zxr[b] + p;
      }
      // ---- prev(t-1) ready wait (proj blocks publish + bump pc) ----
      if (tid == 0 && t) pwait(pc, (unsigned)(NPROJ * t));
      __syncthreads();
      // ---- prefetch h2(t-1) -> bufC (visible per pwait hb-chain) ----
      STAGE_HC(h2g + rbuf * 6144, bufC);
      // ---- prev stage + dot ----
      if (t == 0) {
#pragma unroll
        for (int q = 0; q < 11; ++q) prevs[offP[q]] = 0.f;
      } else {
        const float* pg = (const float*)(prevg + rbuf * 1408);
#pragma unroll
        for (int q = 0; q < 11; ++q)
          prevs[offP[q]] = at_loadf(pg + q * 256 + tid);
      }
      __syncthreads();
#pragma unroll 4
      for (int b = 0; b < 16; ++b) {
        const float* pvv = prevs + s * 177 + b * 11;
        float p = 0.f;
#pragma unroll
        for (int i = 0; i < 11; ++i) p = fmaf(wp[i], pvv[i], p);
        p = red16(p);
        if (s == 0) zl[r * 17 + b] += p;
      }
      __syncthreads();
      // ---- cell 1 ----
      if (tid < 64) {
        int ul = tid >> 4, bb = tid & 15;
        float zi = zl[(0 * 4 + ul) * 17 + bb] + bl1[0];
        float zf = zl[(1 * 4 + ul) * 17 + bb] + bl1[1];
        float zg = zl[(2 * 4 + ul) * 17 + bb] + bl1[2];
        float zo = zl[(3 * 4 + ul) * 17 + bb] + bl1[3];
        c1 = sigf(zf) * c1 + sigf(zi) * tanhf(zg);
        harr[tid] = sigf(zo) * tanhf(c1);
      }
      __syncthreads();
      // ---- publish h1(t) ----
      if (tid < 32) {
        int q = tid >> 4, bb = tid & 15;
        at_store(h1g + wbuf * 6144 + hdst + bb * 24 + q,
                 pack2(harr[(2 * q) * 16 + bb], harr[(2 * q + 1) * 16 + bb]));
      }
      if (tid == 0) {
        __builtin_amdgcn_s_waitcnt(0);
        __atomic_signal_fence(__ATOMIC_SEQ_CST);
        __hip_atomic_store(f1 + blockIdx.x * 16, (unsigned)(t + 1),
                           __ATOMIC_RELAXED, __HIP_MEMORY_SCOPE_AGENT);
      }
      // ---- pipelined x(t+1) stage + dot (hides f1 skew) ----
      if (t < 509) {
        const float4* xb = (const float4*)(aco + (size_t)(t + 1) * 12288);
#pragma unroll
        for (int q = 0; q < 12; ++q)
          *(float4*)(bufA + offX[q]) = xb[q * 256 + tid];
        __syncthreads();
#pragma unroll 4
        for (int b = 0; b < 16; ++b) {
          float p; CDOT48(wx, bufA + s * 772 + b * 48, p);
          zxr[b] = red16(p);
        }
      }
      // ---- f1 wait, stage h1(t), fused w1/w2 dot ----
      wait_flags(f1, (unsigned)(t + 1), tid);
      STAGE_HC(h1g + wbuf * 6144, bufB);
      __syncthreads();
#pragma unroll 2
      for (int b = 0; b < 16; ++b) {
        float p1, p2;
        CDOT48(w1, bufB + s * 772 + b * 48, p1);
        CDOT48(w2, bufC + s * 772 + b * 48, p2);
        float p = red16(p1 + p2);
        if (s == 0) zl[r * 17 + b] = p;
      }
      __syncthreads();
      // ---- cell 2 ----
      if (tid < 64) {
        int ul = tid >> 4, bb = tid & 15;
        float zi = zl[(0 * 4 + ul) * 17 + bb] + bl2[0];
        float zf = zl[(1 * 4 + ul) * 17 + bb] + bl2[1];
        float zg = zl[(2 * 4 + ul) * 17 + bb] + bl2[2];
        float zo = zl[(3 * 4 + ul) * 17 + bb] + bl2[3];
        c2 = sigf(zf) * c2 + sigf(zi) * tanhf(zg);
        harr[tid] = sigf(zo) * tanhf(c2);
      }
      __syncthreads();
      // ---- publish h2(t) ----
      if (tid < 32) {
        int q = tid >> 4, bb = tid & 15;
        at_store(h2g + wbuf * 6144 + hdst + bb * 24 + q,
                 pack2(harr[(2 * q) * 16 + bb], harr[(2 * q + 1) * 16 + bb]));
      }
      if (tid == 0) {
        __builtin_amdgcn_s_waitcnt(0);
        __atomic_signal_fence(__ATOMIC_SEQ_CST);
        __hip_atomic_store(f2 + blockIdx.x * 16, (unsigned)(t + 1),
                           __ATOMIC_RELAXED, __HIP_MEMORY_SCOPE_AGENT);
      }
    }
  } else {
    // =======================================================================
    // PROJECTION BLOCK: 10 logit rows (2 argmax groups), all 16 batches.
    // =======================================================================
    const int bp = blockIdx.x - NCOMP;   // 0..43
    const int prow = bp * 10 + r;        // valid for r < 10
    float pwr[48];
    float pbv = 0.f;
    if (r < 10) {
      const float* p = pw + (size_t)prow * 768 + 48 * s;
#pragma unroll
      for (int i = 0; i < 48; i += 4) {
        float4 v = *(const float4*)(p + i);
        pwr[i] = v.x; pwr[i+1] = v.y; pwr[i+2] = v.z; pwr[i+3] = v.w;
      }
      pbv = pb[prow];
    } else {
#pragma unroll
      for (int i = 0; i < 48; ++i) pwr[i] = 0.f;
    }
    if (tid < 10) embS[tid] = emb[tid];
    __syncthreads();

    for (int t = 0; t < 510; ++t) {
      const int wbuf = t & 1;
      // h2(t) from all 192 compute blocks
      wait_flags(f2, (unsigned)(t + 1), tid);
      STAGE_HC(h2g + wbuf * 6144, bufA);
      __syncthreads();
#pragma unroll 4
      for (int b = 0; b < 16; ++b) {
        float p; CDOT48(pwr, bufA + s * 772 + b * 48, p);
        p = red16(p);
        if (r < 10 && s == 0) {
          float lg = p + pbv;
          out[((size_t)b * 510 + t) * 440 + prow] = lg;
          zl[r * 17 + b] = lg;
        }
      }
      __syncthreads();
      if (tid < 32) {
        int q = tid >> 4, bb = tid & 15;
        float best = zl[(q * 5) * 17 + bb]; int bi = 0;
#pragma unroll
        for (int c = 1; c < 5; ++c) {
          float v = zl[(q * 5 + c) * 17 + bb];
          if (v > best) { best = v; bi = c; }
        }
        at_store(prevg + wbuf * 1408 + bb * 88 + bp * 2 + q,
                 pack2(embS[bi * 2], embS[bi * 2 + 1]));
      }
      __syncthreads();
      if (tid == 0) {
        __builtin_amdgcn_s_waitcnt(0);
        __atomic_signal_fence(__ATOMIC_SEQ_CST);
        __hip_atomic_fetch_add(pc + (bp & 7) * 16, 1u,
                               __ATOMIC_RELAXED, __HIP_MEMORY_SCOPE_AGENT);
      }
    }
  }
}

// ---------------------------------------------------------------------------
extern "C" void kernel_launch(void* const* d_in, const int* in_sizes, int n_in,
                              void* d_out, int out_size, void* d_ws, size_t ws_size,
                              hipStream_t stream) {
  (void)in_sizes; (void)n_in; (void)out_size;
  const float* mel  = (const float*)d_in[0];
  const float* c1w  = (const float*)d_in[1];
  const float* c1b  = (const float*)d_in[2];
  const float* c2w  = (const float*)d_in[3];
  const float* c2b  = (const float*)d_in[4];
  const float* c3w  = (const float*)d_in[5];
  const float* c3b  = (const float*)d_in[6];
  const float* bn1g = (const float*)d_in[7];
  const float* bn1b = (const float*)d_in[8];
  const float* bn1m = (const float*)d_in[9];
  const float* bn1v = (const float*)d_in[10];
  const float* bn2g = (const float*)d_in[11];
  const float* bn2b = (const float*)d_in[12];
  const float* bn2m = (const float*)d_in[13];
  const float* bn2v = (const float*)d_in[14];
  const float* bn3g = (const float*)d_in[15];
  const float* bn3b = (const float*)d_in[16];
  const float* bn3m = (const float*)d_in[17];
  const float* bn3v = (const float*)d_in[18];
  const float* fcw  = (const float*)d_in[19];
  const float* fcb  = (const float*)d_in[20];
  const float* wih0 = (const float*)d_in[21];
  const float* whh0 = (const float*)d_in[22];
  const float* bih0 = (const float*)d_in[23];
  const float* bhh0 = (const float*)d_in[24];
  const float* wih1 = (const float*)d_in[25];
  const float* whh1 = (const float*)d_in[26];
  const float* bih1 = (const float*)d_in[27];
  const float* bhh1 = (const float*)d_in[28];
  const float* pw   = (const float*)d_in[29];
  const float* pb   = (const float*)d_in[30];
  const float* emb  = (const float*)d_in[31];

  float* ws = (float*)d_ws;
  float* outp = (float*)d_out;

  const size_t ST_ULL = 12288ull + 12288ull + 2816ull;
  int CB = 1;
  for (int cb = 4; cb >= 1; cb >>= 1) {
    size_t need = (ACO_FL + (size_t)cb * 48 * 512 * 114 + (size_t)cb * 510 * 5472) * 4
                + ST_ULL * 8 + BAR_U32 * 4 + 1024;
    if (ws_size >= need) { CB = cb; break; }
  }
  const int nchunks = 16 / CB;
  const size_t A_FL  = (size_t)CB * 48 * 512 * 114;
  const size_t BF_FL = (size_t)CB * 510 * 5472;

  float* aco = ws;                       // [510][16][768]
  float* Ac  = ws + ACO_FL;
  float* Bfc = Ac + A_FL;
  ull* h1g   = (ull*)(Bfc + BF_FL);
  ull* h2g   = h1g + 12288;
  ull* prevg = h2g + 12288;
  unsigned* bar = (unsigned*)(prevg + 2816);

  for (int ch = 0; ch < nchunks; ++ch) {
    int b0 = ch * CB;
    hipLaunchKernelGGL(conv12_kernel, dim3(CB * 512), dim3(256), 0, stream,
                       mel, c1w, c1b, bn1g, bn1b, bn1m, bn1v,
                       c2w, c2b, bn2g, bn2b, bn2m, bn2v, Ac, b0);
    hipLaunchKernelGGL(conv3_kernel, dim3(CB * 510), dim3(256), 0, stream,
                       Ac, c3w, c3b, bn3g, bn3b, bn3m, bn3v, Bfc);
    int M = CB * 510;
    hipLaunchKernelGGL(gemm_nt, dim3((M + 63) / 64, 12), dim3(256), 0, stream,
                       Bfc, fcw, fcb, aco, M, 5472, 5472, 5472, b0);
  }
  hipLaunchKernelGGL(init_state, dim3(48), dim3(256), 0, stream,
                     h1g, h2g, prevg, bar);

  {
    void* args[] = {
      (void*)&aco, (void*)&whh0, (void*)&wih0, (void*)&wih1, (void*)&whh1,
      (void*)&bih0, (void*)&bhh0, (void*)&bih1, (void*)&bhh1,
      (void*)&pw, (void*)&pb, (void*)&emb,
      (void*)&h1g, (void*)&h2g, (void*)&prevg, (void*)&bar, (void*)&outp
    };
    hipError_t e = hipLaunchCooperativeKernel((const void*)lstm_kernel,
                                              dim3(NCOMP + NPROJ), dim3(256),
                                              args, 0, stream);
    if (e != hipSuccess) {
      (void)hipGetLastError();
      hipLaunchKernelGGL(lstm_kernel, dim3(NCOMP + NPROJ), dim3(256), 0, stream,
                         aco, whh0, wih0, wih1, whh1, bih0, bhh0, bih1, bhh1,
                         pw, pb, emb, h1g, h2g, prevg, bar, outp);
    }
  }
}

// Round 5
// 25841.507 us; speedup vs baseline: 1.5832x; 1.3082x over previous
//
#include <hip/hip_runtime.h>
#include <math.h>

// ============================================================================
// AR_Transcriber round 10.
// r7-r9: sync restructures gave <=8% each; steady 51us/step vs ~6us VALU.
// New theory: gather path = per-lane 8B AGENT-SCOPE ATOMIC loads -> no TA
// coalescing, ~2.9M LLC transactions/step -> transaction-throughput bound.
// Fix: gathers via __builtin_amdgcn_global_load_lds (16B, coalesced,
// direct-to-LDS) with cpol sc0|sc1 (aux=17) = device-coherent read at LLC.
// Producer publishes unchanged (agent atomic stores + s_waitcnt(0) + flag),
// so flag-observed => data at LLC => sc0sc1 read sees it.
//  - r7 chunked global h layout is LDS-linear per chunk -> identity mapping.
//  - prev: pad-free [b][176] LDS (stride-11 dot reads stay conflict-free),
//    staged with 11 gload_lds; producer layout unchanged.
//  - x-stage converted too (aux=0: written by prior dispatch, cached OK).
// Role split (192 compute + 44 proj), flags, pwait: unchanged from r9.
// ============================================================================

typedef unsigned long long ull;

#define ACO_FL 6266880ull  // 510*16*768
#define F1_OFF 0           // 192 flags * 16 u32 stride
#define F2_OFF 3072
#define PC_OFF 6144        // 8 prev counters * 16 u32 stride
#define BAR_U32 8192
#define NCOMP 192
#define NPROJ 44

__device__ __forceinline__ float sigf(float x) { return 1.0f / (1.0f + expf(-x)); }

__device__ __forceinline__ ull pack2(float x, float y) {
  union { float f[2]; ull u; } c; c.f[0] = x; c.f[1] = y; return c.u;
}
__device__ __forceinline__ ull at_load(const ull* p) {
  return __hip_atomic_load((ull*)p, __ATOMIC_RELAXED, __HIP_MEMORY_SCOPE_AGENT);
}
__device__ __forceinline__ void at_store(ull* p, ull v) {
  __hip_atomic_store(p, v, __ATOMIC_RELAXED, __HIP_MEMORY_SCOPE_AGENT);
}

// Device-coherent (sc0|sc1 = 1|16 = 17) global -> LDS direct copy, 16B/lane.
__device__ __forceinline__ void gl2lds(const float4* g, float* l) {
  __builtin_amdgcn_global_load_lds(
      (const __attribute__((address_space(1))) void*)(g),
      (__attribute__((address_space(3))) void*)(l), 16, 0, 17);
}
// Cached variant (input written by a prior dispatch).
__device__ __forceinline__ void gl2lds_nc(const float4* g, float* l) {
  __builtin_amdgcn_global_load_lds(
      (const __attribute__((address_space(1))) void*)(g),
      (__attribute__((address_space(3))) void*)(l), 16, 0, 0);
}

// Per-producer flag wait: thread tid<NCOMP spins on producer tid's line.
__device__ __forceinline__ void wait_flags(const unsigned* f, unsigned tgt, int tid) {
  if (tid < NCOMP) {
    const unsigned* fp = f + tid * 16;
    while (__hip_atomic_load((unsigned*)fp, __ATOMIC_RELAXED,
                             __HIP_MEMORY_SCOPE_AGENT) < tgt)
      __builtin_amdgcn_s_sleep(1);
  }
  __atomic_signal_fence(__ATOMIC_SEQ_CST);
  __syncthreads();
}

__device__ __forceinline__ void pwait(const unsigned* pc, unsigned target) {
  for (;;) {
    unsigned s0 = 0;
#pragma unroll
    for (int i = 0; i < 8; ++i)
      s0 += __hip_atomic_load((unsigned*)(pc + i * 16), __ATOMIC_RELAXED,
                              __HIP_MEMORY_SCOPE_AGENT);
    if (s0 >= target) break;
    __builtin_amdgcn_s_sleep(1);
  }
  __atomic_signal_fence(__ATOMIC_SEQ_CST);
}

__device__ __forceinline__ float red16(float v) {
  v += __shfl_xor(v, 1, 16);
  v += __shfl_xor(v, 2, 16);
  v += __shfl_xor(v, 4, 16);
  v += __shfl_xor(v, 8, 16);
  return v;
}

// 48-FMA chunk dot: weights from VGPR array W, data from LDS pointer PTR.
#define CDOT48(W, PTR, RES) do {                                              \
  const float* _p = (PTR);                                                    \
  float _a0 = 0.f, _a1 = 0.f, _a2 = 0.f, _a3 = 0.f;                           \
  _Pragma("unroll")                                                           \
  for (int _i = 0; _i < 48; _i += 16) {                                       \
    float4 _v0 = *(const float4*)(_p + _i);                                   \
    float4 _v1 = *(const float4*)(_p + _i + 4);                               \
    float4 _v2 = *(const float4*)(_p + _i + 8);                               \
    float4 _v3 = *(const float4*)(_p + _i + 12);                              \
    _a0 = fmaf((W)[_i + 0], _v0.x, _a0); _a0 = fmaf((W)[_i + 1], _v0.y, _a0); \
    _a0 = fmaf((W)[_i + 2], _v0.z, _a0); _a0 = fmaf((W)[_i + 3], _v0.w, _a0); \
    _a1 = fmaf((W)[_i + 4], _v1.x, _a1); _a1 = fmaf((W)[_i + 5], _v1.y, _a1); \
    _a1 = fmaf((W)[_i + 6], _v1.z, _a1); _a1 = fmaf((W)[_i + 7], _v1.w, _a1); \
    _a2 = fmaf((W)[_i + 8], _v2.x, _a2); _a2 = fmaf((W)[_i + 9], _v2.y, _a2); \
    _a2 = fmaf((W)[_i +10], _v2.z, _a2); _a2 = fmaf((W)[_i +11], _v2.w, _a2); \
    _a3 = fmaf((W)[_i +12], _v3.x, _a3); _a3 = fmaf((W)[_i +13], _v3.y, _a3); \
    _a3 = fmaf((W)[_i +14], _v3.z, _a3); _a3 = fmaf((W)[_i +15], _v3.w, _a3); \
  }                                                                           \
  RES = (_a0 + _a1) + (_a2 + _a3);                                            \
} while (0)

// h gather: global chunked [s][r][24 ull] is LDS-linear per chunk (identity
// mapping). Per wave: 4 chunks x 3 KB. Coherent (sc0 sc1).
#define STAGE_H(SRC, DSTF) do {                                              \
  const float4* _g = (const float4*)(const void*)(SRC);                      \
  _Pragma("unroll")                                                          \
  for (int _cc = 0; _cc < 4; ++_cc) {                                        \
    int _c = wv * 4 + _cc;                                                   \
    _Pragma("unroll")                                                        \
    for (int _k = 0; _k < 3; ++_k)                                           \
      gl2lds(_g + _c * 192 + _k * 64 + ln, (DSTF) + _c * 772 + _k * 256);    \
  }                                                                          \
} while (0)

// prev gather: global [b][88 ull] -> LDS [b][176] linear. 11 x 1KB regions.
#define STAGE_PREV(PAR) do {                                                 \
  const float4* _gp = (const float4*)(const void*)(prevg + (size_t)(PAR) * 1408); \
  _Pragma("unroll")                                                          \
  for (int _j = 0; _j < 11; ++_j)                                            \
    if (wv == (_j & 3))                                                      \
      gl2lds(_gp + _j * 64 + ln, prevs + _j * 256);                          \
} while (0)

// x gather: global [t][b][768] -> LDS chunked [s][b][48] (pad 4/chunk).
#define STAGE_X(T) do {                                                      \
  const float4* _gx = (const float4*)(aco + (size_t)(T) * 12288);            \
  _Pragma("unroll")                                                          \
  for (int _cc = 0; _cc < 4; ++_cc) {                                        \
    int _c = wv * 4 + _cc;                                                   \
    _Pragma("unroll")                                                        \
    for (int _k = 0; _k < 3; ++_k) {                                         \
      int _u = _k * 64 + ln;                                                 \
      int _b = _u / 12, _m = _u - _b * 12;                                   \
      gl2lds_nc(_gx + _b * 192 + _c * 12 + _m, bufA + _c * 772 + _k * 256);  \
    }                                                                        \
  }                                                                          \
} while (0)

// ---------------------------------------------------------------------------
// K1: fused conv1+bn1+relu -> conv2+bn2+relu -> pool(1,2). (unchanged)
// ---------------------------------------------------------------------------
__global__ __launch_bounds__(256) void conv12_kernel(
    const float* __restrict__ mel,
    const float* __restrict__ c1w, const float* __restrict__ c1b,
    const float* __restrict__ bn1g, const float* __restrict__ bn1b,
    const float* __restrict__ bn1m, const float* __restrict__ bn1v,
    const float* __restrict__ c2w, const float* __restrict__ c2b,
    const float* __restrict__ bn2g, const float* __restrict__ bn2b,
    const float* __restrict__ bn2m, const float* __restrict__ bn2v,
    float* __restrict__ A, int b0)
{
  __shared__ float melS[5 * 232];
  __shared__ float x1S[12 * 3 * 232];
  __shared__ float wS[48 * 12 * 9];
  const int tid = threadIdx.x;
  const int bl = blockIdx.x >> 9;
  const int b = b0 + bl;
  const int t = blockIdx.x & 511;

  for (int idx = tid; idx < 5 * 232; idx += 256) {
    int rr = idx / 232, cc = idx - rr * 232;
    int r = t - 2 + rr, w = cc - 1;
    float v = 0.f;
    if (r >= 0 && r < 512 && w >= 0 && w < 229) v = mel[(b * 512 + r) * 229 + w];
    melS[idx] = v;
  }

  float accA[22], accB[22];
#pragma unroll
  for (int i = 0; i < 22; ++i) { accA[i] = 0.f; accB[i] = 0.f; }
  __syncthreads();

  for (int icc = 0; icc < 4; ++icc) {
    if (icc) __syncthreads();
    for (int idx = tid; idx < 12 * 3 * 232; idx += 256) {
      int cl = idx / (3 * 232);
      int rem = idx - cl * (3 * 232);
      int rr = rem / 232, cc = rem - rr * 232;
      int c = icc * 12 + cl;
      int r1 = t - 1 + rr, w = cc - 1;
      float v = 0.f;
      if (r1 >= 0 && r1 < 512 && w >= 0 && w < 229) {
        const float* cw = c1w + c * 9;
        const float* m0 = melS + rr * 232 + cc - 1;
        float s = m0[0] * cw[0] + m0[1] * cw[1] + m0[2] * cw[2]
                + m0[232] * cw[3] + m0[233] * cw[4] + m0[234] * cw[5]
                + m0[464] * cw[6] + m0[465] * cw[7] + m0[466] * cw[8];
        s += c1b[c];
        float sc = bn1g[c] * rsqrtf(bn1v[c] + 1e-5f);
        v = fmaxf(s * sc + (bn1b[c] - bn1m[c] * sc), 0.f);
      }
      x1S[idx] = v;
    }
    for (int idx = tid; idx < 48 * 12 * 9; idx += 256) {
      int oc = idx / 108, rem = idx - oc * 108;
      wS[idx] = c2w[(oc * 48 + icc * 12) * 9 + rem];
    }
    __syncthreads();
    for (int i = 0; i < 22; ++i) {
      int oidx = tid + i * 256;
      if (oidx >= 5472) break;
      int oc = oidx / 114, wp = oidx - oc * 114;
      int w0 = 2 * wp;
      float a0 = accA[i], a1 = accB[i];
      const float* wp9 = wS + oc * 108;
      for (int icl = 0; icl < 12; ++icl) {
#pragma unroll
        for (int a = 0; a < 3; ++a) {
          const float* xr = x1S + (icl * 3 + a) * 232 + w0;
          float x0 = xr[0], x1 = xr[1], x2 = xr[2], x3 = xr[3];
          float wA = wp9[icl * 9 + a * 3 + 0];
          float wB = wp9[icl * 9 + a * 3 + 1];
          float wC = wp9[icl * 9 + a * 3 + 2];
          a0 = fmaf(x0, wA, a0); a0 = fmaf(x1, wB, a0); a0 = fmaf(x2, wC, a0);
          a1 = fmaf(x1, wA, a1); a1 = fmaf(x2, wB, a1); a1 = fmaf(x3, wC, a1);
        }
      }
      accA[i] = a0; accB[i] = a1;
    }
  }
  for (int i = 0; i < 22; ++i) {
    int oidx = tid + i * 256;
    if (oidx >= 5472) break;
    int oc = oidx / 114, wp = oidx - oc * 114;
    float sc = bn2g[oc] * rsqrtf(bn2v[oc] + 1e-5f);
    float sh = bn2b[oc] - bn2m[oc] * sc;
    float v0 = fmaxf((accA[i] + c2b[oc]) * sc + sh, 0.f);
    float v1 = fmaxf((accB[i] + c2b[oc]) * sc + sh, 0.f);
    A[((bl * 48 + oc) * 512 + t) * 114 + wp] = fmaxf(v0, v1);
  }
}

// ---------------------------------------------------------------------------
// K2: conv3+bn3+relu+pool(1,2); GEMM-ready output. (unchanged)
// ---------------------------------------------------------------------------
__global__ __launch_bounds__(256) void conv3_kernel(
    const float* __restrict__ A,
    const float* __restrict__ c3w, const float* __restrict__ c3b,
    const float* __restrict__ bn3g, const float* __restrict__ bn3b,
    const float* __restrict__ bn3m, const float* __restrict__ bn3v,
    float* __restrict__ Bf)
{
  __shared__ float aS[16 * 3 * 116];
  __shared__ float wS[48 * 16 * 9];
  const int tid = threadIdx.x;
  const int bl = blockIdx.x / 510;
  const int t = blockIdx.x - bl * 510;

  for (int ocg = 0; ocg < 2; ++ocg) {
    float accA[11], accB[11];
#pragma unroll
    for (int i = 0; i < 11; ++i) { accA[i] = 0.f; accB[i] = 0.f; }
    for (int icc = 0; icc < 3; ++icc) {
      __syncthreads();
      for (int idx = tid; idx < 16 * 3 * 116; idx += 256) {
        int cl = idx / 348, rem = idx - cl * 348;
        int rr = rem / 116, cc = rem - rr * 116;
        int w = cc - 1;
        float v = 0.f;
        if (w >= 0 && w < 114) v = A[((bl * 48 + icc * 16 + cl) * 512 + t + rr) * 114 + w];
        aS[idx] = v;
      }
      for (int idx = tid; idx < 48 * 16 * 9; idx += 256) {
        int ocl = idx / 144, rem = idx - ocl * 144;
        wS[idx] = c3w[((ocg * 48 + ocl) * 48 + icc * 16) * 9 + rem];
      }
      __syncthreads();
      for (int i = 0; i < 11; ++i) {
        int oidx = tid + i * 256;
        if (oidx >= 2736) break;
        int ocl = oidx / 57, wp = oidx - ocl * 57;
        int w0 = 2 * wp;
        float a0 = accA[i], a1 = accB[i];
        const float* wb = wS + ocl * 144;
        for (int icl = 0; icl < 16; ++icl) {
#pragma unroll
          for (int a = 0; a < 3; ++a) {
            const float* xr = aS + (icl * 3 + a) * 116 + w0;
            float x0 = xr[0], x1 = xr[1], x2 = xr[2], x3 = xr[3];
            float wA = wb[icl * 9 + a * 3 + 0];
            float wB = wb[icl * 9 + a * 3 + 1];
            float wC = wb[icl * 9 + a * 3 + 2];
            a0 = fmaf(x0, wA, a0); a0 = fmaf(x1, wB, a0); a0 = fmaf(x2, wC, a0);
            a1 = fmaf(x1, wA, a1); a1 = fmaf(x2, wB, a1); a1 = fmaf(x3, wC, a1);
          }
        }
        accA[i] = a0; accB[i] = a1;
      }
    }
    for (int i = 0; i < 11; ++i) {
      int oidx = tid + i * 256;
      if (oidx >= 2736) break;
      int ocl = oidx / 57, wp = oidx - ocl * 57;
      int oc = ocg * 48 + ocl;
      float sc = bn3g[oc] * rsqrtf(bn3v[oc] + 1e-5f);
      float sh = bn3b[oc] - bn3m[oc] * sc;
      float v0 = fmaxf((accA[i] + c3b[oc]) * sc + sh, 0.f);
      float v1 = fmaxf((accB[i] + c3b[oc]) * sc + sh, 0.f);
      Bf[(size_t)(bl * 510 + t) * 5472 + oc * 57 + wp] = fmaxf(v0, v1);
    }
  }
}

// ---------------------------------------------------------------------------
// K3: fp32 NT GEMM  C = A * B^T + bias, output relaid to [t][16][768].
// ---------------------------------------------------------------------------
__global__ __launch_bounds__(256) void gemm_nt(
    const float* __restrict__ Am, const float* __restrict__ Bm,
    const float* __restrict__ bias, float* __restrict__ C,
    int M, int K, int lda, int ldb, int b0)
{
  __shared__ float As[64 * 33];
  __shared__ float Bs[64 * 33];
  const int tid = threadIdx.x;
  const int m0 = blockIdx.x * 64, n0 = blockIdx.y * 64;
  const int tx = tid & 15, ty = tid >> 4;
  const int kq = (tid & 7) * 4, rw = tid >> 3;
  float acc[4][4];
#pragma unroll
  for (int i = 0; i < 4; ++i)
#pragma unroll
    for (int j = 0; j < 4; ++j) acc[i][j] = 0.f;

  for (int k0 = 0; k0 < K; k0 += 32) {
    int m1 = m0 + rw, m2 = m1 + 32;
    float4 va = make_float4(0.f, 0.f, 0.f, 0.f), vb = va;
    if (m1 < M) va = *(const float4*)(Am + (size_t)m1 * lda + k0 + kq);
    if (m2 < M) vb = *(const float4*)(Am + (size_t)m2 * lda + k0 + kq);
    float4 wa = *(const float4*)(Bm + (size_t)(n0 + rw) * ldb + k0 + kq);
    float4 wb = *(const float4*)(Bm + (size_t)(n0 + rw + 32) * ldb + k0 + kq);
    As[rw * 33 + kq + 0] = va.x; As[rw * 33 + kq + 1] = va.y;
    As[rw * 33 + kq + 2] = va.z; As[rw * 33 + kq + 3] = va.w;
    As[(rw + 32) * 33 + kq + 0] = vb.x; As[(rw + 32) * 33 + kq + 1] = vb.y;
    As[(rw + 32) * 33 + kq + 2] = vb.z; As[(rw + 32) * 33 + kq + 3] = vb.w;
    Bs[rw * 33 + kq + 0] = wa.x; Bs[rw * 33 + kq + 1] = wa.y;
    Bs[rw * 33 + kq + 2] = wa.z; Bs[rw * 33 + kq + 3] = wa.w;
    Bs[(rw + 32) * 33 + kq + 0] = wb.x; Bs[(rw + 32) * 33 + kq + 1] = wb.y;
    Bs[(rw + 32) * 33 + kq + 2] = wb.z; Bs[(rw + 32) * 33 + kq + 3] = wb.w;
    __syncthreads();
#pragma unroll 8
    for (int k = 0; k < 32; ++k) {
      float av[4], bv[4];
#pragma unroll
      for (int i = 0; i < 4; ++i) av[i] = As[(ty * 4 + i) * 33 + k];
#pragma unroll
      for (int j = 0; j < 4; ++j) bv[j] = Bs[(tx * 4 + j) * 33 + k];
#pragma unroll
      for (int i = 0; i < 4; ++i)
#pragma unroll
        for (int j = 0; j < 4; ++j) acc[i][j] = fmaf(av[i], bv[j], acc[i][j]);
    }
    __syncthreads();
  }
#pragma unroll
  for (int i = 0; i < 4; ++i) {
    int m = m0 + ty * 4 + i;
    if (m >= M) continue;
    int bl2 = m / 510, tt2 = m - bl2 * 510;
    float* crow = C + ((size_t)tt2 * 16 + (b0 + bl2)) * 768;
#pragma unroll
    for (int j = 0; j < 4; ++j) {
      int n = n0 + tx * 4 + j;
      crow[n] = acc[i][j] + bias[n];
    }
  }
}

// ---------------------------------------------------------------------------
__global__ void init_state(ull* __restrict__ h1g, ull* __restrict__ h2g,
                           ull* __restrict__ prevg, unsigned* __restrict__ bar) {
  int gid = blockIdx.x * 256 + threadIdx.x;
  if (gid < 12288) { at_store(h1g + gid, 0ull); at_store(h2g + gid, 0ull); }
  if (gid < 2816) at_store(prevg + gid, 0ull);
  if (gid < BAR_U32)
    __hip_atomic_store(bar + gid, 0u, __ATOMIC_RELAXED, __HIP_MEMORY_SCOPE_AGENT);
}

// ---------------------------------------------------------------------------
// K6: persistent LSTM. 192 compute + 44 proj blocks; gathers via coherent
// global_load_lds.
// ---------------------------------------------------------------------------
__global__ __launch_bounds__(256, 1) void lstm_kernel(
    const float* __restrict__ aco,   // [510][16][768]
    const float* __restrict__ whh0,  // [3072][768]
    const float* __restrict__ wih0,  // [3072][944]
    const float* __restrict__ wih1,  // [3072][768]
    const float* __restrict__ whh1,  // [3072][768]
    const float* __restrict__ bih0, const float* __restrict__ bhh0,
    const float* __restrict__ bih1, const float* __restrict__ bhh1,
    const float* __restrict__ pw,    // [440][768]
    const float* __restrict__ pb,
    const float* __restrict__ emb,   // [5][2]
    ull* __restrict__ h1g,           // [2][6144] chunked
    ull* __restrict__ h2g,           // [2][6144] chunked
    ull* __restrict__ prevg,         // [2][16][88]
    unsigned* __restrict__ bar,
    float* __restrict__ out)         // [16][510][440]
{
  __shared__ float bufA[16 * 772];   // x (compute) / h2 (proj)
  __shared__ float bufB[16 * 772];   // h1
  __shared__ float bufC[16 * 772];   // h2(t-1)
  __shared__ float prevs[16 * 176];  // [b][176] pad-free
  __shared__ float zl[16 * 17];
  __shared__ float harr[64];
  __shared__ float embS[10];
  const int tid = threadIdx.x;
  const int s = tid & 15;
  const int r = tid >> 4;
  const int wv = tid >> 6;           // wave index
  const int ln = tid & 63;           // lane
  unsigned* f1 = bar + F1_OFF;
  unsigned* f2 = bar + F2_OFF;
  unsigned* pc = bar + PC_OFF;

  if (blockIdx.x < NCOMP) {
    // =======================================================================
    // COMPUTE BLOCK
    // =======================================================================
    const int uB = blockIdx.x * 4;
    const int j = (r >> 2) * 768 + uB + (r & 3);

    float wx[48], w0[48], w1[48], w2[48], wp[11];
    {
      const float* p = wih0 + (size_t)j * 944 + 48 * s;
#pragma unroll
      for (int i = 0; i < 48; i += 4) {
        float4 v = *(const float4*)(p + i);
        wx[i] = v.x; wx[i+1] = v.y; wx[i+2] = v.z; wx[i+3] = v.w;
      }
      p = whh0 + (size_t)j * 768 + 48 * s;
#pragma unroll
      for (int i = 0; i < 48; i += 4) {
        float4 v = *(const float4*)(p + i);
        w0[i] = v.x; w0[i+1] = v.y; w0[i+2] = v.z; w0[i+3] = v.w;
      }
      p = wih1 + (size_t)j * 768 + 48 * s;
#pragma unroll
      for (int i = 0; i < 48; i += 4) {
        float4 v = *(const float4*)(p + i);
        w1[i] = v.x; w1[i+1] = v.y; w1[i+2] = v.z; w1[i+3] = v.w;
      }
      p = whh1 + (size_t)j * 768 + 48 * s;
#pragma unroll
      for (int i = 0; i < 48; i += 4) {
        float4 v = *(const float4*)(p + i);
        w2[i] = v.x; w2[i+1] = v.y; w2[i+2] = v.z; w2[i+3] = v.w;
      }
      const float* pp = wih0 + (size_t)j * 944 + 768 + 11 * s;
#pragma unroll
      for (int i = 0; i < 11; ++i) wp[i] = pp[i];
    }
    float bl1[4], bl2[4], c1 = 0.f, c2 = 0.f;
    if (tid < 64) {
      int ul = tid >> 4;
#pragma unroll
      for (int g = 0; g < 4; ++g) {
        int jj = g * 768 + uB + ul;
        bl1[g] = bih0[jj] + bhh0[jj];
        bl2[g] = bih1[jj] + bhh1[jj];
      }
    }
    const int hdst = (blockIdx.x / 12) * 384 + (blockIdx.x % 12) * 2;

    // h1(-1) = 0, h2(-1) = 0
    for (int i = tid; i < 16 * 772; i += 256) { bufB[i] = 0.f; bufC[i] = 0.f; }

    // prologue: x(0) stage + dot
    float zxr[16];
    STAGE_X(0);
    __syncthreads();
#pragma unroll 4
    for (int b = 0; b < 16; ++b) {
      float p; CDOT48(wx, bufA + s * 772 + b * 48, p);
      zxr[b] = red16(p);
    }

    for (int t = 0; t < 510; ++t) {
      const int wbuf = t & 1, rbuf = wbuf ^ 1;
      __syncthreads();
      // ---- w0 dot: bufB = h1(t-1) (overlaps proj blocks' step-(t-1) tail) --
#pragma unroll 4
      for (int b = 0; b < 16; ++b) {
        float p; CDOT48(w0, bufB + s * 772 + b * 48, p);
        p = red16(p);
        if (s == 0) zl[r * 17 + b] = zxr[b] + p;
      }
      // ---- prev(t-1) ready wait ----
      if (tid == 0 && t) pwait(pc, (unsigned)(NPROJ * t));
      __syncthreads();
      // ---- prefetch h2(t-1) -> bufC; stage prev (init zeroed both parity) --
      STAGE_H(h2g + rbuf * 6144, bufC);
      STAGE_PREV(rbuf);
      __syncthreads();
#pragma unroll 4
      for (int b = 0; b < 16; ++b) {
        const float* pvv = prevs + b * 176 + s * 11;
        float p = 0.f;
#pragma unroll
        for (int i = 0; i < 11; ++i) p = fmaf(wp[i], pvv[i], p);
        p = red16(p);
        if (s == 0) zl[r * 17 + b] += p;
      }
      __syncthreads();
      // ---- cell 1 ----
      if (tid < 64) {
        int ul = tid >> 4, bb = tid & 15;
        float zi = zl[(0 * 4 + ul) * 17 + bb] + bl1[0];
        float zf = zl[(1 * 4 + ul) * 17 + bb] + bl1[1];
        float zg = zl[(2 * 4 + ul) * 17 + bb] + bl1[2];
        float zo = zl[(3 * 4 + ul) * 17 + bb] + bl1[3];
        c1 = sigf(zf) * c1 + sigf(zi) * tanhf(zg);
        harr[tid] = sigf(zo) * tanhf(c1);
      }
      __syncthreads();
      // ---- publish h1(t) ----
      if (tid < 32) {
        int q = tid >> 4, bb = tid & 15;
        at_store(h1g + wbuf * 6144 + hdst + bb * 24 + q,
                 pack2(harr[(2 * q) * 16 + bb], harr[(2 * q + 1) * 16 + bb]));
      }
      if (tid == 0) {
        __builtin_amdgcn_s_waitcnt(0);
        __atomic_signal_fence(__ATOMIC_SEQ_CST);
        __hip_atomic_store(f1 + blockIdx.x * 16, (unsigned)(t + 1),
                           __ATOMIC_RELAXED, __HIP_MEMORY_SCOPE_AGENT);
      }
      // ---- pipelined x(t+1) stage + dot (hides f1 skew) ----
      if (t < 509) {
        STAGE_X(t + 1);
        __syncthreads();
#pragma unroll 4
        for (int b = 0; b < 16; ++b) {
          float p; CDOT48(wx, bufA + s * 772 + b * 48, p);
          zxr[b] = red16(p);
        }
      }
      // ---- f1 wait, stage h1(t), fused w1/w2 dot ----
      wait_flags(f1, (unsigned)(t + 1), tid);
      STAGE_H(h1g + wbuf * 6144, bufB);
      __syncthreads();
#pragma unroll 2
      for (int b = 0; b < 16; ++b) {
        float p1, p2;
        CDOT48(w1, bufB + s * 772 + b * 48, p1);
        CDOT48(w2, bufC + s * 772 + b * 48, p2);
        float p = red16(p1 + p2);
        if (s == 0) zl[r * 17 + b] = p;
      }
      __syncthreads();
      // ---- cell 2 ----
      if (tid < 64) {
        int ul = tid >> 4, bb = tid & 15;
        float zi = zl[(0 * 4 + ul) * 17 + bb] + bl2[0];
        float zf = zl[(1 * 4 + ul) * 17 + bb] + bl2[1];
        float zg = zl[(2 * 4 + ul) * 17 + bb] + bl2[2];
        float zo = zl[(3 * 4 + ul) * 17 + bb] + bl2[3];
        c2 = sigf(zf) * c2 + sigf(zi) * tanhf(zg);
        harr[tid] = sigf(zo) * tanhf(c2);
      }
      __syncthreads();
      // ---- publish h2(t) ----
      if (tid < 32) {
        int q = tid >> 4, bb = tid & 15;
        at_store(h2g + wbuf * 6144 + hdst + bb * 24 + q,
                 pack2(harr[(2 * q) * 16 + bb], harr[(2 * q + 1) * 16 + bb]));
      }
      if (tid == 0) {
        __builtin_amdgcn_s_waitcnt(0);
        __atomic_signal_fence(__ATOMIC_SEQ_CST);
        __hip_atomic_store(f2 + blockIdx.x * 16, (unsigned)(t + 1),
                           __ATOMIC_RELAXED, __HIP_MEMORY_SCOPE_AGENT);
      }
    }
  } else {
    // =======================================================================
    // PROJECTION BLOCK: 10 logit rows (2 argmax groups), all 16 batches.
    // =======================================================================
    const int bp = blockIdx.x - NCOMP;   // 0..43
    const int prow = bp * 10 + r;        // valid for r < 10
    float pwr[48];
    float pbv = 0.f;
    if (r < 10) {
      const float* p = pw + (size_t)prow * 768 + 48 * s;
#pragma unroll
      for (int i = 0; i < 48; i += 4) {
        float4 v = *(const float4*)(p + i);
        pwr[i] = v.x; pwr[i+1] = v.y; pwr[i+2] = v.z; pwr[i+3] = v.w;
      }
      pbv = pb[prow];
    } else {
#pragma unroll
      for (int i = 0; i < 48; ++i) pwr[i] = 0.f;
    }
    if (tid < 10) embS[tid] = emb[tid];
    __syncthreads();

    for (int t = 0; t < 510; ++t) {
      const int wbuf = t & 1;
      wait_flags(f2, (unsigned)(t + 1), tid);
      STAGE_H(h2g + wbuf * 6144, bufA);
      __syncthreads();
#pragma unroll 4
      for (int b = 0; b < 16; ++b) {
        float p; CDOT48(pwr, bufA + s * 772 + b * 48, p);
        p = red16(p);
        if (r < 10 && s == 0) {
          float lg = p + pbv;
          out[((size_t)b * 510 + t) * 440 + prow] = lg;
          zl[r * 17 + b] = lg;
        }
      }
      __syncthreads();
      if (tid < 32) {
        int q = tid >> 4, bb = tid & 15;
        float best = zl[(q * 5) * 17 + bb]; int bi = 0;
#pragma unroll
        for (int c = 1; c < 5; ++c) {
          float v = zl[(q * 5 + c) * 17 + bb];
          if (v > best) { best = v; bi = c; }
        }
        at_store(prevg + wbuf * 1408 + bb * 88 + bp * 2 + q,
                 pack2(embS[bi * 2], embS[bi * 2 + 1]));
      }
      __syncthreads();
      if (tid == 0) {
        __builtin_amdgcn_s_waitcnt(0);
        __atomic_signal_fence(__ATOMIC_SEQ_CST);
        __hip_atomic_fetch_add(pc + (bp & 7) * 16, 1u,
                               __ATOMIC_RELAXED, __HIP_MEMORY_SCOPE_AGENT);
      }
    }
  }
}

// ---------------------------------------------------------------------------
extern "C" void kernel_launch(void* const* d_in, const int* in_sizes, int n_in,
                              void* d_out, int out_size, void* d_ws, size_t ws_size,
                              hipStream_t stream) {
  (void)in_sizes; (void)n_in; (void)out_size;
  const float* mel  = (const float*)d_in[0];
  const float* c1w  = (const float*)d_in[1];
  const float* c1b  = (const float*)d_in[2];
  const float* c2w  = (const float*)d_in[3];
  const float* c2b  = (const float*)d_in[4];
  const float* c3w  = (const float*)d_in[5];
  const float* c3b  = (const float*)d_in[6];
  const float* bn1g = (const float*)d_in[7];
  const float* bn1b = (const float*)d_in[8];
  const float* bn1m = (const float*)d_in[9];
  const float* bn1v = (const float*)d_in[10];
  const float* bn2g = (const float*)d_in[11];
  const float* bn2b = (const float*)d_in[12];
  const float* bn2m = (const float*)d_in[13];
  const float* bn2v = (const float*)d_in[14];
  const float* bn3g = (const float*)d_in[15];
  const float* bn3b = (const float*)d_in[16];
  const float* bn3m = (const float*)d_in[17];
  const float* bn3v = (const float*)d_in[18];
  const float* fcw  = (const float*)d_in[19];
  const float* fcb  = (const float*)d_in[20];
  const float* wih0 = (const float*)d_in[21];
  const float* whh0 = (const float*)d_in[22];
  const float* bih0 = (const float*)d_in[23];
  const float* bhh0 = (const float*)d_in[24];
  const float* wih1 = (const float*)d_in[25];
  const float* whh1 = (const float*)d_in[26];
  const float* bih1 = (const float*)d_in[27];
  const float* bhh1 = (const float*)d_in[28];
  const float* pw   = (const float*)d_in[29];
  const float* pb   = (const float*)d_in[30];
  const float* emb  = (const float*)d_in[31];

  float* ws = (float*)d_ws;
  float* outp = (float*)d_out;

  const size_t ST_ULL = 12288ull + 12288ull + 2816ull;
  int CB = 1;
  for (int cb = 4; cb >= 1; cb >>= 1) {
    size_t need = (ACO_FL + (size_t)cb * 48 * 512 * 114 + (size_t)cb * 510 * 5472) * 4
                + ST_ULL * 8 + BAR_U32 * 4 + 1024;
    if (ws_size >= need) { CB = cb; break; }
  }
  const int nchunks = 16 / CB;
  const size_t A_FL  = (size_t)CB * 48 * 512 * 114;
  const size_t BF_FL = (size_t)CB * 510 * 5472;

  float* aco = ws;                       // [510][16][768]
  float* Ac  = ws + ACO_FL;
  float* Bfc = Ac + A_FL;
  ull* h1g   = (ull*)(Bfc + BF_FL);
  ull* h2g   = h1g + 12288;
  ull* prevg = h2g + 12288;
  unsigned* bar = (unsigned*)(prevg + 2816);

  for (int ch = 0; ch < nchunks; ++ch) {
    int b0 = ch * CB;
    hipLaunchKernelGGL(conv12_kernel, dim3(CB * 512), dim3(256), 0, stream,
                       mel, c1w, c1b, bn1g, bn1b, bn1m, bn1v,
                       c2w, c2b, bn2g, bn2b, bn2m, bn2v, Ac, b0);
    hipLaunchKernelGGL(conv3_kernel, dim3(CB * 510), dim3(256), 0, stream,
                       Ac, c3w, c3b, bn3g, bn3b, bn3m, bn3v, Bfc);
    int M = CB * 510;
    hipLaunchKernelGGL(gemm_nt, dim3((M + 63) / 64, 12), dim3(256), 0, stream,
                       Bfc, fcw, fcb, aco, M, 5472, 5472, 5472, b0);
  }
  hipLaunchKernelGGL(init_state, dim3(48), dim3(256), 0, stream,
                     h1g, h2g, prevg, bar);

  {
    void* args[] = {
      (void*)&aco, (void*)&whh0, (void*)&wih0, (void*)&wih1, (void*)&whh1,
      (void*)&bih0, (void*)&bhh0, (void*)&bih1, (void*)&bhh1,
      (void*)&pw, (void*)&pb, (void*)&emb,
      (void*)&h1g, (void*)&h2g, (void*)&prevg, (void*)&bar, (void*)&outp
    };
    hipError_t e = hipLaunchCooperativeKernel((const void*)lstm_kernel,
                                              dim3(NCOMP + NPROJ), dim3(256),
                                              args, 0, stream);
    if (e != hipSuccess) {
      (void)hipGetLastError();
      hipLaunchKernelGGL(lstm_kernel, dim3(NCOMP + NPROJ), dim3(256), 0, stream,
                         aco, whh0, wih0, wih1, whh1, bih0, bhh0, bih1, bhh1,
                         pw, pb, emb, h1g, h2g, prevg, bar, outp);
    }
  }
}

// Round 6
// 24843.314 us; speedup vs baseline: 1.6468x; 1.0402x over previous
//
#include <hip/hip_runtime.h>
#include <math.h>

// ============================================================================
// AR_Transcriber round 11.
// r10 (coherent global_load_lds gather) -> steady 18.05ms, VALU 17%. Remaining
// ~20us/step unexplained by dots+RVs. Theory: polling self-contention -- each
// waiting block sweeps up to 192 coherent flag lines at s_sleep(1) pace,
// ~45K LLC loads/sweep x 236 blocks colliding with data stages.
// This round (sync/schedule only, data path unchanged):
//  1. Poll backoff: check-then-s_sleep(4) in all waits (4x less traffic).
//  2. pwait (serial 8-line RMW-counter sweep) -> 44 per-proj flags polled
//     one-per-thread in parallel; no per-step RMWs.
//  3. h1/h2 publish via intra-wave shfl (no harr LDS hop, one fewer barrier,
//     flag in same-wave program order).
//  4. STAGE_X(t+1) issued at step start; drains at existing post-w0 barrier,
//     so the wx-dot fully fills the f1-hide window.
// ============================================================================

typedef unsigned long long ull;

#define ACO_FL 6266880ull  // 510*16*768
#define F1_OFF 0           // 192 flags * 16 u32 stride
#define F2_OFF 3072
#define FP_OFF 6144        // 44 proj flags * 16 u32 stride
#define BAR_U32 8192
#define NCOMP 192
#define NPROJ 44

__device__ __forceinline__ float sigf(float x) { return 1.0f / (1.0f + expf(-x)); }

__device__ __forceinline__ ull pack2(float x, float y) {
  union { float f[2]; ull u; } c; c.f[0] = x; c.f[1] = y; return c.u;
}
__device__ __forceinline__ ull at_load(const ull* p) {
  return __hip_atomic_load((ull*)p, __ATOMIC_RELAXED, __HIP_MEMORY_SCOPE_AGENT);
}
__device__ __forceinline__ void at_store(ull* p, ull v) {
  __hip_atomic_store(p, v, __ATOMIC_RELAXED, __HIP_MEMORY_SCOPE_AGENT);
}

// Device-coherent (sc0|sc1 = 17) global -> LDS direct copy, 16B/lane.
__device__ __forceinline__ void gl2lds(const float4* g, float* l) {
  __builtin_amdgcn_global_load_lds(
      (const __attribute__((address_space(1))) void*)(g),
      (__attribute__((address_space(3))) void*)(l), 16, 0, 17);
}
// Cached variant (input written by a prior dispatch).
__device__ __forceinline__ void gl2lds_nc(const float4* g, float* l) {
  __builtin_amdgcn_global_load_lds(
      (const __attribute__((address_space(1))) void*)(g),
      (__attribute__((address_space(3))) void*)(l), 16, 0, 0);
}

// Parallel per-producer flag wait with backoff: thread tid<n polls line tid.
__device__ __forceinline__ void wait_flags_n(const unsigned* f, unsigned tgt,
                                             int tid, int n) {
  if (tid < n) {
    const unsigned* fp = f + tid * 16;
    unsigned v = __hip_atomic_load((unsigned*)fp, __ATOMIC_RELAXED,
                                   __HIP_MEMORY_SCOPE_AGENT);
    while (v < tgt) {
      __builtin_amdgcn_s_sleep(4);
      v = __hip_atomic_load((unsigned*)fp, __ATOMIC_RELAXED,
                            __HIP_MEMORY_SCOPE_AGENT);
    }
  }
  __atomic_signal_fence(__ATOMIC_SEQ_CST);
  __syncthreads();
}

__device__ __forceinline__ float red16(float v) {
  v += __shfl_xor(v, 1, 16);
  v += __shfl_xor(v, 2, 16);
  v += __shfl_xor(v, 4, 16);
  v += __shfl_xor(v, 8, 16);
  return v;
}

// 48-FMA chunk dot: weights from VGPR array W, data from LDS pointer PTR.
#define CDOT48(W, PTR, RES) do {                                              \
  const float* _p = (PTR);                                                    \
  float _a0 = 0.f, _a1 = 0.f, _a2 = 0.f, _a3 = 0.f;                           \
  _Pragma("unroll")                                                           \
  for (int _i = 0; _i < 48; _i += 16) {                                       \
    float4 _v0 = *(const float4*)(_p + _i);                                   \
    float4 _v1 = *(const float4*)(_p + _i + 4);                               \
    float4 _v2 = *(const float4*)(_p + _i + 8);                               \
    float4 _v3 = *(const float4*)(_p + _i + 12);                              \
    _a0 = fmaf((W)[_i + 0], _v0.x, _a0); _a0 = fmaf((W)[_i + 1], _v0.y, _a0); \
    _a0 = fmaf((W)[_i + 2], _v0.z, _a0); _a0 = fmaf((W)[_i + 3], _v0.w, _a0); \
    _a1 = fmaf((W)[_i + 4], _v1.x, _a1); _a1 = fmaf((W)[_i + 5], _v1.y, _a1); \
    _a1 = fmaf((W)[_i + 6], _v1.z, _a1); _a1 = fmaf((W)[_i + 7], _v1.w, _a1); \
    _a2 = fmaf((W)[_i + 8], _v2.x, _a2); _a2 = fmaf((W)[_i + 9], _v2.y, _a2); \
    _a2 = fmaf((W)[_i +10], _v2.z, _a2); _a2 = fmaf((W)[_i +11], _v2.w, _a2); \
    _a3 = fmaf((W)[_i +12], _v3.x, _a3); _a3 = fmaf((W)[_i +13], _v3.y, _a3); \
    _a3 = fmaf((W)[_i +14], _v3.z, _a3); _a3 = fmaf((W)[_i +15], _v3.w, _a3); \
  }                                                                           \
  RES = (_a0 + _a1) + (_a2 + _a3);                                            \
} while (0)

// h gather: global chunked [s][r][24 ull] is LDS-linear per chunk.
#define STAGE_H(SRC, DSTF) do {                                              \
  const float4* _g = (const float4*)(const void*)(SRC);                      \
  _Pragma("unroll")                                                          \
  for (int _cc = 0; _cc < 4; ++_cc) {                                        \
    int _c = wv * 4 + _cc;                                                   \
    _Pragma("unroll")                                                        \
    for (int _k = 0; _k < 3; ++_k)                                           \
      gl2lds(_g + _c * 192 + _k * 64 + ln, (DSTF) + _c * 772 + _k * 256);    \
  }                                                                          \
} while (0)

// prev gather: global [b][88 ull] -> LDS [b][176] linear.
#define STAGE_PREV(PAR) do {                                                 \
  const float4* _gp = (const float4*)(const void*)(prevg + (size_t)(PAR) * 1408); \
  _Pragma("unroll")                                                          \
  for (int _j = 0; _j < 11; ++_j)                                            \
    if (wv == (_j & 3))                                                      \
      gl2lds(_gp + _j * 64 + ln, prevs + _j * 256);                          \
} while (0)

// x gather: global [t][b][768] -> LDS chunked [s][b][48] (pad 4/chunk).
#define STAGE_X(T) do {                                                      \
  const float4* _gx = (const float4*)(aco + (size_t)(T) * 12288);            \
  _Pragma("unroll")                                                          \
  for (int _cc = 0; _cc < 4; ++_cc) {                                        \
    int _c = wv * 4 + _cc;                                                   \
    _Pragma("unroll")                                                        \
    for (int _k = 0; _k < 3; ++_k) {                                         \
      int _u = _k * 64 + ln;                                                 \
      int _b = _u / 12, _m = _u - _b * 12;                                   \
      gl2lds_nc(_gx + _b * 192 + _c * 12 + _m, bufA + _c * 772 + _k * 256);  \
    }                                                                        \
  }                                                                          \
} while (0)

// ---------------------------------------------------------------------------
// K1: fused conv1+bn1+relu -> conv2+bn2+relu -> pool(1,2). (unchanged)
// ---------------------------------------------------------------------------
__global__ __launch_bounds__(256) void conv12_kernel(
    const float* __restrict__ mel,
    const float* __restrict__ c1w, const float* __restrict__ c1b,
    const float* __restrict__ bn1g, const float* __restrict__ bn1b,
    const float* __restrict__ bn1m, const float* __restrict__ bn1v,
    const float* __restrict__ c2w, const float* __restrict__ c2b,
    const float* __restrict__ bn2g, const float* __restrict__ bn2b,
    const float* __restrict__ bn2m, const float* __restrict__ bn2v,
    float* __restrict__ A, int b0)
{
  __shared__ float melS[5 * 232];
  __shared__ float x1S[12 * 3 * 232];
  __shared__ float wS[48 * 12 * 9];
  const int tid = threadIdx.x;
  const int bl = blockIdx.x >> 9;
  const int b = b0 + bl;
  const int t = blockIdx.x & 511;

  for (int idx = tid; idx < 5 * 232; idx += 256) {
    int rr = idx / 232, cc = idx - rr * 232;
    int r = t - 2 + rr, w = cc - 1;
    float v = 0.f;
    if (r >= 0 && r < 512 && w >= 0 && w < 229) v = mel[(b * 512 + r) * 229 + w];
    melS[idx] = v;
  }

  float accA[22], accB[22];
#pragma unroll
  for (int i = 0; i < 22; ++i) { accA[i] = 0.f; accB[i] = 0.f; }
  __syncthreads();

  for (int icc = 0; icc < 4; ++icc) {
    if (icc) __syncthreads();
    for (int idx = tid; idx < 12 * 3 * 232; idx += 256) {
      int cl = idx / (3 * 232);
      int rem = idx - cl * (3 * 232);
      int rr = rem / 232, cc = rem - rr * 232;
      int c = icc * 12 + cl;
      int r1 = t - 1 + rr, w = cc - 1;
      float v = 0.f;
      if (r1 >= 0 && r1 < 512 && w >= 0 && w < 229) {
        const float* cw = c1w + c * 9;
        const float* m0 = melS + rr * 232 + cc - 1;
        float s = m0[0] * cw[0] + m0[1] * cw[1] + m0[2] * cw[2]
                + m0[232] * cw[3] + m0[233] * cw[4] + m0[234] * cw[5]
                + m0[464] * cw[6] + m0[465] * cw[7] + m0[466] * cw[8];
        s += c1b[c];
        float sc = bn1g[c] * rsqrtf(bn1v[c] + 1e-5f);
        v = fmaxf(s * sc + (bn1b[c] - bn1m[c] * sc), 0.f);
      }
      x1S[idx] = v;
    }
    for (int idx = tid; idx < 48 * 12 * 9; idx += 256) {
      int oc = idx / 108, rem = idx - oc * 108;
      wS[idx] = c2w[(oc * 48 + icc * 12) * 9 + rem];
    }
    __syncthreads();
    for (int i = 0; i < 22; ++i) {
      int oidx = tid + i * 256;
      if (oidx >= 5472) break;
      int oc = oidx / 114, wp = oidx - oc * 114;
      int w0 = 2 * wp;
      float a0 = accA[i], a1 = accB[i];
      const float* wp9 = wS + oc * 108;
      for (int icl = 0; icl < 12; ++icl) {
#pragma unroll
        for (int a = 0; a < 3; ++a) {
          const float* xr = x1S + (icl * 3 + a) * 232 + w0;
          float x0 = xr[0], x1 = xr[1], x2 = xr[2], x3 = xr[3];
          float wA = wp9[icl * 9 + a * 3 + 0];
          float wB = wp9[icl * 9 + a * 3 + 1];
          float wC = wp9[icl * 9 + a * 3 + 2];
          a0 = fmaf(x0, wA, a0); a0 = fmaf(x1, wB, a0); a0 = fmaf(x2, wC, a0);
          a1 = fmaf(x1, wA, a1); a1 = fmaf(x2, wB, a1); a1 = fmaf(x3, wC, a1);
        }
      }
      accA[i] = a0; accB[i] = a1;
    }
  }
  for (int i = 0; i < 22; ++i) {
    int oidx = tid + i * 256;
    if (oidx >= 5472) break;
    int oc = oidx / 114, wp = oidx - oc * 114;
    float sc = bn2g[oc] * rsqrtf(bn2v[oc] + 1e-5f);
    float sh = bn2b[oc] - bn2m[oc] * sc;
    float v0 = fmaxf((accA[i] + c2b[oc]) * sc + sh, 0.f);
    float v1 = fmaxf((accB[i] + c2b[oc]) * sc + sh, 0.f);
    A[((bl * 48 + oc) * 512 + t) * 114 + wp] = fmaxf(v0, v1);
  }
}

// ---------------------------------------------------------------------------
// K2: conv3+bn3+relu+pool(1,2); GEMM-ready output. (unchanged)
// ---------------------------------------------------------------------------
__global__ __launch_bounds__(256) void conv3_kernel(
    const float* __restrict__ A,
    const float* __restrict__ c3w, const float* __restrict__ c3b,
    const float* __restrict__ bn3g, const float* __restrict__ bn3b,
    const float* __restrict__ bn3m, const float* __restrict__ bn3v,
    float* __restrict__ Bf)
{
  __shared__ float aS[16 * 3 * 116];
  __shared__ float wS[48 * 16 * 9];
  const int tid = threadIdx.x;
  const int bl = blockIdx.x / 510;
  const int t = blockIdx.x - bl * 510;

  for (int ocg = 0; ocg < 2; ++ocg) {
    float accA[11], accB[11];
#pragma unroll
    for (int i = 0; i < 11; ++i) { accA[i] = 0.f; accB[i] = 0.f; }
    for (int icc = 0; icc < 3; ++icc) {
      __syncthreads();
      for (int idx = tid; idx < 16 * 3 * 116; idx += 256) {
        int cl = idx / 348, rem = idx - cl * 348;
        int rr = rem / 116, cc = rem - rr * 116;
        int w = cc - 1;
        float v = 0.f;
        if (w >= 0 && w < 114) v = A[((bl * 48 + icc * 16 + cl) * 512 + t + rr) * 114 + w];
        aS[idx] = v;
      }
      for (int idx = tid; idx < 48 * 16 * 9; idx += 256) {
        int ocl = idx / 144, rem = idx - ocl * 144;
        wS[idx] = c3w[((ocg * 48 + ocl) * 48 + icc * 16) * 9 + rem];
      }
      __syncthreads();
      for (int i = 0; i < 11; ++i) {
        int oidx = tid + i * 256;
        if (oidx >= 2736) break;
        int ocl = oidx / 57, wp = oidx - ocl * 57;
        int w0 = 2 * wp;
        float a0 = accA[i], a1 = accB[i];
        const float* wb = wS + ocl * 144;
        for (int icl = 0; icl < 16; ++icl) {
#pragma unroll
          for (int a = 0; a < 3; ++a) {
            const float* xr = aS + (icl * 3 + a) * 116 + w0;
            float x0 = xr[0], x1 = xr[1], x2 = xr[2], x3 = xr[3];
            float wA = wb[icl * 9 + a * 3 + 0];
            float wB = wb[icl * 9 + a * 3 + 1];
            float wC = wb[icl * 9 + a * 3 + 2];
            a0 = fmaf(x0, wA, a0); a0 = fmaf(x1, wB, a0); a0 = fmaf(x2, wC, a0);
            a1 = fmaf(x1, wA, a1); a1 = fmaf(x2, wB, a1); a1 = fmaf(x3, wC, a1);
          }
        }
        accA[i] = a0; accB[i] = a1;
      }
    }
    for (int i = 0; i < 11; ++i) {
      int oidx = tid + i * 256;
      if (oidx >= 2736) break;
      int ocl = oidx / 57, wp = oidx - ocl * 57;
      int oc = ocg * 48 + ocl;
      float sc = bn3g[oc] * rsqrtf(bn3v[oc] + 1e-5f);
      float sh = bn3b[oc] - bn3m[oc] * sc;
      float v0 = fmaxf((accA[i] + c3b[oc]) * sc + sh, 0.f);
      float v1 = fmaxf((accB[i] + c3b[oc]) * sc + sh, 0.f);
      Bf[(size_t)(bl * 510 + t) * 5472 + oc * 57 + wp] = fmaxf(v0, v1);
    }
  }
}

// ---------------------------------------------------------------------------
// K3: fp32 NT GEMM  C = A * B^T + bias, output relaid to [t][16][768].
// ---------------------------------------------------------------------------
__global__ __launch_bounds__(256) void gemm_nt(
    const float* __restrict__ Am, const float* __restrict__ Bm,
    const float* __restrict__ bias, float* __restrict__ C,
    int M, int K, int lda, int ldb, int b0)
{
  __shared__ float As[64 * 33];
  __shared__ float Bs[64 * 33];
  const int tid = threadIdx.x;
  const int m0 = blockIdx.x * 64, n0 = blockIdx.y * 64;
  const int tx = tid & 15, ty = tid >> 4;
  const int kq = (tid & 7) * 4, rw = tid >> 3;
  float acc[4][4];
#pragma unroll
  for (int i = 0; i < 4; ++i)
#pragma unroll
    for (int j = 0; j < 4; ++j) acc[i][j] = 0.f;

  for (int k0 = 0; k0 < K; k0 += 32) {
    int m1 = m0 + rw, m2 = m1 + 32;
    float4 va = make_float4(0.f, 0.f, 0.f, 0.f), vb = va;
    if (m1 < M) va = *(const float4*)(Am + (size_t)m1 * lda + k0 + kq);
    if (m2 < M) vb = *(const float4*)(Am + (size_t)m2 * lda + k0 + kq);
    float4 wa = *(const float4*)(Bm + (size_t)(n0 + rw) * ldb + k0 + kq);
    float4 wb = *(const float4*)(Bm + (size_t)(n0 + rw + 32) * ldb + k0 + kq);
    As[rw * 33 + kq + 0] = va.x; As[rw * 33 + kq + 1] = va.y;
    As[rw * 33 + kq + 2] = va.z; As[rw * 33 + kq + 3] = va.w;
    As[(rw + 32) * 33 + kq + 0] = vb.x; As[(rw + 32) * 33 + kq + 1] = vb.y;
    As[(rw + 32) * 33 + kq + 2] = vb.z; As[(rw + 32) * 33 + kq + 3] = vb.w;
    Bs[rw * 33 + kq + 0] = wa.x; Bs[rw * 33 + kq + 1] = wa.y;
    Bs[rw * 33 + kq + 2] = wa.z; Bs[rw * 33 + kq + 3] = wa.w;
    Bs[(rw + 32) * 33 + kq + 0] = wb.x; Bs[(rw + 32) * 33 + kq + 1] = wb.y;
    Bs[(rw + 32) * 33 + kq + 2] = wb.z; Bs[(rw + 32) * 33 + kq + 3] = wb.w;
    __syncthreads();
#pragma unroll 8
    for (int k = 0; k < 32; ++k) {
      float av[4], bv[4];
#pragma unroll
      for (int i = 0; i < 4; ++i) av[i] = As[(ty * 4 + i) * 33 + k];
#pragma unroll
      for (int j = 0; j < 4; ++j) bv[j] = Bs[(tx * 4 + j) * 33 + k];
#pragma unroll
      for (int i = 0; i < 4; ++i)
#pragma unroll
        for (int j = 0; j < 4; ++j) acc[i][j] = fmaf(av[i], bv[j], acc[i][j]);
    }
    __syncthreads();
  }
#pragma unroll
  for (int i = 0; i < 4; ++i) {
    int m = m0 + ty * 4 + i;
    if (m >= M) continue;
    int bl2 = m / 510, tt2 = m - bl2 * 510;
    float* crow = C + ((size_t)tt2 * 16 + (b0 + bl2)) * 768;
#pragma unroll
    for (int j = 0; j < 4; ++j) {
      int n = n0 + tx * 4 + j;
      crow[n] = acc[i][j] + bias[n];
    }
  }
}

// ---------------------------------------------------------------------------
__global__ void init_state(ull* __restrict__ h1g, ull* __restrict__ h2g,
                           ull* __restrict__ prevg, unsigned* __restrict__ bar) {
  int gid = blockIdx.x * 256 + threadIdx.x;
  if (gid < 12288) { at_store(h1g + gid, 0ull); at_store(h2g + gid, 0ull); }
  if (gid < 2816) at_store(prevg + gid, 0ull);
  if (gid < BAR_U32)
    __hip_atomic_store(bar + gid, 0u, __ATOMIC_RELAXED, __HIP_MEMORY_SCOPE_AGENT);
}

// ---------------------------------------------------------------------------
// K6: persistent LSTM. 192 compute + 44 proj blocks; coherent gload_lds
// gathers; parallel flag waits with backoff; shfl-based publish.
// ---------------------------------------------------------------------------
__global__ __launch_bounds__(256, 1) void lstm_kernel(
    const float* __restrict__ aco,   // [510][16][768]
    const float* __restrict__ whh0,  // [3072][768]
    const float* __restrict__ wih0,  // [3072][944]
    const float* __restrict__ wih1,  // [3072][768]
    const float* __restrict__ whh1,  // [3072][768]
    const float* __restrict__ bih0, const float* __restrict__ bhh0,
    const float* __restrict__ bih1, const float* __restrict__ bhh1,
    const float* __restrict__ pw,    // [440][768]
    const float* __restrict__ pb,
    const float* __restrict__ emb,   // [5][2]
    ull* __restrict__ h1g,           // [2][6144] chunked
    ull* __restrict__ h2g,           // [2][6144] chunked
    ull* __restrict__ prevg,         // [2][16][88]
    unsigned* __restrict__ bar,
    float* __restrict__ out)         // [16][510][440]
{
  __shared__ float bufA[16 * 772];   // x (compute) / h2 (proj)
  __shared__ float bufB[16 * 772];   // h1
  __shared__ float bufC[16 * 772];   // h2(t-1)
  __shared__ float prevs[16 * 176];  // [b][176] pad-free
  __shared__ float zl[16 * 17];
  __shared__ float embS[10];
  const int tid = threadIdx.x;
  const int s = tid & 15;
  const int r = tid >> 4;
  const int wv = tid >> 6;           // wave index
  const int ln = tid & 63;           // lane
  unsigned* f1 = bar + F1_OFF;
  unsigned* f2 = bar + F2_OFF;
  unsigned* fp = bar + FP_OFF;

  if (blockIdx.x < NCOMP) {
    // =======================================================================
    // COMPUTE BLOCK
    // =======================================================================
    const int uB = blockIdx.x * 4;
    const int j = (r >> 2) * 768 + uB + (r & 3);

    float wx[48], w0[48], w1[48], w2[48], wp[11];
    {
      const float* p = wih0 + (size_t)j * 944 + 48 * s;
#pragma unroll
      for (int i = 0; i < 48; i += 4) {
        float4 v = *(const float4*)(p + i);
        wx[i] = v.x; wx[i+1] = v.y; wx[i+2] = v.z; wx[i+3] = v.w;
      }
      p = whh0 + (size_t)j * 768 + 48 * s;
#pragma unroll
      for (int i = 0; i < 48; i += 4) {
        float4 v = *(const float4*)(p + i);
        w0[i] = v.x; w0[i+1] = v.y; w0[i+2] = v.z; w0[i+3] = v.w;
      }
      p = wih1 + (size_t)j * 768 + 48 * s;
#pragma unroll
      for (int i = 0; i < 48; i += 4) {
        float4 v = *(const float4*)(p + i);
        w1[i] = v.x; w1[i+1] = v.y; w1[i+2] = v.z; w1[i+3] = v.w;
      }
      p = whh1 + (size_t)j * 768 + 48 * s;
#pragma unroll
      for (int i = 0; i < 48; i += 4) {
        float4 v = *(const float4*)(p + i);
        w2[i] = v.x; w2[i+1] = v.y; w2[i+2] = v.z; w2[i+3] = v.w;
      }
      const float* pp = wih0 + (size_t)j * 944 + 768 + 11 * s;
#pragma unroll
      for (int i = 0; i < 11; ++i) wp[i] = pp[i];
    }
    float bl1[4], bl2[4], c1 = 0.f, c2 = 0.f;
    if (tid < 64) {
      int ul = tid >> 4;
#pragma unroll
      for (int g = 0; g < 4; ++g) {
        int jj = g * 768 + uB + ul;
        bl1[g] = bih0[jj] + bhh0[jj];
        bl2[g] = bih1[jj] + bhh1[jj];
      }
    }
    const int hdst = (blockIdx.x / 12) * 384 + (blockIdx.x % 12) * 2;

    // h1(-1) = 0, h2(-1) = 0
    for (int i = tid; i < 16 * 772; i += 256) { bufB[i] = 0.f; bufC[i] = 0.f; }

    // prologue: x(0) stage + dot
    float zxr[16];
    STAGE_X(0);
    __syncthreads();
#pragma unroll 4
    for (int b = 0; b < 16; ++b) {
      float p; CDOT48(wx, bufA + s * 772 + b * 48, p);
      zxr[b] = red16(p);
    }

    for (int t = 0; t < 510; ++t) {
      const int wbuf = t & 1, rbuf = wbuf ^ 1;
      __syncthreads();
      // ---- issue x(t+1) stage early; drains at the post-w0 barrier ----
      if (t < 509) STAGE_X(t + 1);
      // ---- w0 dot: bufB = h1(t-1) (overlaps proj blocks' step-(t-1)) ----
#pragma unroll 4
      for (int b = 0; b < 16; ++b) {
        float p; CDOT48(w0, bufB + s * 772 + b * 48, p);
        p = red16(p);
        if (s == 0) zl[r * 17 + b] = zxr[b] + p;
      }
      // ---- prev(t-1) ready: all 44 proj flags >= t (parallel poll) ----
      if (t) wait_flags_n(fp, (unsigned)t, tid, NPROJ);
      else __syncthreads();
      // ---- prefetch h2(t-1) -> bufC; stage prev ----
      STAGE_H(h2g + rbuf * 6144, bufC);
      STAGE_PREV(rbuf);
      __syncthreads();
#pragma unroll 4
      for (int b = 0; b < 16; ++b) {
        const float* pvv = prevs + b * 176 + s * 11;
        float p = 0.f;
#pragma unroll
        for (int i = 0; i < 11; ++i) p = fmaf(wp[i], pvv[i], p);
        p = red16(p);
        if (s == 0) zl[r * 17 + b] += p;
      }
      __syncthreads();
      // ---- cell 1 + shfl publish (wave 0 only, program-ordered flag) ----
      if (tid < 64) {
        int ul = tid >> 4, bb = tid & 15;
        float zi = zl[(0 * 4 + ul) * 17 + bb] + bl1[0];
        float zf = zl[(1 * 4 + ul) * 17 + bb] + bl1[1];
        float zg = zl[(2 * 4 + ul) * 17 + bb] + bl1[2];
        float zo = zl[(3 * 4 + ul) * 17 + bb] + bl1[3];
        c1 = sigf(zf) * c1 + sigf(zi) * tanhf(zg);
        float h = sigf(zo) * tanhf(c1);
        int src1 = (tid >> 4) * 32 + (tid & 15);
        float v1 = __shfl(h, src1, 64);
        float v2 = __shfl(h, src1 + 16, 64);
        if (tid < 32) {
          int q = tid >> 4, bb2 = tid & 15;
          at_store(h1g + wbuf * 6144 + hdst + bb2 * 24 + q, pack2(v1, v2));
        }
        if (tid == 0) {
          __builtin_amdgcn_s_waitcnt(0);
          __atomic_signal_fence(__ATOMIC_SEQ_CST);
          __hip_atomic_store(f1 + blockIdx.x * 16, (unsigned)(t + 1),
                             __ATOMIC_RELAXED, __HIP_MEMORY_SCOPE_AGENT);
        }
      }
      // ---- wx dot for t+1 fills the f1-hide window (bufA fully staged) ----
      if (t < 509) {
#pragma unroll 4
        for (int b = 0; b < 16; ++b) {
          float p; CDOT48(wx, bufA + s * 772 + b * 48, p);
          zxr[b] = red16(p);
        }
      }
      // ---- f1 wait, stage h1(t), fused w1/w2 dot ----
      wait_flags_n(f1, (unsigned)(t + 1), tid, NCOMP);
      STAGE_H(h1g + wbuf * 6144, bufB);
      __syncthreads();
#pragma unroll 2
      for (int b = 0; b < 16; ++b) {
        float p1, p2;
        CDOT48(w1, bufB + s * 772 + b * 48, p1);
        CDOT48(w2, bufC + s * 772 + b * 48, p2);
        float p = red16(p1 + p2);
        if (s == 0) zl[r * 17 + b] = p;
      }
      __syncthreads();
      // ---- cell 2 + shfl publish ----
      if (tid < 64) {
        int ul = tid >> 4, bb = tid & 15;
        float zi = zl[(0 * 4 + ul) * 17 + bb] + bl2[0];
        float zf = zl[(1 * 4 + ul) * 17 + bb] + bl2[1];
        float zg = zl[(2 * 4 + ul) * 17 + bb] + bl2[2];
        float zo = zl[(3 * 4 + ul) * 17 + bb] + bl2[3];
        c2 = sigf(zf) * c2 + sigf(zi) * tanhf(zg);
        float h = sigf(zo) * tanhf(c2);
        int src1 = (tid >> 4) * 32 + (tid & 15);
        float v1 = __shfl(h, src1, 64);
        float v2 = __shfl(h, src1 + 16, 64);
        if (tid < 32) {
          int q = tid >> 4, bb2 = tid & 15;
          at_store(h2g + wbuf * 6144 + hdst + bb2 * 24 + q, pack2(v1, v2));
        }
        if (tid == 0) {
          __builtin_amdgcn_s_waitcnt(0);
          __atomic_signal_fence(__ATOMIC_SEQ_CST);
          __hip_atomic_store(f2 + blockIdx.x * 16, (unsigned)(t + 1),
                             __ATOMIC_RELAXED, __HIP_MEMORY_SCOPE_AGENT);
        }
      }
    }
  } else {
    // =======================================================================
    // PROJECTION BLOCK: 10 logit rows (2 argmax groups), all 16 batches.
    // =======================================================================
    const int bp = blockIdx.x - NCOMP;   // 0..43
    const int prow = bp * 10 + r;        // valid for r < 10
    float pwr[48];
    float pbv = 0.f;
    if (r < 10) {
      const float* p = pw + (size_t)prow * 768 + 48 * s;
#pragma unroll
      for (int i = 0; i < 48; i += 4) {
        float4 v = *(const float4*)(p + i);
        pwr[i] = v.x; pwr[i+1] = v.y; pwr[i+2] = v.z; pwr[i+3] = v.w;
      }
      pbv = pb[prow];
    } else {
#pragma unroll
      for (int i = 0; i < 48; ++i) pwr[i] = 0.f;
    }
    if (tid < 10) embS[tid] = emb[tid];
    __syncthreads();

    for (int t = 0; t < 510; ++t) {
      const int wbuf = t & 1;
      wait_flags_n(f2, (unsigned)(t + 1), tid, NCOMP);
      STAGE_H(h2g + wbuf * 6144, bufA);
      __syncthreads();
#pragma unroll 4
      for (int b = 0; b < 16; ++b) {
        float p; CDOT48(pwr, bufA + s * 772 + b * 48, p);
        p = red16(p);
        if (r < 10 && s == 0) {
          float lg = p + pbv;
          out[((size_t)b * 510 + t) * 440 + prow] = lg;
          zl[r * 17 + b] = lg;
        }
      }
      __syncthreads();
      if (tid < 32) {
        int q = tid >> 4, bb = tid & 15;
        float best = zl[(q * 5) * 17 + bb]; int bi = 0;
#pragma unroll
        for (int c = 1; c < 5; ++c) {
          float v = zl[(q * 5 + c) * 17 + bb];
          if (v > best) { best = v; bi = c; }
        }
        at_store(prevg + wbuf * 1408 + bb * 88 + bp * 2 + q,
                 pack2(embS[bi * 2], embS[bi * 2 + 1]));
      }
      if (tid == 0) {
        __builtin_amdgcn_s_waitcnt(0);
        __atomic_signal_fence(__ATOMIC_SEQ_CST);
        __hip_atomic_store(fp + bp * 16, (unsigned)(t + 1),
                           __ATOMIC_RELAXED, __HIP_MEMORY_SCOPE_AGENT);
      }
    }
  }
}

// ---------------------------------------------------------------------------
extern "C" void kernel_launch(void* const* d_in, const int* in_sizes, int n_in,
                              void* d_out, int out_size, void* d_ws, size_t ws_size,
                              hipStream_t stream) {
  (void)in_sizes; (void)n_in; (void)out_size;
  const float* mel  = (const float*)d_in[0];
  const float* c1w  = (const float*)d_in[1];
  const float* c1b  = (const float*)d_in[2];
  const float* c2w  = (const float*)d_in[3];
  const float* c2b  = (const float*)d_in[4];
  const float* c3w  = (const float*)d_in[5];
  const float* c3b  = (const float*)d_in[6];
  const float* bn1g = (const float*)d_in[7];
  const float* bn1b = (const float*)d_in[8];
  const float* bn1m = (const float*)d_in[9];
  const float* bn1v = (const float*)d_in[10];
  const float* bn2g = (const float*)d_in[11];
  const float* bn2b = (const float*)d_in[12];
  const float* bn2m = (const float*)d_in[13];
  const float* bn2v = (const float*)d_in[14];
  const float* bn3g = (const float*)d_in[15];
  const float* bn3b = (const float*)d_in[16];
  const float* bn3m = (const float*)d_in[17];
  const float* bn3v = (const float*)d_in[18];
  const float* fcw  = (const float*)d_in[19];
  const float* fcb  = (const float*)d_in[20];
  const float* wih0 = (const float*)d_in[21];
  const float* whh0 = (const float*)d_in[22];
  const float* bih0 = (const float*)d_in[23];
  const float* bhh0 = (const float*)d_in[24];
  const float* wih1 = (const float*)d_in[25];
  const float* whh1 = (const float*)d_in[26];
  const float* bih1 = (const float*)d_in[27];
  const float* bhh1 = (const float*)d_in[28];
  const float* pw   = (const float*)d_in[29];
  const float* pb   = (const float*)d_in[30];
  const float* emb  = (const float*)d_in[31];

  float* ws = (float*)d_ws;
  float* outp = (float*)d_out;

  const size_t ST_ULL = 12288ull + 12288ull + 2816ull;
  int CB = 1;
  for (int cb = 4; cb >= 1; cb >>= 1) {
    size_t need = (ACO_FL + (size_t)cb * 48 * 512 * 114 + (size_t)cb * 510 * 5472) * 4
                + ST_ULL * 8 + BAR_U32 * 4 + 1024;
    if (ws_size >= need) { CB = cb; break; }
  }
  const int nchunks = 16 / CB;
  const size_t A_FL  = (size_t)CB * 48 * 512 * 114;
  const size_t BF_FL = (size_t)CB * 510 * 5472;

  float* aco = ws;                       // [510][16][768]
  float* Ac  = ws + ACO_FL;
  float* Bfc = Ac + A_FL;
  ull* h1g   = (ull*)(Bfc + BF_FL);
  ull* h2g   = h1g + 12288;
  ull* prevg = h2g + 12288;
  unsigned* bar = (unsigned*)(prevg + 2816);

  for (int ch = 0; ch < nchunks; ++ch) {
    int b0 = ch * CB;
    hipLaunchKernelGGL(conv12_kernel, dim3(CB * 512), dim3(256), 0, stream,
                       mel, c1w, c1b, bn1g, bn1b, bn1m, bn1v,
                       c2w, c2b, bn2g, bn2b, bn2m, bn2v, Ac, b0);
    hipLaunchKernelGGL(conv3_kernel, dim3(CB * 510), dim3(256), 0, stream,
                       Ac, c3w, c3b, bn3g, bn3b, bn3m, bn3v, Bfc);
    int M = CB * 510;
    hipLaunchKernelGGL(gemm_nt, dim3((M + 63) / 64, 12), dim3(256), 0, stream,
                       Bfc, fcw, fcb, aco, M, 5472, 5472, 5472, b0);
  }
  hipLaunchKernelGGL(init_state, dim3(48), dim3(256), 0, stream,
                     h1g, h2g, prevg, bar);

  {
    void* args[] = {
      (void*)&aco, (void*)&whh0, (void*)&wih0, (void*)&wih1, (void*)&whh1,
      (void*)&bih0, (void*)&bhh0, (void*)&bih1, (void*)&bhh1,
      (void*)&pw, (void*)&pb, (void*)&emb,
      (void*)&h1g, (void*)&h2g, (void*)&prevg, (void*)&bar, (void*)&outp
    };
    hipError_t e = hipLaunchCooperativeKernel((const void*)lstm_kernel,
                                              dim3(NCOMP + NPROJ), dim3(256),
                                              args, 0, stream);
    if (e != hipSuccess) {
      (void)hipGetLastError();
      hipLaunchKernelGGL(lstm_kernel, dim3(NCOMP + NPROJ), dim3(256), 0, stream,
                         aco, whh0, wih0, wih1, whh1, bih0, bhh0, bih1, bhh1,
                         pw, pb, emb, h1g, h2g, prevg, bar, outp);
    }
  }
}